// Round 7
// baseline (184.161 us; speedup 1.0000x reference)
//
#include <hip/hip_runtime.h>
#include <math.h>

// Bahdanau additive attention. B=4, T=32, S=1024, H=512, D=2H=1024.
// Inputs fp32 (mask int32), OUTPUT fp32 flat:
//   context (4,32,1024) | hidden (4,32,512) | attn_t (4,1024,32)
// Round 22 (tier-4g): block-INTERNAL split-K for prep's qf/hidQ blocks
// (4 k-groups x LDS-reduce; per-block latency unchanged at 128 k-iters --
// NOT the R16/R18 full-K mistake): qf -> Eq=exp2 stored directly (kills the
// 2MB qfp round-trip + f2 prologue); hidQ+bias PLAIN-stored into Bh (kills
// the memset dispatch; f6c atomics accumulate on top, stream-ordered).
// f2j = pure dbuf GEMM + Es bf16 epilogue. 5 dispatches, 0 memsets.
// d_out overlay: A[0,131072): ctx(final)  B[131072,196608): hidden(prep-init)
//                C[196608,327680): attn_t(final)

typedef unsigned short u16;
typedef __bf16 bf16x8 __attribute__((ext_vector_type(8)));
typedef float floatx4 __attribute__((ext_vector_type(4)));

#define B_ 4
#define T_ 32
#define S_ 1024
#define H_ 512
#define D_ 1024
#define BT_ 128
#define TWO_LOG2E 2.8853900817779268f   // tanh(y) = 1 - 2/(exp2(2*log2e*y)+1)
#define LOG2E 1.4426950408889634f

__device__ __forceinline__ float bf2f(u16 u) {
  unsigned int i = ((unsigned int)u) << 16;
  return __builtin_bit_cast(float, i);
}
__device__ __forceinline__ u16 f2bf(float f) {
  unsigned int i = __builtin_bit_cast(unsigned int, f);
  i += 0x7fffu + ((i >> 16) & 1u);  // RNE
  return (u16)(i >> 16);
}
__device__ __forceinline__ void ld_g2l_16(const u16* g, u16* l) {
  __builtin_amdgcn_global_load_lds((__attribute__((address_space(1))) void*)(u16*)g,
                                   (__attribute__((address_space(3))) void*)l, 16, 0, 0);
}

// ================= TIER-4 KERNELS =================

// ---- PREP7: heavy blocks FIRST (light blocks backfill; no serial tail).
//      [0,256)    Eq = exp2(2log2e*(query@Wq+bq)): 8x64 tile, 4 k-groups
//                 internal split-K + LDS reduce, plain store;
//      [256,384)  Bh = query@Wc[1024:]+bc: same structure, PLAIN store
//                 (no atomics -> no memset; f6c accumulates on top);
//      [384,896)  Ws^T -> WsT bf16 (block 384 zeroes rowsum);
//      [896,2944) states -> sbf + sbfT.
__global__ __launch_bounds__(256) void prep_fused7(const float* __restrict__ states, const float* __restrict__ Ws,
                                                   const float* __restrict__ query, const float* __restrict__ Wq,
                                                   const float* __restrict__ bq,
                                                   const float* __restrict__ Wc, const float* __restrict__ bc,
                                                   u16* __restrict__ sbf, u16* __restrict__ sbfT,
                                                   u16* __restrict__ WsT, float* __restrict__ Eq,
                                                   float* __restrict__ rowsum, float* __restrict__ hid) {
  __shared__ __align__(16) float smem[4096];    // 16KB overlay: qq[8][512] -> red[4][8][64] / tile
  const int t = threadIdx.x;
  if (blockIdx.x < 384) {
    const int isQ = (blockIdx.x < 256);
    const int idx = isQ ? blockIdx.x : blockIdx.x - 256;
    const int c0 = isQ ? (idx & 15) * 64 : (idx & 7) * 64;
    const int r0 = isQ ? (idx >> 4) * 8 : (idx >> 3) * 8;
    float* qq = smem;                           // [8][512] fp32
    const float4* qsrc = (const float4*)(query + (size_t)r0 * H_);
    for (int i = t; i < 1024; i += 256) ((float4*)qq)[i] = qsrc[i];
    __syncthreads();
    const int kg = t >> 6, cl = t & 63;
    const int col = c0 + cl;
    const int kbase = kg * 128;
    float acc[8] = {};
    if (isQ) {
      for (int kk = 0; kk < 128; ++kk) {
        const float w = Wq[(size_t)(kbase + kk) * D_ + col];
#pragma unroll
        for (int r = 0; r < 8; ++r) acc[r] = fmaf(qq[r * 512 + kbase + kk], w, acc[r]);
      }
    } else {
      for (int kk = 0; kk < 128; ++kk) {
        const float w = Wc[(size_t)(D_ + kbase + kk) * H_ + col];
#pragma unroll
        for (int r = 0; r < 8; ++r) acc[r] = fmaf(qq[r * 512 + kbase + kk], w, acc[r]);
      }
    }
    __syncthreads();                            // all qq reads done -> overlay
    float* red = smem;                          // [4][8][64]
#pragma unroll
    for (int r = 0; r < 8; ++r) red[(kg * 8 + r) * 64 + cl] = acc[r];
    __syncthreads();
    if (isQ) {
      for (int o = t; o < 512; o += 256) {
        const int r = o >> 6, c = o & 63;
        const float s = red[(0 * 8 + r) * 64 + c] + red[(1 * 8 + r) * 64 + c] +
                        red[(2 * 8 + r) * 64 + c] + red[(3 * 8 + r) * 64 + c] + bq[c0 + c];
        Eq[(size_t)(r0 + r) * D_ + c0 + c] = __builtin_amdgcn_exp2f(TWO_LOG2E * s);
      }
    } else {
      for (int o = t; o < 512; o += 256) {
        const int r = o >> 6, c = o & 63;
        const float s = red[(0 * 8 + r) * 64 + c] + red[(1 * 8 + r) * 64 + c] +
                        red[(2 * 8 + r) * 64 + c] + red[(3 * 8 + r) * 64 + c] + bc[c0 + c];
        hid[(size_t)(r0 + r) * H_ + c0 + c] = s;
      }
    }
  } else if (blockIdx.x < 896) {
    u16 (*tile)[65] = (u16(*)[65])smem;
    const int bid = blockIdx.x - 384;           // 0..511: Ws transpose
    if (bid == 0 && t < 128) rowsum[t] = 0.f;   // zero rsum (read only by f3k/f5e)
    const int n0 = (bid & 15) * 64, k0 = (bid >> 4) * 32;
    const int kr = t >> 3, nc = (t & 7) * 8;
    const float* p = Ws + (size_t)(k0 + kr) * D_ + n0 + nc;
    float4 a = *(const float4*)p, b = *(const float4*)(p + 4);
    tile[kr][nc + 0] = f2bf(a.x); tile[kr][nc + 1] = f2bf(a.y);
    tile[kr][nc + 2] = f2bf(a.z); tile[kr][nc + 3] = f2bf(a.w);
    tile[kr][nc + 4] = f2bf(b.x); tile[kr][nc + 5] = f2bf(b.y);
    tile[kr][nc + 6] = f2bf(b.z); tile[kr][nc + 7] = f2bf(b.w);
    __syncthreads();
    const int nr = t >> 2, kc = (t & 3) * 8;
    union { uint4 v; u16 s[8]; } st;
#pragma unroll
    for (int i = 0; i < 8; ++i) st.s[i] = tile[kc + i][nr];
    *(uint4*)(WsT + (size_t)(n0 + nr) * D_ + k0 + kc) = st.v;
  } else {
    u16 (*tile)[65] = (u16(*)[65])smem;
    const int bid = blockIdx.x - 896;           // 0..2047: states cvt+transpose
    const int b = bid >> 9;
    const int r2 = bid & 511;
    const int d0 = (r2 & 15) * 64, s0 = (r2 >> 4) * 32;
    const int sr = t >> 3, dc = (t & 7) * 8;
    const float* p = states + ((size_t)b * S_ + s0 + sr) * D_ + d0 + dc;
    float4 a = *(const float4*)p, bb = *(const float4*)(p + 4);
    union { uint4 v; u16 s[8]; } pk;
    pk.s[0] = f2bf(a.x); pk.s[1] = f2bf(a.y); pk.s[2] = f2bf(a.z); pk.s[3] = f2bf(a.w);
    pk.s[4] = f2bf(bb.x); pk.s[5] = f2bf(bb.y); pk.s[6] = f2bf(bb.z); pk.s[7] = f2bf(bb.w);
    *(uint4*)(sbf + ((size_t)b * S_ + s0 + sr) * D_ + d0 + dc) = pk.v;
#pragma unroll
    for (int i = 0; i < 8; ++i) tile[sr][dc + i] = pk.s[i];
    __syncthreads();
    const int dr = t >> 2, sc = (t & 3) * 8;
    union { uint4 v; u16 s[8]; } st;
#pragma unroll
    for (int i = 0; i < 8; ++i) st.s[i] = tile[sc + i][dr];
    *(uint4*)(sbfT + ((size_t)b * D_ + d0 + dr) * S_ + s0 + sc) = st.v;
  }
}

// ---- F2j: Es = bf16(exp2(2log2e*(sbf @ Ws))). Pure dbuf GEMM: global_load_lds
// prefetch, counted vmcnt(6), raw s_barrier; XOR-swizzled LDS reads.
__device__ __forceinline__ void f2f_stage(const u16* __restrict__ A, const u16* __restrict__ BT,
                                          u16* sAb, u16* sBb, int bm0, int bn0, int k0,
                                          int wv, int srow, int sp) {
#pragma unroll
  for (int j = 0; j < 4; ++j) {                  // A: rows wv*32 + j*8 + srow
    const int r = wv * 32 + j * 8 + srow;
    const int c = sp ^ (r & 7);
    ld_g2l_16(A + (size_t)(bm0 + r) * D_ + k0 + c * 8, sAb + (wv * 32 + j * 8) * 64);
  }
#pragma unroll
  for (int j = 0; j < 2; ++j) {                  // B: rows wv*16 + j*8 + srow
    const int r = wv * 16 + j * 8 + srow;
    const int c = sp ^ (r & 7);
    ld_g2l_16(BT + (size_t)(bn0 + r) * D_ + k0 + c * 8, sBb + (wv * 16 + j * 8) * 64);
  }
}

__device__ __forceinline__ void f2f_compute(const u16* sAb, const u16* sBb,
                                            int wm, int wn, int fm, int fq, floatx4 (&acc)[4][2]) {
#pragma unroll
  for (int win = 0; win < 2; ++win) {
    bf16x8 af[4], bfr[2];
#pragma unroll
    for (int i = 0; i < 4; ++i) {
      const int R = wm + i * 16 + fm;
      af[i] = *(const bf16x8*)&sAb[R * 64 + ((win * 4 + fq) ^ (R & 7)) * 8];
    }
#pragma unroll
    for (int j = 0; j < 2; ++j) {
      const int R = wn + j * 16 + fm;
      bfr[j] = *(const bf16x8*)&sBb[R * 64 + ((win * 4 + fq) ^ (R & 7)) * 8];
    }
#pragma unroll
    for (int i = 0; i < 4; ++i)
#pragma unroll
      for (int j = 0; j < 2; ++j)
        acc[i][j] = __builtin_amdgcn_mfma_f32_16x16x32_bf16(af[i], bfr[j], acc[i][j], 0, 0, 0);
  }
}

__global__ __launch_bounds__(256) void f2j_sfgemm(const u16* __restrict__ A, const u16* __restrict__ BT,
                                                  u16* __restrict__ Es) {
  __shared__ __align__(16) u16 sA[2][128 * 64];  // 2 x 16 KB
  __shared__ __align__(16) u16 sB[2][64 * 64];   // 2 x 8 KB
  const int bm0 = blockIdx.y * 128, bn0 = blockIdx.x * 64;
  const int t = threadIdx.x;
  const int wv = t >> 6, lane = t & 63;
  const int wm = (wv >> 1) * 64, wn = (wv & 1) * 32;
  const int fm = lane & 15, fq = lane >> 4;
  const int srow = lane >> 3, sp = lane & 7;

  floatx4 acc[4][2];
  const floatx4 fz = {0.f, 0.f, 0.f, 0.f};
#pragma unroll
  for (int i = 0; i < 4; ++i) { acc[i][0] = fz; acc[i][1] = fz; }

  f2f_stage(A, BT, sA[0], sB[0], bm0, bn0, 0, wv, srow, sp);
#pragma unroll 1
  for (int k0 = 0; k0 < D_; k0 += 128) {
    // even phase: compute buf0, prefetch buf1(k0+64)
    f2f_stage(A, BT, sA[1], sB[1], bm0, bn0, k0 + 64, wv, srow, sp);
    asm volatile("s_waitcnt vmcnt(6)" ::: "memory");   // buf0's 6 loads landed
    __builtin_amdgcn_s_barrier();
    f2f_compute(sA[0], sB[0], wm, wn, fm, fq, acc);
    __builtin_amdgcn_s_barrier();                      // all waves done reading buf0
    // odd phase: compute buf1, prefetch buf0(k0+128)
    if (k0 + 128 < D_) {
      f2f_stage(A, BT, sA[0], sB[0], bm0, bn0, k0 + 128, wv, srow, sp);
      asm volatile("s_waitcnt vmcnt(6)" ::: "memory"); // buf1's 6 loads landed
    } else {
      asm volatile("s_waitcnt vmcnt(0)" ::: "memory");
    }
    __builtin_amdgcn_s_barrier();
    f2f_compute(sA[1], sB[1], wm, wn, fm, fq, acc);
    __builtin_amdgcn_s_barrier();
  }
#pragma unroll
  for (int i = 0; i < 4; ++i)
#pragma unroll
    for (int j = 0; j < 2; ++j)
#pragma unroll
      for (int r = 0; r < 4; ++r) {
        const int row = bm0 + wm + i * 16 + fq * 4 + r;   // col=lane&15, row=quad*4+reg (m89)
        const int col = bn0 + wn + j * 16 + fm;
        Es[(size_t)row * D_ + col] = f2bf(__builtin_amdgcn_exp2f(TWO_LOG2E * acc[i][j][r]));
      }
}

// ---- F3k: E = exp(alg), alg = sumv + sum_j vm2_j*rcp(fma(Eq,Es,1)).
// No-max softmax. 4 s-values per wave: Eq L2 re-read 128MB, 4x rcp ILP.
// Four E bf16 packed as one uint2 store. 256 blocks (1024 waves).
__global__ __launch_bounds__(256) void f3k_align(const float* __restrict__ Eq, const u16* __restrict__ Es,
                                                 const float* __restrict__ v, const int* __restrict__ mask,
                                                 u16* __restrict__ pbf, float* __restrict__ rowsum) {
  __shared__ float red[32][4];
  const int wv = threadIdx.x >> 6, lane = threadIdx.x & 63;
  const int w = blockIdx.x * 4 + wv;                      // 0..1023
  const int b = w >> 8;                                   // 256 waves per batch
  const int s0 = (w & 255) * 4;
  const int m0 = mask[(size_t)b * S_ + s0 + 0];
  const int m1 = mask[(size_t)b * S_ + s0 + 1];
  const int m2 = mask[(size_t)b * S_ + s0 + 2];
  const int m3 = mask[(size_t)b * S_ + s0 + 3];
  float vm2[16], es0[16], es1[16], es2[16], es3[16];
  float sumv = 0.f;
  {
    union { uint4 u[2]; u16 h[16]; } u0, u1, u2, u3;
    const uint4* ep0 = (const uint4*)(Es + ((size_t)b * S_ + s0 + 0) * D_ + lane * 16);
    const uint4* ep1 = (const uint4*)(Es + ((size_t)b * S_ + s0 + 1) * D_ + lane * 16);
    const uint4* ep2 = (const uint4*)(Es + ((size_t)b * S_ + s0 + 2) * D_ + lane * 16);
    const uint4* ep3 = (const uint4*)(Es + ((size_t)b * S_ + s0 + 3) * D_ + lane * 16);
    u0.u[0] = ep0[0]; u0.u[1] = ep0[1];
    u1.u[0] = ep1[0]; u1.u[1] = ep1[1];
    u2.u[0] = ep2[0]; u2.u[1] = ep2[1];
    u3.u[0] = ep3[0]; u3.u[1] = ep3[1];
    const float4* vp = (const float4*)(v + lane * 16);
#pragma unroll
    for (int c = 0; c < 4; ++c) {
      const float4 w4 = vp[c];
      vm2[4 * c + 0] = -2.f * w4.x; vm2[4 * c + 1] = -2.f * w4.y;
      vm2[4 * c + 2] = -2.f * w4.z; vm2[4 * c + 3] = -2.f * w4.w;
      sumv += w4.x + w4.y + w4.z + w4.w;
    }
#pragma unroll
    for (int j = 0; j < 16; ++j) {
      es0[j] = bf2f(u0.h[j]); es1[j] = bf2f(u1.h[j]);
      es2[j] = bf2f(u2.h[j]); es3[j] = bf2f(u3.h[j]);
    }
  }
  const float* qbase = Eq + ((size_t)(b * T_)) * D_ + lane * 16;
  for (int tc = 0; tc < 8; ++tc) {               // 8 chunks of 4 t-rows
    float sa[4], sb[4], sc[4], sd[4];
#pragma unroll
    for (int ti = 0; ti < 4; ++ti) {
      const float4* qp = (const float4*)(qbase + (size_t)(tc * 4 + ti) * D_);
      float a0 = sumv, a1 = sumv, a2 = sumv, a3 = sumv;
#pragma unroll
      for (int c = 0; c < 4; ++c) {
        const float4 q4 = qp[c];
        const float xs[4] = {q4.x, q4.y, q4.z, q4.w};
#pragma unroll
        for (int u2 = 0; u2 < 4; ++u2) {
          const int j = 4 * c + u2;
          a0 = fmaf(vm2[j], __builtin_amdgcn_rcpf(fmaf(xs[u2], es0[j], 1.f)), a0);
          a1 = fmaf(vm2[j], __builtin_amdgcn_rcpf(fmaf(xs[u2], es1[j], 1.f)), a1);
          a2 = fmaf(vm2[j], __builtin_amdgcn_rcpf(fmaf(xs[u2], es2[j], 1.f)), a2);
          a3 = fmaf(vm2[j], __builtin_amdgcn_rcpf(fmaf(xs[u2], es3[j], 1.f)), a3);
        }
      }
      sa[ti] = a0; sb[ti] = a1; sc[ti] = a2; sd[ti] = a3;
    }
#pragma unroll
    for (int off = 32; off > 0; off >>= 1)
#pragma unroll
      for (int ti = 0; ti < 4; ++ti) {
        sa[ti] += __shfl_xor(sa[ti], off);
        sb[ti] += __shfl_xor(sb[ti], off);
        sc[ti] += __shfl_xor(sc[ti], off);
        sd[ti] += __shfl_xor(sd[ti], off);
      }
    if (lane == 0) {
#pragma unroll
      for (int ti = 0; ti < 4; ++ti) {
        const int tt = tc * 4 + ti;
        const float e0 = m0 ? __builtin_amdgcn_exp2f(sa[ti] * LOG2E) : 0.f;
        const float e1 = m1 ? __builtin_amdgcn_exp2f(sb[ti] * LOG2E) : 0.f;
        const float e2 = m2 ? __builtin_amdgcn_exp2f(sc[ti] * LOG2E) : 0.f;
        const float e3 = m3 ? __builtin_amdgcn_exp2f(sd[ti] * LOG2E) : 0.f;
        const u16 p0 = f2bf(e0), p1 = f2bf(e1), p2 = f2bf(e2), p3 = f2bf(e3);
        uint2 pk;
        pk.x = (unsigned int)p0 | ((unsigned int)p1 << 16);
        pk.y = (unsigned int)p2 | ((unsigned int)p3 << 16);
        *(uint2*)&pbf[((size_t)(b * T_ + tt)) * S_ + s0] = pk;
        red[tt][wv] = bf2f(p0) + bf2f(p1) + bf2f(p2) + bf2f(p3);
      }
    }
  }
  __syncthreads();
  if (threadIdx.x < 32) {
    const int bb = blockIdx.x >> 6;              // 64 blocks per batch
    const float rs = red[threadIdx.x][0] + red[threadIdx.x][1] +
                     red[threadIdx.x][2] + red[threadIdx.x][3];
    atomicAdd(&rowsum[bb * 32 + threadIdx.x], rs);
  }
}

// ---- F5e: ctx = (E @ states)/rowsum. 256 blocks (16 ctx-cols each); 4 waves
// split S into 256-chunks, LDS-reduce; normalization + attn_t slice folded.
__global__ __launch_bounds__(256) void f5e_context(const u16* __restrict__ pbf, const u16* __restrict__ sbfT,
                                                   const float* __restrict__ rowsum,
                                                   float* __restrict__ ctx, float* __restrict__ out_at) {
  __shared__ float rinv[32];
  __shared__ float red[4][64][9];
  const int b = blockIdx.x >> 6, dt = blockIdx.x & 63;
  const int wv = threadIdx.x >> 6, lane = threadIdx.x & 63;
  if (threadIdx.x < 32) rinv[threadIdx.x] = 1.f / rowsum[b * 32 + threadIdx.x];
  const int n0 = dt * 16;
  const int fm = lane & 15, fq = lane >> 4;
  const floatx4 fz = {0.f, 0.f, 0.f, 0.f};
  floatx4 acc0 = fz, acc1 = fz;
  const u16* pa0 = pbf + ((size_t)b * T_ + fm) * S_ + wv * 256 + fq * 8;
  const u16* pa1 = pa0 + (size_t)16 * S_;
  const u16* pb  = sbfT + ((size_t)b * D_ + n0 + fm) * S_ + wv * 256 + fq * 8;
#pragma unroll
  for (int k0 = 0; k0 < 256; k0 += 32) {
    bf16x8 a0 = *(const bf16x8*)(pa0 + k0);
    bf16x8 a1 = *(const bf16x8*)(pa1 + k0);
    bf16x8 bb = *(const bf16x8*)(pb + k0);
    acc0 = __builtin_amdgcn_mfma_f32_16x16x32_bf16(a0, bb, acc0, 0, 0, 0);
    acc1 = __builtin_amdgcn_mfma_f32_16x16x32_bf16(a1, bb, acc1, 0, 0, 0);
  }
#pragma unroll
  for (int r = 0; r < 4; ++r) {
    red[wv][lane][r] = acc0[r];
    red[wv][lane][4 + r] = acc1[r];
  }
  __syncthreads();
  // attn_t slice: s in [dt*16, dt*16+16), all 32 t. All threads.
  const int s0a = dt * 16;
  for (int i = threadIdx.x; i < 512; i += 256) {
    const int tt = i & 31, sl = i >> 5;
    const float e = bf2f(pbf[((size_t)(b * T_ + tt)) * S_ + s0a + sl]);
    out_at[((size_t)(b * S_ + s0a + sl)) * T_ + tt] = e * rinv[tt];
  }
  if (wv == 0) {
#pragma unroll
    for (int r = 0; r < 4; ++r) {
      const float v0 = red[0][lane][r] + red[1][lane][r] + red[2][lane][r] + red[3][lane][r];
      const float v1 = red[0][lane][4 + r] + red[1][lane][4 + r] +
                       red[2][lane][4 + r] + red[3][lane][4 + r];
      const int t0r = fq * 4 + r;
      ctx[((size_t)b * T_ + t0r) * D_ + n0 + fm] = v0 * rinv[t0r];
      ctx[((size_t)b * T_ + 16 + t0r) * D_ + n0 + fm] = v1 * rinv[16 + t0r];
    }
  }
}

// ---- F6c: hidden += ctx_kslice @ Wc[0:1024] (query part + bias pre-stored by prep). ----
__global__ __launch_bounds__(256) void f6c_outproj(const float* __restrict__ ctx,
                                                   const float* __restrict__ Wc,
                                                   float* __restrict__ out_hid) {
  __shared__ float cq[16][128];
  const int c0 = blockIdx.x * 128, r0 = blockIdx.y * 16, k0 = blockIdx.z * 128;
  const int tid = threadIdx.x;
  const int cl = tid & 127, rh = tid >> 7;
  for (int i = tid; i < 16 * 128; i += 256) {
    const int rl = i >> 7, kk = i & 127;
    cq[rl][kk] = ctx[(size_t)(r0 + rl) * D_ + k0 + kk];
  }
  __syncthreads();
  float acc[8] = {};
  for (int kk = 0; kk < 128; ++kk) {
    const float w = Wc[(size_t)(k0 + kk) * H_ + c0 + cl];
#pragma unroll
    for (int rr = 0; rr < 8; ++rr) acc[rr] = fmaf(cq[rh * 8 + rr][kk], w, acc[rr]);
  }
#pragma unroll
  for (int rr = 0; rr < 8; ++rr)
    atomicAdd(&out_hid[(size_t)(r0 + rh * 8 + rr) * H_ + c0 + cl], acc[rr]);
}

// ================= TIER-3 KERNELS =================

__global__ __launch_bounds__(256) void prep_fused(const float* __restrict__ states, const float* __restrict__ Ws,
                                                  const float* __restrict__ query, const float* __restrict__ Wq,
                                                  const float* __restrict__ bq,
                                                  u16* __restrict__ sbf, u16* __restrict__ sbfT,
                                                  u16* __restrict__ WsT, float* __restrict__ qf) {
  __shared__ u16 tile[32][65];
  __shared__ float q[8][128];
  const int t = threadIdx.x;
  if (blockIdx.x < 512) {
    const int n0 = (blockIdx.x & 15) * 64, k0 = (blockIdx.x >> 4) * 32;
    const int kr = t >> 3, nc = (t & 7) * 8;
    const float* p = Ws + (size_t)(k0 + kr) * D_ + n0 + nc;
    float4 a = *(const float4*)p, b = *(const float4*)(p + 4);
    tile[kr][nc + 0] = f2bf(a.x); tile[kr][nc + 1] = f2bf(a.y);
    tile[kr][nc + 2] = f2bf(a.z); tile[kr][nc + 3] = f2bf(a.w);
    tile[kr][nc + 4] = f2bf(b.x); tile[kr][nc + 5] = f2bf(b.y);
    tile[kr][nc + 6] = f2bf(b.z); tile[kr][nc + 7] = f2bf(b.w);
    __syncthreads();
    const int nr = t >> 2, kc = (t & 3) * 8;
    union { uint4 v; u16 s[8]; } st;
#pragma unroll
    for (int i = 0; i < 8; ++i) st.s[i] = tile[kc + i][nr];
    *(uint4*)(WsT + (size_t)(n0 + nr) * D_ + k0 + kc) = st.v;
  } else if (blockIdx.x < 2560) {
    const int bid = blockIdx.x - 512;
    const int b = bid >> 9;
    const int r2 = bid & 511;
    const int d0 = (r2 & 15) * 64, s0 = (r2 >> 4) * 32;
    const int sr = t >> 3, dc = (t & 7) * 8;
    const float* p = states + ((size_t)b * S_ + s0 + sr) * D_ + d0 + dc;
    float4 a = *(const float4*)p, bb = *(const float4*)(p + 4);
    union { uint4 v; u16 s[8]; } pk;
    pk.s[0] = f2bf(a.x); pk.s[1] = f2bf(a.y); pk.s[2] = f2bf(a.z); pk.s[3] = f2bf(a.w);
    pk.s[4] = f2bf(bb.x); pk.s[5] = f2bf(bb.y); pk.s[6] = f2bf(bb.z); pk.s[7] = f2bf(bb.w);
    *(uint4*)(sbf + ((size_t)b * S_ + s0 + sr) * D_ + d0 + dc) = pk.v;
#pragma unroll
    for (int i = 0; i < 8; ++i) tile[sr][dc + i] = pk.s[i];
    __syncthreads();
    const int dr = t >> 2, sc = (t & 3) * 8;
    union { uint4 v; u16 s[8]; } st;
#pragma unroll
    for (int i = 0; i < 8; ++i) st.s[i] = tile[sc + i][dr];
    *(uint4*)(sbfT + ((size_t)b * D_ + d0 + dr) * S_ + s0 + sc) = st.v;
  } else {
    const int idx = blockIdx.x - 2560;            // 0..255
    const int c0 = (idx & 3) * 256, r0 = ((idx >> 2) & 15) * 8, k0 = (idx >> 6) * 128;
    for (int i = t; i < 8 * 128; i += 256) {
      const int rl = i >> 7, kk = i & 127;
      q[rl][kk] = query[(size_t)(r0 + rl) * H_ + k0 + kk];
    }
    __syncthreads();
    const int col = c0 + t;
    float acc[8] = {};
    for (int kk = 0; kk < 128; ++kk) {
      const float w = Wq[(size_t)(k0 + kk) * D_ + col];
#pragma unroll
      for (int r = 0; r < 8; ++r) acc[r] = fmaf(q[r][kk], w, acc[r]);
    }
    const float bb = (k0 == 0) ? bq[col] : 0.f;
#pragma unroll
    for (int r = 0; r < 8; ++r)
      atomicAdd(&qf[(size_t)(r0 + r) * D_ + col], TWO_LOG2E * (acc[r] + bb));
  }
}

__global__ __launch_bounds__(256) void f2e_sfgemm(const u16* __restrict__ A, const u16* __restrict__ BT,
                                                  u16* __restrict__ Cb) {
  __shared__ __align__(16) u16 sA[128 * 64];   // 16 KB, row stride 64 u16
  __shared__ __align__(16) u16 sB[64 * 64];    // 8 KB
  const int bm0 = blockIdx.y * 128, bn0 = blockIdx.x * 64;
  const int t = threadIdx.x;
  const int wv = t >> 6, lane = t & 63;
  const int wm = (wv >> 1) * 64, wn = (wv & 1) * 32;
  const int fm = lane & 15, fq = lane >> 4;
  const int srow = lane >> 3, sp = lane & 7;   // staging: 8 rows x 8 chunks per inst

  floatx4 acc[4][2];
  const floatx4 fz = {0.f, 0.f, 0.f, 0.f};
#pragma unroll
  for (int i = 0; i < 4; ++i) { acc[i][0] = fz; acc[i][1] = fz; }

  for (int k0 = 0; k0 < D_; k0 += 64) {
    __syncthreads();                           // prev tile reads done
#pragma unroll
    for (int j = 0; j < 4; ++j) {              // A: rows wv*32 + j*8 + srow
      const int r = wv * 32 + j * 8 + srow;
      const int c = sp ^ (r & 7);
      ld_g2l_16(A + (size_t)(bm0 + r) * D_ + k0 + c * 8, &sA[(wv * 32 + j * 8) * 64]);
    }
#pragma unroll
    for (int j = 0; j < 2; ++j) {              // B: rows wv*16 + j*8 + srow
      const int r = wv * 16 + j * 8 + srow;
      const int c = sp ^ (r & 7);
      ld_g2l_16(BT + (size_t)(bn0 + r) * D_ + k0 + c * 8, &sB[(wv * 16 + j * 8) * 64]);
    }
    __syncthreads();                           // vmcnt(0) drains the async loads
#pragma unroll
    for (int win = 0; win < 2; ++win) {
      bf16x8 af[4], bfr[2];
#pragma unroll
      for (int i = 0; i < 4; ++i) {
        const int R = wm + i * 16 + fm;
        af[i] = *(const bf16x8*)&sA[R * 64 + ((win * 4 + fq) ^ (R & 7)) * 8];
      }
#pragma unroll
      for (int j = 0; j < 2; ++j) {
        const int R = wn + j * 16 + fm;
        bfr[j] = *(const bf16x8*)&sB[R * 64 + ((win * 4 + fq) ^ (R & 7)) * 8];
      }
#pragma unroll
      for (int i = 0; i < 4; ++i)
#pragma unroll
        for (int j = 0; j < 2; ++j)
          acc[i][j] = __builtin_amdgcn_mfma_f32_16x16x32_bf16(af[i], bfr[j], acc[i][j], 0, 0, 0);
    }
  }
#pragma unroll
  for (int i = 0; i < 4; ++i)
#pragma unroll
    for (int j = 0; j < 2; ++j)
#pragma unroll
      for (int r = 0; r < 4; ++r) {
        const int row = bm0 + wm + i * 16 + fq * 4 + r;   // col=lane&15, row=quad*4+reg (m89)
        const int col = bn0 + wn + j * 16 + fm;
        Cb[(size_t)row * D_ + col] = f2bf(TWO_LOG2E * acc[i][j][r]);
      }
}

__global__ __launch_bounds__(256, 6) void f3f_align(const float* __restrict__ qf, const u16* __restrict__ sfb,
                                                    const float* __restrict__ v, float* __restrict__ alg) {
  const int wid = (blockIdx.x * 256 + threadIdx.x) >> 6;  // b*1024+s
  const int lane = threadIdx.x & 63;
  const int b = wid >> 10, s = wid & 1023;
  const int t0 = blockIdx.y * 16;
  float vr[16], sr[16];
  {
    union { uint4 v[2]; u16 s[16]; } u;
    const uint4* sp = (const uint4*)(sfb + (size_t)wid * D_ + lane * 16);
    u.v[0] = sp[0]; u.v[1] = sp[1];
    const float* vp = v + lane * 16;
#pragma unroll
    for (int c = 0; c < 4; ++c) {
      float4 w = *(const float4*)(vp + 4 * c);
      vr[4 * c + 0] = w.x; vr[4 * c + 1] = w.y; vr[4 * c + 2] = w.z; vr[4 * c + 3] = w.w;
    }
#pragma unroll
    for (int j = 0; j < 16; ++j) sr[j] = bf2f(u.s[j]);
  }
  float sum[16];
#pragma unroll
  for (int tt = 0; tt < 16; ++tt) sum[tt] = 0.f;

  const float* qbase = qf + ((size_t)(b * T_ + t0)) * D_ + lane * 16;
  for (int tt = 0; tt < 16; ++tt) {
    const float4* qp = (const float4*)(qbase + (size_t)tt * D_);
    float acc = 0.f;
#pragma unroll
    for (int c = 0; c < 4; ++c) {
      float4 q4 = qp[c];
      float xs[4] = {q4.x, q4.y, q4.z, q4.w};
#pragma unroll
      for (int u2 = 0; u2 < 4; ++u2) {
        const int j = 4 * c + u2;
        const float x = xs[u2] + sr[j];                        // prescaled by 2log2e
        const float e = __builtin_amdgcn_exp2f(x);
        acc = fmaf(vr[j], fmaf(-2.f, __builtin_amdgcn_rcpf(e + 1.f), 1.f), acc);
      }
    }
    sum[tt] = acc;
  }
#pragma unroll
  for (int off = 32; off > 0; off >>= 1)
#pragma unroll
    for (int tt = 0; tt < 16; ++tt) sum[tt] += __shfl_xor(sum[tt], off);
  if (lane == 0) {
#pragma unroll
    for (int tt = 0; tt < 16; ++tt)
      alg[((size_t)(b * T_ + t0 + tt)) * S_ + s] = sum[tt];
  }
}

__global__ __launch_bounds__(256) void f4b_softmax(const float* __restrict__ alg, const int* __restrict__ mask,
                                                   float* __restrict__ out_at, u16* __restrict__ pbf) {
  const int r = blockIdx.x;                    // b*T+t
  const int b = r >> 5, t = r & 31;
  const int tid = threadIdx.x;
  __shared__ float red[256];
  float a[4];
#pragma unroll
  for (int jj = 0; jj < 4; ++jj) {
    const int s = tid + 256 * jj;
    const float x = alg[(size_t)r * S_ + s];
    a[jj] = (mask[(size_t)b * S_ + s] != 0) ? x : -3.0e38f;
  }
  float m = fmaxf(fmaxf(a[0], a[1]), fmaxf(a[2], a[3]));
  red[tid] = m; __syncthreads();
  for (int st = 128; st > 0; st >>= 1) { if (tid < st) red[tid] = fmaxf(red[tid], red[tid + st]); __syncthreads(); }
  m = red[0]; __syncthreads();
  float e[4], lsum = 0.f;
#pragma unroll
  for (int jj = 0; jj < 4; ++jj) {
    e[jj] = (a[jj] > -1.0e38f) ? expf(a[jj] - m) : 0.f;
    lsum += e[jj];
  }
  red[tid] = lsum; __syncthreads();
  for (int st = 128; st > 0; st >>= 1) { if (tid < st) red[tid] += red[tid + st]; __syncthreads(); }
  const float rs = 1.f / red[0];
#pragma unroll
  for (int jj = 0; jj < 4; ++jj) {
    const int s = tid + 256 * jj;
    const float p = e[jj] * rs;
    out_at[((size_t)b * S_ + s) * T_ + t] = p;
    pbf[(size_t)r * S_ + s] = f2bf(p);
  }
}

__global__ __launch_bounds__(256) void f5c_context(const u16* __restrict__ pbf, const u16* __restrict__ sbfT,
                                                   float* __restrict__ ctx) {
  const int b = blockIdx.x >> 4, dt = blockIdx.x & 15;
  const int wv = threadIdx.x >> 6, lane = threadIdx.x & 63;
  const int n0 = dt * 64 + wv * 16;
  const int fm = lane & 15, fq = lane >> 4;
  const floatx4 fz = {0.f, 0.f, 0.f, 0.f};
  floatx4 acc0 = fz, acc1 = fz;
  const u16* pa0 = pbf + ((size_t)b * T_ + fm) * S_ + fq * 8;
  const u16* pa1 = pbf + ((size_t)b * T_ + 16 + fm) * S_ + fq * 8;
  const u16* pb  = sbfT + ((size_t)b * D_ + n0 + fm) * S_ + fq * 8;
#pragma unroll 4
  for (int k0 = 0; k0 < S_; k0 += 32) {
    bf16x8 a0 = *(const bf16x8*)(pa0 + k0);
    bf16x8 a1 = *(const bf16x8*)(pa1 + k0);
    bf16x8 bb = *(const bf16x8*)(pb + k0);
    acc0 = __builtin_amdgcn_mfma_f32_16x16x32_bf16(a0, bb, acc0, 0, 0, 0);
    acc1 = __builtin_amdgcn_mfma_f32_16x16x32_bf16(a1, bb, acc1, 0, 0, 0);
  }
  const int col = n0 + fm;
#pragma unroll
  for (int r = 0; r < 4; ++r) {
    ctx[((size_t)b * T_ + fq * 4 + r) * D_ + col] = acc0[r];
    ctx[((size_t)b * T_ + 16 + fq * 4 + r) * D_ + col] = acc1[r];
  }
}

__global__ __launch_bounds__(256) void f6b_outproj(const float* __restrict__ ctx, const float* __restrict__ query,
                                                   const float* __restrict__ Wc, const float* __restrict__ bc,
                                                   float* __restrict__ out_hid) {
  __shared__ float cq[16][128];
  const int c0 = blockIdx.x * 128, r0 = blockIdx.y * 16, k0 = blockIdx.z * 128;
  const int tid = threadIdx.x;
  const int cl = tid & 127, rh = tid >> 7;
  for (int i = tid; i < 16 * 128; i += 256) {
    const int rl = i >> 7, kk = i & 127;
    const int k = k0 + kk, row = r0 + rl;
    cq[rl][kk] = (k < D_) ? ctx[(size_t)row * D_ + k] : query[(size_t)row * H_ + k - D_];
  }
  __syncthreads();
  float acc[8] = {};
  for (int kk = 0; kk < 128; ++kk) {
    const float w = Wc[(size_t)(k0 + kk) * H_ + c0 + cl];
#pragma unroll
    for (int rr = 0; rr < 8; ++rr) acc[rr] = fmaf(cq[rh * 8 + rr][kk], w, acc[rr]);
  }
  const float bb = (blockIdx.z == 0) ? bc[c0 + cl] : 0.f;
#pragma unroll
  for (int rr = 0; rr < 8; ++rr)
    atomicAdd(&out_hid[(size_t)(r0 + rh * 8 + rr) * H_ + c0 + cl], acc[rr] + bb);
}

// ================= TIER-1/2 EXTRAS =================

__global__ __launch_bounds__(256) void kc_cvt(const float* __restrict__ in, u16* __restrict__ out) {
  const size_t i0 = ((size_t)blockIdx.x * 256 + threadIdx.x) * 8;
  float4 a = *(const float4*)(in + i0);
  float4 b = *(const float4*)(in + i0 + 4);
  union { uint4 v; u16 s[8]; } r;
  r.s[0] = f2bf(a.x); r.s[1] = f2bf(a.y); r.s[2] = f2bf(a.z); r.s[3] = f2bf(a.w);
  r.s[4] = f2bf(b.x); r.s[5] = f2bf(b.y); r.s[6] = f2bf(b.z); r.s[7] = f2bf(b.w);
  *(uint4*)(out + i0) = r.v;
}

__global__ __launch_bounds__(256) void f0_transpose(const float* __restrict__ Ws, u16* __restrict__ WsT) {
  __shared__ u16 tile[32][65];
  const int n0 = blockIdx.x * 64, k0 = blockIdx.y * 32;
  const int t = threadIdx.x;
  {
    const int kr = t >> 3, nc = (t & 7) * 8;
    const float* p = Ws + (size_t)(k0 + kr) * D_ + n0 + nc;
    float4 a = *(const float4*)p, b = *(const float4*)(p + 4);
    tile[kr][nc + 0] = f2bf(a.x); tile[kr][nc + 1] = f2bf(a.y);
    tile[kr][nc + 2] = f2bf(a.z); tile[kr][nc + 3] = f2bf(a.w);
    tile[kr][nc + 4] = f2bf(b.x); tile[kr][nc + 5] = f2bf(b.y);
    tile[kr][nc + 6] = f2bf(b.z); tile[kr][nc + 7] = f2bf(b.w);
  }
  __syncthreads();
  {
    const int nr = t >> 2, kc = (t & 3) * 8;
    union { uint4 v; u16 s[8]; } st;
#pragma unroll
    for (int i = 0; i < 8; ++i) st.s[i] = tile[kc + i][nr];
    *(uint4*)(WsT + (size_t)(n0 + nr) * D_ + k0 + kc) = st.v;
  }
}

__global__ __launch_bounds__(256) void f1b_qf(const float* __restrict__ query, const float* __restrict__ Wq,
                                              const float* __restrict__ bq, float* __restrict__ qf) {
  __shared__ float q[8][128];
  const int c0 = blockIdx.x * 256, r0 = blockIdx.y * 8, k0 = blockIdx.z * 128;
  const int tid = threadIdx.x;
  for (int i = tid; i < 8 * 128; i += 256) {
    const int rl = i >> 7, kk = i & 127;
    q[rl][kk] = query[(size_t)(r0 + rl) * H_ + k0 + kk];
  }
  __syncthreads();
  const int col = c0 + tid;
  float acc[8] = {};
  for (int kk = 0; kk < 128; ++kk) {
    const float w = Wq[(size_t)(k0 + kk) * D_ + col];
#pragma unroll
    for (int r = 0; r < 8; ++r) acc[r] = fmaf(q[r][kk], w, acc[r]);
  }
  const float bb = (blockIdx.z == 0) ? bq[col] : 0.f;
#pragma unroll
  for (int r = 0; r < 8; ++r)
    atomicAdd(&qf[(size_t)(r0 + r) * D_ + col], TWO_LOG2E * (acc[r] + bb));
}

__global__ __launch_bounds__(256) void f2c_sfgemm(const u16* __restrict__ A, const u16* __restrict__ BT,
                                                  u16* __restrict__ Cb) {
  __shared__ __align__(16) u16 sA[128 * 40];
  __shared__ __align__(16) u16 sB[64 * 40];
  const int bm0 = blockIdx.y * 128, bn0 = blockIdx.x * 64;
  const int t = threadIdx.x;
  const int wv = t >> 6, lane = t & 63;
  const int wm = (wv >> 1) * 64, wn = (wv & 1) * 32;
  const int fm = lane & 15, fq = lane >> 4;
  const int arow = t >> 1, akc = (t & 1) * 16;
  const int brow = t >> 2, bkc = (t & 3) * 8;
  floatx4 acc[4][2];
  const floatx4 fz = {0.f, 0.f, 0.f, 0.f};
#pragma unroll
  for (int i = 0; i < 4; ++i) { acc[i][0] = fz; acc[i][1] = fz; }
  const uint4* gA = (const uint4*)(A + (size_t)(bm0 + arow) * D_ + akc);
  const uint4* gB = (const uint4*)(BT + (size_t)(bn0 + brow) * D_ + bkc);
  for (int k0 = 0; k0 < D_; k0 += 32) {
    uint4 va0 = gA[k0 >> 3];
    uint4 va1 = gA[(k0 >> 3) + 1];
    uint4 vb = gB[k0 >> 3];
    __syncthreads();
    *(uint4*)&sA[arow * 40 + akc] = va0;
    *(uint4*)&sA[arow * 40 + akc + 8] = va1;
    *(uint4*)&sB[brow * 40 + bkc] = vb;
    __syncthreads();
    bf16x8 af[4], bfr[2];
#pragma unroll
    for (int i = 0; i < 4; ++i) af[i] = *(const bf16x8*)&sA[(wm + i * 16 + fm) * 40 + fq * 8];
#pragma unroll
    for (int j = 0; j < 2; ++j) bfr[j] = *(const bf16x8*)&sB[(wn + j * 16 + fm) * 40 + fq * 8];
#pragma unroll
    for (int i = 0; i < 4; ++i)
#pragma unroll
      for (int j = 0; j < 2; ++j)
        acc[i][j] = __builtin_amdgcn_mfma_f32_16x16x32_bf16(af[i], bfr[j], acc[i][j], 0, 0, 0);
  }
#pragma unroll
  for (int i = 0; i < 4; ++i)
#pragma unroll
    for (int j = 0; j < 2; ++j)
#pragma unroll
      for (int r = 0; r < 4; ++r) {
        const int row = bm0 + wm + i * 16 + fq * 4 + r;
        const int col = bn0 + wn + j * 16 + fm;
        Cb[(size_t)row * D_ + col] = f2bf(TWO_LOG2E * acc[i][j][r]);
      }
}

__global__ __launch_bounds__(256) void f2d_sfgemm(const float* __restrict__ A, const u16* __restrict__ BT,
                                                  u16* __restrict__ Cb) {
  __shared__ __align__(16) u16 sA[128 * 40];
  __shared__ __align__(16) u16 sB[64 * 40];
  const int bm0 = blockIdx.y * 128, bn0 = blockIdx.x * 64;
  const int t = threadIdx.x;
  const int wv = t >> 6, lane = t & 63;
  const int wm = (wv >> 1) * 64, wn = (wv & 1) * 32;
  const int fm = lane & 15, fq = lane >> 4;
  const int arow = t >> 1, akc = (t & 1) * 16;
  const int brow = t >> 2, bkc = (t & 3) * 8;
  floatx4 acc[4][2];
  const floatx4 fz = {0.f, 0.f, 0.f, 0.f};
#pragma unroll
  for (int i = 0; i < 4; ++i) { acc[i][0] = fz; acc[i][1] = fz; }
  const float* gA = A + (size_t)(bm0 + arow) * D_ + akc;
  const uint4* gB = (const uint4*)(BT + (size_t)(bn0 + brow) * D_ + bkc);
  for (int k0 = 0; k0 < D_; k0 += 32) {
    float4 a0 = *(const float4*)(gA + k0);
    float4 a1 = *(const float4*)(gA + k0 + 4);
    float4 a2 = *(const float4*)(gA + k0 + 8);
    float4 a3 = *(const float4*)(gA + k0 + 12);
    uint4 vb = gB[k0 >> 3];
    union { uint4 v[2]; u16 s[16]; } pa;
    pa.s[0] = f2bf(a0.x); pa.s[1] = f2bf(a0.y); pa.s[2] = f2bf(a0.z); pa.s[3] = f2bf(a0.w);
    pa.s[4] = f2bf(a1.x); pa.s[5] = f2bf(a1.y); pa.s[6] = f2bf(a1.z); pa.s[7] = f2bf(a1.w);
    pa.s[8] = f2bf(a2.x); pa.s[9] = f2bf(a2.y); pa.s[10] = f2bf(a2.z); pa.s[11] = f2bf(a2.w);
    pa.s[12] = f2bf(a3.x); pa.s[13] = f2bf(a3.y); pa.s[14] = f2bf(a3.z); pa.s[15] = f2bf(a3.w);
    __syncthreads();
    *(uint4*)&sA[arow * 40 + akc] = pa.v[0];
    *(uint4*)&sA[arow * 40 + akc + 8] = pa.v[1];
    *(uint4*)&sB[brow * 40 + bkc] = vb;
    __syncthreads();
    bf16x8 af[4], bfr[2];
#pragma unroll
    for (int i = 0; i < 4; ++i) af[i] = *(const bf16x8*)&sA[(wm + i * 16 + fm) * 40 + fq * 8];
#pragma unroll
    for (int j = 0; j < 2; ++j) bfr[j] = *(const bf16x8*)&sB[(wn + j * 16 + fm) * 40 + fq * 8];
#pragma unroll
    for (int i = 0; i < 4; ++i)
#pragma unroll
      for (int j = 0; j < 2; ++j)
        acc[i][j] = __builtin_amdgcn_mfma_f32_16x16x32_bf16(af[i], bfr[j], acc[i][j], 0, 0, 0);
  }
#pragma unroll
  for (int i = 0; i < 4; ++i)
#pragma unroll
    for (int j = 0; j < 2; ++j)
#pragma unroll
      for (int r = 0; r < 4; ++r) {
        const int row = bm0 + wm + i * 16 + fq * 4 + r;
        const int col = bn0 + wn + j * 16 + fm;
        Cb[(size_t)row * D_ + col] = f2bf(TWO_LOG2E * acc[i][j][r]);
      }
}

__global__ __launch_bounds__(256) void f4_softmax(const float* __restrict__ alg, const int* __restrict__ mask,
                                                  float* __restrict__ attn) {
  const int r = blockIdx.x;
  const int b = r >> 5;
  const int tid = threadIdx.x;
  __shared__ float red[256];
  float a[4];
#pragma unroll
  for (int jj = 0; jj < 4; ++jj) {
    const int s = tid + 256 * jj;
    const float x = alg[(size_t)r * S_ + s];
    a[jj] = (mask[(size_t)b * S_ + s] != 0) ? x : -3.0e38f;
  }
  float m = fmaxf(fmaxf(a[0], a[1]), fmaxf(a[2], a[3]));
  red[tid] = m; __syncthreads();
  for (int st = 128; st > 0; st >>= 1) { if (tid < st) red[tid] = fmaxf(red[tid], red[tid + st]); __syncthreads(); }
  m = red[0]; __syncthreads();
  float e[4], lsum = 0.f;
#pragma unroll
  for (int jj = 0; jj < 4; ++jj) {
    e[jj] = (a[jj] > -1.0e38f) ? expf(a[jj] - m) : 0.f;
    lsum += e[jj];
  }
  red[tid] = lsum; __syncthreads();
  for (int st = 128; st > 0; st >>= 1) { if (tid < st) red[tid] += red[tid + st]; __syncthreads(); }
  const float rs = 1.f / red[0];
#pragma unroll
  for (int jj = 0; jj < 4; ++jj)
    attn[(size_t)r * S_ + tid + 256 * jj] = e[jj] * rs;
}

__global__ __launch_bounds__(256) void f5b_context(const float* __restrict__ attn, const u16* __restrict__ sbf,
                                                   float* __restrict__ ctx, float* __restrict__ out_at) {
  __shared__ float at[16][64];
  const int s0 = blockIdx.x * 64, t0 = blockIdx.y * 16, b = blockIdx.z;
  const int tid = threadIdx.x;
  for (int i = tid; i < 16 * 64; i += 256) {
    const int tl = i >> 6, sl = i & 63;
    at[tl][sl] = attn[(size_t)(b * T_ + t0 + tl) * S_ + s0 + sl];
  }
  __syncthreads();
  for (int i = tid; i < 64 * 16; i += 256) {
    const int sl = i >> 4, tl = i & 15;
    out_at[((size_t)b * S_ + s0 + sl) * T_ + t0 + tl] = at[tl][sl];
  }
  float acc[16][4] = {};
  for (int sl = 0; sl < 64; ++sl) {
    const u16* srow = sbf + ((size_t)b * S_ + s0 + sl) * D_ + tid;
    float sv[4];
#pragma unroll
    for (int jj = 0; jj < 4; ++jj) sv[jj] = bf2f(srow[256 * jj]);
#pragma unroll
    for (int tl = 0; tl < 16; ++tl) {
      const float w = at[tl][sl];
#pragma unroll
      for (int jj = 0; jj < 4; ++jj) acc[tl][jj] = fmaf(w, sv[jj], acc[tl][jj]);
    }
  }
#pragma unroll
  for (int tl = 0; tl < 16; ++tl)
#pragma unroll
    for (int jj = 0; jj < 4; ++jj)
      atomicAdd(&ctx[(size_t)(b * T_ + t0 + tl) * D_ + tid + 256 * jj], acc[tl][jj]);
}

__global__ __launch_bounds__(256) void f5_context(const float* __restrict__ attn, const float* __restrict__ states,
                                                  float* __restrict__ ctx, float* __restrict__ out_at) {
  __shared__ float at[16][64];
  const int s0 = blockIdx.x * 64, t0 = blockIdx.y * 16, b = blockIdx.z;
  const int tid = threadIdx.x;
  for (int i = tid; i < 16 * 64; i += 256) {
    const int tl = i >> 6, sl = i & 63;
    at[tl][sl] = attn[(size_t)(b * T_ + t0 + tl) * S_ + s0 + sl];
  }
  __syncthreads();
  for (int i = tid; i < 64 * 16; i += 256) {
    const int sl = i >> 4, tl = i & 15;
    out_at[((size_t)b * S_ + s0 + sl) * T_ + t0 + tl] = at[tl][sl];
  }
  float acc[16][4] = {};
  for (int sl = 0; sl < 64; ++sl) {
    const float* srow = states + ((size_t)b * S_ + s0 + sl) * D_ + tid;
    float sv[4];
#pragma unroll
    for (int jj = 0; jj < 4; ++jj) sv[jj] = srow[256 * jj];
#pragma unroll
    for (int tl = 0; tl < 16; ++tl) {
      const float w = at[tl][sl];
#pragma unroll
      for (int jj = 0; jj < 4; ++jj) acc[tl][jj] = fmaf(w, sv[jj], acc[tl][jj]);
    }
  }
#pragma unroll
  for (int tl = 0; tl < 16; ++tl)
#pragma unroll
    for (int jj = 0; jj < 4; ++jj)
      atomicAdd(&ctx[(size_t)(b * T_ + t0 + tl) * D_ + tid + 256 * jj], acc[tl][jj]);
}

// ================= FALLBACK (round-7, passing) =================

__global__ __launch_bounds__(256) void k1_qf(const float* __restrict__ query, const float* __restrict__ Wq,
                                             const float* __restrict__ bq, float* __restrict__ qf) {
  const int r = blockIdx.x;
  const int tid = threadIdx.x;
  __shared__ float q[H_];
  for (int i = tid; i < H_; i += 256) q[i] = query[(size_t)r * H_ + i];
  __syncthreads();
#pragma unroll
  for (int jj = 0; jj < 4; ++jj) {
    const int j = tid + 256 * jj;
    float acc = bq[j];
    for (int k = 0; k < H_; ++k) acc = fmaf(q[k], Wq[(size_t)k * D_ + j], acc);
    qf[(size_t)r * D_ + j] = acc;
  }
}

__global__ __launch_bounds__(256) void k23_align(const float* __restrict__ states, const float* __restrict__ Ws,
                                                 const float* __restrict__ v, const float* __restrict__ qf,
                                                 float* __restrict__ alg) {
  const int b = blockIdx.x >> 6;
  const int s0 = (blockIdx.x & 63) * 16;
  const int tid = threadIdx.x, lane = tid & 63, wv = tid >> 6;
  __shared__ u16 stL[16 * D_];
  __shared__ float vvL[D_];
  __shared__ float red[16 * 4];
  for (int i = tid; i < 16 * D_; i += 256) {
    const int row = i >> 10, col = i & (D_ - 1);
    stL[i] = f2bf(states[((size_t)b * S_ + s0 + row) * D_ + col]);
  }
  for (int i = tid; i < D_; i += 256) vvL[i] = v[i];
  __syncthreads();
  float acc[64];
#pragma unroll
  for (int i = 0; i < 64; ++i) acc[i] = 0.f;
#pragma unroll 4
  for (int k = 0; k < D_; ++k) {
    float wsv[4];
#pragma unroll
    for (int jj = 0; jj < 4; ++jj) wsv[jj] = Ws[(size_t)k * D_ + tid + 256 * jj];
#pragma unroll
    for (int i = 0; i < 16; ++i) {
      const float sv = bf2f(stL[i * D_ + k]);
#pragma unroll
      for (int jj = 0; jj < 4; ++jj) acc[i * 4 + jj] = fmaf(sv, wsv[jj], acc[i * 4 + jj]);
    }
  }
  for (int t = 0; t < T_; ++t) {
    float qv[4];
#pragma unroll
    for (int jj = 0; jj < 4; ++jj) qv[jj] = qf[((size_t)b * T_ + t) * D_ + tid + 256 * jj];
    float part[16];
#pragma unroll
    for (int i = 0; i < 16; ++i) {
      float p = 0.f;
#pragma unroll
      for (int jj = 0; jj < 4; ++jj)
        p = fmaf(vvL[tid + 256 * jj], tanhf(qv[jj] + acc[i * 4 + jj]), p);
      part[i] = p;
    }
#pragma unroll
    for (int i = 0; i < 16; ++i) {
      float x = part[i];
#pragma unroll
      for (int off = 32; off > 0; off >>= 1) x += __shfl_xor(x, off);
      if (lane == 0) red[i * 4 + wv] = x;
    }
    __syncthreads();
    if (tid < 16)
      alg[((size_t)b * T_ + t) * S_ + s0 + tid] =
          red[tid * 4 + 0] + red[tid * 4 + 1] + red[tid * 4 + 2] + red[tid * 4 + 3];
    __syncthreads();
  }
}

__global__ __launch_bounds__(256) void k4_softmax(const float* __restrict__ alg, const int* __restrict__ mask,
                                                  float* __restrict__ attn) {
  const int r = blockIdx.x;
  const int b = r >> 5;
  const int tid = threadIdx.x;
  __shared__ float red[256];
  float a[4];
#pragma unroll
  for (int jj = 0; jj < 4; ++jj) {
    const int s = tid + 256 * jj;
    const float x = alg[(size_t)r * S_ + s];
    a[jj] = (mask[(size_t)b * S_ + s] != 0) ? x : -3.0e38f;
  }
  float m = fmaxf(fmaxf(a[0], a[1]), fmaxf(a[2], a[3]));
  red[tid] = m; __syncthreads();
  for (int st = 128; st > 0; st >>= 1) { if (tid < st) red[tid] = fmaxf(red[tid], red[tid + st]); __syncthreads(); }
  m = red[0]; __syncthreads();
  float e[4], lsum = 0.f;
#pragma unroll
  for (int jj = 0; jj < 4; ++jj) {
    e[jj] = (a[jj] > -1.0e38f) ? expf(a[jj] - m) : 0.f;
    lsum += e[jj];
  }
  red[tid] = lsum; __syncthreads();
  for (int st = 128; st > 0; st >>= 1) { if (tid < st) red[tid] += red[tid + st]; __syncthreads(); }
  const float rs = 1.f / red[0];
#pragma unroll
  for (int jj = 0; jj < 4; ++jj)
    attn[(size_t)r * S_ + tid + 256 * jj] = e[jj] * rs;
}

__global__ __launch_bounds__(256) void k56_ctx_proj(const float* __restrict__ attn, const float* __restrict__ states,
                                                    const float* __restrict__ query, const float* __restrict__ Wc,
                                                    const float* __restrict__ bc,
                                                    float* __restrict__ out_ctx, float* __restrict__ out_hid,
                                                    float* __restrict__ out_at) {
  const int r = blockIdx.x;
  const int b = r >> 5, t = r & (T_ - 1);
  const int tid = threadIdx.x;
  __shared__ float pr[S_];
  __shared__ float cq[D_ + H_];
  for (int s = tid; s < S_; s += 256) pr[s] = attn[(size_t)r * S_ + s];
  __syncthreads();
  for (int s = tid; s < S_; s += 256) out_at[((size_t)b * S_ + s) * T_ + t] = pr[s];
  float acc[4] = {0.f, 0.f, 0.f, 0.f};
  for (int s = 0; s < S_; ++s) {
    const float w = pr[s];
    const float* srow = states + ((size_t)b * S_ + s) * D_ + tid;
#pragma unroll
    for (int jj = 0; jj < 4; ++jj) acc[jj] = fmaf(w, srow[256 * jj], acc[jj]);
  }
#pragma unroll
  for (int jj = 0; jj < 4; ++jj) {
    cq[tid + 256 * jj] = acc[jj];
    out_ctx[(size_t)r * D_ + tid + 256 * jj] = acc[jj];
  }
  for (int i = tid; i < H_; i += 256) cq[D_ + i] = query[(size_t)r * H_ + i];
  __syncthreads();
#pragma unroll
  for (int jj = 0; jj < 2; ++jj) {
    const int n = tid + 256 * jj;
    float h = bc[n];
    for (int k = 0; k < D_ + H_; ++k) h = fmaf(cq[k], Wc[(size_t)k * H_ + n], h);
    out_hid[(size_t)r * H_ + n] = h;
  }
}

extern "C" void kernel_launch(void* const* d_in, const int* in_sizes, int n_in,
                              void* d_out, int out_size, void* d_ws, size_t ws_size,
                              hipStream_t stream) {
  const float* query  = (const float*)d_in[0];
  const float* states = (const float*)d_in[1];
  const int*   mask   = (const int*)d_in[2];
  const float* Wq     = (const float*)d_in[3];
  const float* bq     = (const float*)d_in[4];
  const float* Ws     = (const float*)d_in[5];
  const float* v      = (const float*)d_in[6];
  const float* Wc     = (const float*)d_in[7];
  const float* bc     = (const float*)d_in[8];

  float* A  = (float*)d_out;               // ctx(final)
  float* Bh = A + (size_t)BT_ * D_;        // hidden
  float* C  = Bh + (size_t)BT_ * H_;       // attn_t

  char* ws = (char*)d_ws;
  u16*   sfb  = (u16*)(ws + 0);
  u16*   WsT  = (u16*)(ws + 8388608);
  float* alg  = (float*)(ws + 10485760);
  u16*   sbf  = (u16*)(ws + 11010048);
  u16*   sbfT = (u16*)(ws + 19398656);
  u16*   pbf  = (u16*)(ws + 27787264);

  const size_t WS_T1 = 11010048;
  const size_t WS_T2 = 19398656;
  const size_t WS_T3 = 28049408;
  const size_t WS_T4 = 36962816;   // + Es16 (8.4MB) + Eq (512KB) + rsum (512B)

  if (ws_size >= WS_T4) {
    // ---------- tier 4 ----------
    u16*   Es16 = (u16*)(ws + 28049408);   // 8.4 MB bf16 exp2(scale*sf)
    float* Eq4  = (float*)(ws + 36438016); // 512 KB fp32 exp2(scale*qf)
    float* rsum = (float*)(ws + 36962304); // 512 B fp32 softmax row sums
    prep_fused7<<<2944, 256, 0, stream>>>(states, Ws, query, Wq, bq, Wc, bc,
                                          sbf, sbfT, WsT, Eq4, rsum, Bh);
    f2j_sfgemm<<<dim3(16, 32), 256, 0, stream>>>(sbf, WsT, Es16);
    f3k_align<<<256, 256, 0, stream>>>(Eq4, Es16, v, mask, pbf, rsum);
    f5e_context<<<256, 256, 0, stream>>>(pbf, sbfT, rsum, A, C);
    f6c_outproj<<<dim3(4, 8, 8), 256, 0, stream>>>(A, Wc, Bh);
  } else if (ws_size >= WS_T3) {
    // ---------- tier 3 ----------
    (void)hipMemsetAsync(A, 0, (size_t)(BT_ * D_ + BT_ * H_) * 4, stream);  // qf + hidden zero
    prep_fused<<<2816, 256, 0, stream>>>(states, Ws, query, Wq, bq, sbf, sbfT, WsT, A);
    f2e_sfgemm<<<dim3(16, 32), 256, 0, stream>>>(sbf, WsT, sfb);
    f3f_align<<<dim3(1024, 2), 256, 0, stream>>>(A, sfb, v, alg);
    f4b_softmax<<<BT_, 256, 0, stream>>>(alg, mask, C, pbf);
    f5c_context<<<64, 256, 0, stream>>>(pbf, sbfT, A);
    f6b_outproj<<<dim3(4, 8, 12), 256, 0, stream>>>(A, query, Wc, bc, Bh);
  } else if (ws_size >= WS_T1) {
    // ---------- tier 1/2 ----------
    float* attn = alg;
    (void)hipMemsetAsync(A, 0, (size_t)(BT_ * D_ + BT_ * H_) * 4, stream);
    f1b_qf<<<dim3(4, 16, 4), 256, 0, stream>>>(query, Wq, bq, A);
    f0_transpose<<<dim3(16, 32), 256, 0, stream>>>(Ws, WsT);
    const int tier2 = (ws_size >= WS_T2);
    if (tier2) {
      kc_cvt<<<2048, 256, 0, stream>>>(states, sbf);
      f2c_sfgemm<<<dim3(16, 32), 256, 0, stream>>>(sbf, WsT, sfb);
    } else {
      f2d_sfgemm<<<dim3(16, 32), 256, 0, stream>>>(states, WsT, sfb);
    }
    f3f_align<<<dim3(1024, 2), 256, 0, stream>>>(A, sfb, v, C);
    (void)hipMemsetAsync(A, 0, (size_t)BT_ * D_ * 4, stream);
    f4_softmax<<<BT_, 256, 0, stream>>>(C, mask, attn);
    if (tier2)
      f5b_context<<<dim3(16, 2, 4), 256, 0, stream>>>(attn, sbf, A, C);
    else
      f5_context<<<dim3(16, 2, 4), 256, 0, stream>>>(attn, states, A, C);
    f6b_outproj<<<dim3(4, 8, 12), 256, 0, stream>>>(A, query, Wc, bc, Bh);
  } else {
    // ---------- fallback ----------
    k1_qf<<<BT_, 256, 0, stream>>>(query, Wq, bq, A);
    k23_align<<<B_ * (S_ / 16), 256, 0, stream>>>(states, Ws, v, A, C);
    k4_softmax<<<BT_, 256, 0, stream>>>(C, mask, A);
    k56_ctx_proj<<<BT_, 256, 0, stream>>>(A, states, query, Wc, bc, A, Bh, C);
  }
}

// Round 8
// 166.101 us; speedup vs baseline: 1.1087x; 1.1087x over previous
//
#include <hip/hip_runtime.h>
#include <math.h>

// Bahdanau additive attention. B=4, T=32, S=1024, H=512, D=2H=1024.
// Inputs fp32 (mask int32), OUTPUT fp32 flat:
//   context (4,32,1024) | hidden (4,32,512) | attn_t (4,1024,32)
// Round 23: REVERT to R21 (measured 164.5us best). R22's internal-split-K
// inflated every prep block's LDS to 16KB (occupancy 20%, prep 56-62us,
// BW 525GB/s) -- prep's 2048 states blocks are occupancy/BW-bound; keep
// their LDS at ~8.3KB. Structure: heavy GEMM blocks FIRST (qf split-K ->
// qfp partials, hidQ split-K atomics -> Bh), light transpose blocks
// backfill; f2i = dbuf GEMM + Eq prologue; f3k = 4 s/wave no-max softmax;
// f5e = 256-block ctx with folded normalization; f6c = ctx-only split-K.
// Chain: memset(Bh) + prep(2944) + f2i(512) + f3k(256) + f5e(256) + f6c(256).
// d_out overlay: A[0,131072): ctx(final)  B[131072,196608): hidden(memset)
//                C[196608,327680): attn_t(final)

typedef unsigned short u16;
typedef __bf16 bf16x8 __attribute__((ext_vector_type(8)));
typedef float floatx4 __attribute__((ext_vector_type(4)));

#define B_ 4
#define T_ 32
#define S_ 1024
#define H_ 512
#define D_ 1024
#define BT_ 128
#define TWO_LOG2E 2.8853900817779268f   // tanh(y) = 1 - 2/(exp2(2*log2e*y)+1)
#define LOG2E 1.4426950408889634f

__device__ __forceinline__ float bf2f(u16 u) {
  unsigned int i = ((unsigned int)u) << 16;
  return __builtin_bit_cast(float, i);
}
__device__ __forceinline__ u16 f2bf(float f) {
  unsigned int i = __builtin_bit_cast(unsigned int, f);
  i += 0x7fffu + ((i >> 16) & 1u);  // RNE
  return (u16)(i >> 16);
}
__device__ __forceinline__ void ld_g2l_16(const u16* g, u16* l) {
  __builtin_amdgcn_global_load_lds((__attribute__((address_space(1))) void*)(u16*)g,
                                   (__attribute__((address_space(3))) void*)l, 16, 0, 0);
}

// ================= TIER-4 KERNELS =================

// ---- PREP6: heavy blocks FIRST so light blocks backfill (no serial tail).
//      [0,256)    qf split-K -> qfp partials (plain stores);
//      [256,384)  hidden query-part split-K atomics -> Bh (+bc on slice 0);
//      [384,896)  Ws^T -> WsT bf16 (block 384 zeroes rowsum);
//      [896,2944) states -> sbf + sbfT.
__global__ __launch_bounds__(256) void prep_fused6(const float* __restrict__ states, const float* __restrict__ Ws,
                                                   const float* __restrict__ query, const float* __restrict__ Wq,
                                                   const float* __restrict__ bq,
                                                   const float* __restrict__ Wc, const float* __restrict__ bc,
                                                   u16* __restrict__ sbf, u16* __restrict__ sbfT,
                                                   u16* __restrict__ WsT, float* __restrict__ qfp,
                                                   float* __restrict__ rowsum, float* __restrict__ hid) {
  __shared__ u16 tile[32][65];
  __shared__ float q[8][128];
  const int t = threadIdx.x;
  if (blockIdx.x < 256) {
    const int idx = blockIdx.x;                   // 0..255: qf split-K partials
    const int c0 = (idx & 3) * 256, r0 = ((idx >> 2) & 15) * 8, ks = idx >> 6;
    const int k0 = ks * 128;
    for (int i = t; i < 8 * 128; i += 256) {
      const int rl = i >> 7, kk = i & 127;
      q[rl][kk] = query[(size_t)(r0 + rl) * H_ + k0 + kk];
    }
    __syncthreads();
    const int col = c0 + t;
    float acc[8] = {};
    for (int kk = 0; kk < 128; ++kk) {
      const float w = Wq[(size_t)(k0 + kk) * D_ + col];
#pragma unroll
      for (int r = 0; r < 8; ++r) acc[r] = fmaf(q[r][kk], w, acc[r]);
    }
    const float bb = (ks == 0) ? bq[col] : 0.f;
    float* dst = qfp + (size_t)ks * (BT_ * D_);
#pragma unroll
    for (int r = 0; r < 8; ++r)
      dst[(size_t)(r0 + r) * D_ + col] = TWO_LOG2E * (acc[r] + bb);
  } else if (blockIdx.x < 384) {
    const int idx = blockIdx.x - 256;             // 0..127: hidden query-part
    const int c0 = (idx & 1) * 256, r0 = ((idx >> 1) & 15) * 8, ks = idx >> 5;
    const int k0 = ks * 128;
    for (int i = t; i < 8 * 128; i += 256) {
      const int rl = i >> 7, kk = i & 127;
      q[rl][kk] = query[(size_t)(r0 + rl) * H_ + k0 + kk];
    }
    __syncthreads();
    const int col = c0 + t;
    float acc[8] = {};
    for (int kk = 0; kk < 128; ++kk) {
      const float w = Wc[(size_t)(D_ + k0 + kk) * H_ + col];
#pragma unroll
      for (int r = 0; r < 8; ++r) acc[r] = fmaf(q[r][kk], w, acc[r]);
    }
    const float bb = (ks == 0) ? bc[col] : 0.f;
#pragma unroll
    for (int r = 0; r < 8; ++r)
      atomicAdd(&hid[(size_t)(r0 + r) * H_ + col], acc[r] + bb);
  } else if (blockIdx.x < 896) {
    const int bid = blockIdx.x - 384;             // 0..511: Ws transpose
    if (bid == 0 && t < 128) rowsum[t] = 0.f;     // zero rsum (read only by f3k)
    const int n0 = (bid & 15) * 64, k0 = (bid >> 4) * 32;
    const int kr = t >> 3, nc = (t & 7) * 8;
    const float* p = Ws + (size_t)(k0 + kr) * D_ + n0 + nc;
    float4 a = *(const float4*)p, b = *(const float4*)(p + 4);
    tile[kr][nc + 0] = f2bf(a.x); tile[kr][nc + 1] = f2bf(a.y);
    tile[kr][nc + 2] = f2bf(a.z); tile[kr][nc + 3] = f2bf(a.w);
    tile[kr][nc + 4] = f2bf(b.x); tile[kr][nc + 5] = f2bf(b.y);
    tile[kr][nc + 6] = f2bf(b.z); tile[kr][nc + 7] = f2bf(b.w);
    __syncthreads();
    const int nr = t >> 2, kc = (t & 3) * 8;
    union { uint4 v; u16 s[8]; } st;
#pragma unroll
    for (int i = 0; i < 8; ++i) st.s[i] = tile[kc + i][nr];
    *(uint4*)(WsT + (size_t)(n0 + nr) * D_ + k0 + kc) = st.v;
  } else {
    const int bid = blockIdx.x - 896;             // 0..2047: states cvt+transpose
    const int b = bid >> 9;
    const int r2 = bid & 511;
    const int d0 = (r2 & 15) * 64, s0 = (r2 >> 4) * 32;
    const int sr = t >> 3, dc = (t & 7) * 8;
    const float* p = states + ((size_t)b * S_ + s0 + sr) * D_ + d0 + dc;
    float4 a = *(const float4*)p, bb = *(const float4*)(p + 4);
    union { uint4 v; u16 s[8]; } pk;
    pk.s[0] = f2bf(a.x); pk.s[1] = f2bf(a.y); pk.s[2] = f2bf(a.z); pk.s[3] = f2bf(a.w);
    pk.s[4] = f2bf(bb.x); pk.s[5] = f2bf(bb.y); pk.s[6] = f2bf(bb.z); pk.s[7] = f2bf(bb.w);
    *(uint4*)(sbf + ((size_t)b * S_ + s0 + sr) * D_ + d0 + dc) = pk.v;
#pragma unroll
    for (int i = 0; i < 8; ++i) tile[sr][dc + i] = pk.s[i];
    __syncthreads();
    const int dr = t >> 2, sc = (t & 3) * 8;
    union { uint4 v; u16 s[8]; } st;
#pragma unroll
    for (int i = 0; i < 8; ++i) st.s[i] = tile[sc + i][dr];
    *(uint4*)(sbfT + ((size_t)b * D_ + d0 + dr) * S_ + s0 + sc) = st.v;
  }
}

// ---- F2i: Es = bf16(exp2(2log2e*(sbf @ Ws))); prologue Eq = exp2(sum qfp[ks]).
// Double-buffered global_load_lds prefetch, counted vmcnt(6), raw s_barrier;
// XOR-swizzled LDS reads.
__device__ __forceinline__ void f2f_stage(const u16* __restrict__ A, const u16* __restrict__ BT,
                                          u16* sAb, u16* sBb, int bm0, int bn0, int k0,
                                          int wv, int srow, int sp) {
#pragma unroll
  for (int j = 0; j < 4; ++j) {                  // A: rows wv*32 + j*8 + srow
    const int r = wv * 32 + j * 8 + srow;
    const int c = sp ^ (r & 7);
    ld_g2l_16(A + (size_t)(bm0 + r) * D_ + k0 + c * 8, sAb + (wv * 32 + j * 8) * 64);
  }
#pragma unroll
  for (int j = 0; j < 2; ++j) {                  // B: rows wv*16 + j*8 + srow
    const int r = wv * 16 + j * 8 + srow;
    const int c = sp ^ (r & 7);
    ld_g2l_16(BT + (size_t)(bn0 + r) * D_ + k0 + c * 8, sBb + (wv * 16 + j * 8) * 64);
  }
}

__device__ __forceinline__ void f2f_compute(const u16* sAb, const u16* sBb,
                                            int wm, int wn, int fm, int fq, floatx4 (&acc)[4][2]) {
#pragma unroll
  for (int win = 0; win < 2; ++win) {
    bf16x8 af[4], bfr[2];
#pragma unroll
    for (int i = 0; i < 4; ++i) {
      const int R = wm + i * 16 + fm;
      af[i] = *(const bf16x8*)&sAb[R * 64 + ((win * 4 + fq) ^ (R & 7)) * 8];
    }
#pragma unroll
    for (int j = 0; j < 2; ++j) {
      const int R = wn + j * 16 + fm;
      bfr[j] = *(const bf16x8*)&sBb[R * 64 + ((win * 4 + fq) ^ (R & 7)) * 8];
    }
#pragma unroll
    for (int i = 0; i < 4; ++i)
#pragma unroll
      for (int j = 0; j < 2; ++j)
        acc[i][j] = __builtin_amdgcn_mfma_f32_16x16x32_bf16(af[i], bfr[j], acc[i][j], 0, 0, 0);
  }
}

__global__ __launch_bounds__(256) void f2i_sfgemm(const u16* __restrict__ A, const u16* __restrict__ BT,
                                                  const float* __restrict__ qfp, float* __restrict__ Eq,
                                                  u16* __restrict__ Es) {
  __shared__ __align__(16) u16 sA[2][128 * 64];  // 2 x 16 KB
  __shared__ __align__(16) u16 sB[2][64 * 64];   // 2 x 8 KB
  const int bm0 = blockIdx.y * 128, bn0 = blockIdx.x * 64;
  const int t = threadIdx.x;
  const int wv = t >> 6, lane = t & 63;
  const int wm = (wv >> 1) * 64, wn = (wv & 1) * 32;
  const int fm = lane & 15, fq = lane >> 4;
  const int srow = lane >> 3, sp = lane & 7;

  // Eq transform: 512 blocks x 256 threads = 131072 = BT_*D_ elems.
  {
    const int bid = blockIdx.y * 16 + blockIdx.x;
    const int idx = bid * 256 + t;
    const float s = qfp[idx] + qfp[BT_ * D_ + idx] +
                    qfp[2 * BT_ * D_ + idx] + qfp[3 * BT_ * D_ + idx];
    Eq[idx] = __builtin_amdgcn_exp2f(s);         // prescaled by 2log2e
  }

  floatx4 acc[4][2];
  const floatx4 fz = {0.f, 0.f, 0.f, 0.f};
#pragma unroll
  for (int i = 0; i < 4; ++i) { acc[i][0] = fz; acc[i][1] = fz; }

  f2f_stage(A, BT, sA[0], sB[0], bm0, bn0, 0, wv, srow, sp);
#pragma unroll 1
  for (int k0 = 0; k0 < D_; k0 += 128) {
    // even phase: compute buf0, prefetch buf1(k0+64)
    f2f_stage(A, BT, sA[1], sB[1], bm0, bn0, k0 + 64, wv, srow, sp);
    asm volatile("s_waitcnt vmcnt(6)" ::: "memory");   // buf0's 6 loads landed
    __builtin_amdgcn_s_barrier();
    f2f_compute(sA[0], sB[0], wm, wn, fm, fq, acc);
    __builtin_amdgcn_s_barrier();                      // all waves done reading buf0
    // odd phase: compute buf1, prefetch buf0(k0+128)
    if (k0 + 128 < D_) {
      f2f_stage(A, BT, sA[0], sB[0], bm0, bn0, k0 + 128, wv, srow, sp);
      asm volatile("s_waitcnt vmcnt(6)" ::: "memory"); // buf1's 6 loads landed
    } else {
      asm volatile("s_waitcnt vmcnt(0)" ::: "memory");
    }
    __builtin_amdgcn_s_barrier();
    f2f_compute(sA[1], sB[1], wm, wn, fm, fq, acc);
    __builtin_amdgcn_s_barrier();
  }
#pragma unroll
  for (int i = 0; i < 4; ++i)
#pragma unroll
    for (int j = 0; j < 2; ++j)
#pragma unroll
      for (int r = 0; r < 4; ++r) {
        const int row = bm0 + wm + i * 16 + fq * 4 + r;   // col=lane&15, row=quad*4+reg (m89)
        const int col = bn0 + wn + j * 16 + fm;
        Es[(size_t)row * D_ + col] = f2bf(__builtin_amdgcn_exp2f(TWO_LOG2E * acc[i][j][r]));
      }
}

// ---- F3k: E = exp(alg), alg = sumv + sum_j vm2_j*rcp(fma(Eq,Es,1)).
// No-max softmax. 4 s-values per wave: Eq L2 re-read 128MB, 4x rcp ILP.
// Four E bf16 packed as one uint2 store. 256 blocks (1024 waves).
__global__ __launch_bounds__(256) void f3k_align(const float* __restrict__ Eq, const u16* __restrict__ Es,
                                                 const float* __restrict__ v, const int* __restrict__ mask,
                                                 u16* __restrict__ pbf, float* __restrict__ rowsum) {
  __shared__ float red[32][4];
  const int wv = threadIdx.x >> 6, lane = threadIdx.x & 63;
  const int w = blockIdx.x * 4 + wv;                      // 0..1023
  const int b = w >> 8;                                   // 256 waves per batch
  const int s0 = (w & 255) * 4;
  const int m0 = mask[(size_t)b * S_ + s0 + 0];
  const int m1 = mask[(size_t)b * S_ + s0 + 1];
  const int m2 = mask[(size_t)b * S_ + s0 + 2];
  const int m3 = mask[(size_t)b * S_ + s0 + 3];
  float vm2[16], es0[16], es1[16], es2[16], es3[16];
  float sumv = 0.f;
  {
    union { uint4 u[2]; u16 h[16]; } u0, u1, u2, u3;
    const uint4* ep0 = (const uint4*)(Es + ((size_t)b * S_ + s0 + 0) * D_ + lane * 16);
    const uint4* ep1 = (const uint4*)(Es + ((size_t)b * S_ + s0 + 1) * D_ + lane * 16);
    const uint4* ep2 = (const uint4*)(Es + ((size_t)b * S_ + s0 + 2) * D_ + lane * 16);
    const uint4* ep3 = (const uint4*)(Es + ((size_t)b * S_ + s0 + 3) * D_ + lane * 16);
    u0.u[0] = ep0[0]; u0.u[1] = ep0[1];
    u1.u[0] = ep1[0]; u1.u[1] = ep1[1];
    u2.u[0] = ep2[0]; u2.u[1] = ep2[1];
    u3.u[0] = ep3[0]; u3.u[1] = ep3[1];
    const float4* vp = (const float4*)(v + lane * 16);
#pragma unroll
    for (int c = 0; c < 4; ++c) {
      const float4 w4 = vp[c];
      vm2[4 * c + 0] = -2.f * w4.x; vm2[4 * c + 1] = -2.f * w4.y;
      vm2[4 * c + 2] = -2.f * w4.z; vm2[4 * c + 3] = -2.f * w4.w;
      sumv += w4.x + w4.y + w4.z + w4.w;
    }
#pragma unroll
    for (int j = 0; j < 16; ++j) {
      es0[j] = bf2f(u0.h[j]); es1[j] = bf2f(u1.h[j]);
      es2[j] = bf2f(u2.h[j]); es3[j] = bf2f(u3.h[j]);
    }
  }
  const float* qbase = Eq + ((size_t)(b * T_)) * D_ + lane * 16;
  for (int tc = 0; tc < 8; ++tc) {               // 8 chunks of 4 t-rows
    float sa[4], sb[4], sc[4], sd[4];
#pragma unroll
    for (int ti = 0; ti < 4; ++ti) {
      const float4* qp = (const float4*)(qbase + (size_t)(tc * 4 + ti) * D_);
      float a0 = sumv, a1 = sumv, a2 = sumv, a3 = sumv;
#pragma unroll
      for (int c = 0; c < 4; ++c) {
        const float4 q4 = qp[c];
        const float xs[4] = {q4.x, q4.y, q4.z, q4.w};
#pragma unroll
        for (int u2 = 0; u2 < 4; ++u2) {
          const int j = 4 * c + u2;
          a0 = fmaf(vm2[j], __builtin_amdgcn_rcpf(fmaf(xs[u2], es0[j], 1.f)), a0);
          a1 = fmaf(vm2[j], __builtin_amdgcn_rcpf(fmaf(xs[u2], es1[j], 1.f)), a1);
          a2 = fmaf(vm2[j], __builtin_amdgcn_rcpf(fmaf(xs[u2], es2[j], 1.f)), a2);
          a3 = fmaf(vm2[j], __builtin_amdgcn_rcpf(fmaf(xs[u2], es3[j], 1.f)), a3);
        }
      }
      sa[ti] = a0; sb[ti] = a1; sc[ti] = a2; sd[ti] = a3;
    }
#pragma unroll
    for (int off = 32; off > 0; off >>= 1)
#pragma unroll
      for (int ti = 0; ti < 4; ++ti) {
        sa[ti] += __shfl_xor(sa[ti], off);
        sb[ti] += __shfl_xor(sb[ti], off);
        sc[ti] += __shfl_xor(sc[ti], off);
        sd[ti] += __shfl_xor(sd[ti], off);
      }
    if (lane == 0) {
#pragma unroll
      for (int ti = 0; ti < 4; ++ti) {
        const int tt = tc * 4 + ti;
        const float e0 = m0 ? __builtin_amdgcn_exp2f(sa[ti] * LOG2E) : 0.f;
        const float e1 = m1 ? __builtin_amdgcn_exp2f(sb[ti] * LOG2E) : 0.f;
        const float e2 = m2 ? __builtin_amdgcn_exp2f(sc[ti] * LOG2E) : 0.f;
        const float e3 = m3 ? __builtin_amdgcn_exp2f(sd[ti] * LOG2E) : 0.f;
        const u16 p0 = f2bf(e0), p1 = f2bf(e1), p2 = f2bf(e2), p3 = f2bf(e3);
        uint2 pk;
        pk.x = (unsigned int)p0 | ((unsigned int)p1 << 16);
        pk.y = (unsigned int)p2 | ((unsigned int)p3 << 16);
        *(uint2*)&pbf[((size_t)(b * T_ + tt)) * S_ + s0] = pk;
        red[tt][wv] = bf2f(p0) + bf2f(p1) + bf2f(p2) + bf2f(p3);
      }
    }
  }
  __syncthreads();
  if (threadIdx.x < 32) {
    const int bb = blockIdx.x >> 6;              // 64 blocks per batch
    const float rs = red[threadIdx.x][0] + red[threadIdx.x][1] +
                     red[threadIdx.x][2] + red[threadIdx.x][3];
    atomicAdd(&rowsum[bb * 32 + threadIdx.x], rs);
  }
}

// ---- F5e: ctx = (E @ states)/rowsum. 256 blocks (16 ctx-cols each); 4 waves
// split S into 256-chunks, LDS-reduce; normalization + attn_t slice folded.
__global__ __launch_bounds__(256) void f5e_context(const u16* __restrict__ pbf, const u16* __restrict__ sbfT,
                                                   const float* __restrict__ rowsum,
                                                   float* __restrict__ ctx, float* __restrict__ out_at) {
  __shared__ float rinv[32];
  __shared__ float red[4][64][9];
  const int b = blockIdx.x >> 6, dt = blockIdx.x & 63;
  const int wv = threadIdx.x >> 6, lane = threadIdx.x & 63;
  if (threadIdx.x < 32) rinv[threadIdx.x] = 1.f / rowsum[b * 32 + threadIdx.x];
  const int n0 = dt * 16;
  const int fm = lane & 15, fq = lane >> 4;
  const floatx4 fz = {0.f, 0.f, 0.f, 0.f};
  floatx4 acc0 = fz, acc1 = fz;
  const u16* pa0 = pbf + ((size_t)b * T_ + fm) * S_ + wv * 256 + fq * 8;
  const u16* pa1 = pa0 + (size_t)16 * S_;
  const u16* pb  = sbfT + ((size_t)b * D_ + n0 + fm) * S_ + wv * 256 + fq * 8;
#pragma unroll
  for (int k0 = 0; k0 < 256; k0 += 32) {
    bf16x8 a0 = *(const bf16x8*)(pa0 + k0);
    bf16x8 a1 = *(const bf16x8*)(pa1 + k0);
    bf16x8 bb = *(const bf16x8*)(pb + k0);
    acc0 = __builtin_amdgcn_mfma_f32_16x16x32_bf16(a0, bb, acc0, 0, 0, 0);
    acc1 = __builtin_amdgcn_mfma_f32_16x16x32_bf16(a1, bb, acc1, 0, 0, 0);
  }
#pragma unroll
  for (int r = 0; r < 4; ++r) {
    red[wv][lane][r] = acc0[r];
    red[wv][lane][4 + r] = acc1[r];
  }
  __syncthreads();
  // attn_t slice: s in [dt*16, dt*16+16), all 32 t. All threads.
  const int s0a = dt * 16;
  for (int i = threadIdx.x; i < 512; i += 256) {
    const int tt = i & 31, sl = i >> 5;
    const float e = bf2f(pbf[((size_t)(b * T_ + tt)) * S_ + s0a + sl]);
    out_at[((size_t)(b * S_ + s0a + sl)) * T_ + tt] = e * rinv[tt];
  }
  if (wv == 0) {
#pragma unroll
    for (int r = 0; r < 4; ++r) {
      const float v0 = red[0][lane][r] + red[1][lane][r] + red[2][lane][r] + red[3][lane][r];
      const float v1 = red[0][lane][4 + r] + red[1][lane][4 + r] +
                       red[2][lane][4 + r] + red[3][lane][4 + r];
      const int t0r = fq * 4 + r;
      ctx[((size_t)b * T_ + t0r) * D_ + n0 + fm] = v0 * rinv[t0r];
      ctx[((size_t)b * T_ + 16 + t0r) * D_ + n0 + fm] = v1 * rinv[16 + t0r];
    }
  }
}

// ---- F6c: hidden += ctx_kslice @ Wc[0:1024] (query part + bias done in prep). ----
__global__ __launch_bounds__(256) void f6c_outproj(const float* __restrict__ ctx,
                                                   const float* __restrict__ Wc,
                                                   float* __restrict__ out_hid) {
  __shared__ float cq[16][128];
  const int c0 = blockIdx.x * 128, r0 = blockIdx.y * 16, k0 = blockIdx.z * 128;
  const int tid = threadIdx.x;
  const int cl = tid & 127, rh = tid >> 7;
  for (int i = tid; i < 16 * 128; i += 256) {
    const int rl = i >> 7, kk = i & 127;
    cq[rl][kk] = ctx[(size_t)(r0 + rl) * D_ + k0 + kk];
  }
  __syncthreads();
  float acc[8] = {};
  for (int kk = 0; kk < 128; ++kk) {
    const float w = Wc[(size_t)(k0 + kk) * H_ + c0 + cl];
#pragma unroll
    for (int rr = 0; rr < 8; ++rr) acc[rr] = fmaf(cq[rh * 8 + rr][kk], w, acc[rr]);
  }
#pragma unroll
  for (int rr = 0; rr < 8; ++rr)
    atomicAdd(&out_hid[(size_t)(r0 + rh * 8 + rr) * H_ + c0 + cl], acc[rr]);
}

// ================= TIER-3 KERNELS =================

__global__ __launch_bounds__(256) void prep_fused(const float* __restrict__ states, const float* __restrict__ Ws,
                                                  const float* __restrict__ query, const float* __restrict__ Wq,
                                                  const float* __restrict__ bq,
                                                  u16* __restrict__ sbf, u16* __restrict__ sbfT,
                                                  u16* __restrict__ WsT, float* __restrict__ qf) {
  __shared__ u16 tile[32][65];
  __shared__ float q[8][128];
  const int t = threadIdx.x;
  if (blockIdx.x < 512) {
    const int n0 = (blockIdx.x & 15) * 64, k0 = (blockIdx.x >> 4) * 32;
    const int kr = t >> 3, nc = (t & 7) * 8;
    const float* p = Ws + (size_t)(k0 + kr) * D_ + n0 + nc;
    float4 a = *(const float4*)p, b = *(const float4*)(p + 4);
    tile[kr][nc + 0] = f2bf(a.x); tile[kr][nc + 1] = f2bf(a.y);
    tile[kr][nc + 2] = f2bf(a.z); tile[kr][nc + 3] = f2bf(a.w);
    tile[kr][nc + 4] = f2bf(b.x); tile[kr][nc + 5] = f2bf(b.y);
    tile[kr][nc + 6] = f2bf(b.z); tile[kr][nc + 7] = f2bf(b.w);
    __syncthreads();
    const int nr = t >> 2, kc = (t & 3) * 8;
    union { uint4 v; u16 s[8]; } st;
#pragma unroll
    for (int i = 0; i < 8; ++i) st.s[i] = tile[kc + i][nr];
    *(uint4*)(WsT + (size_t)(n0 + nr) * D_ + k0 + kc) = st.v;
  } else if (blockIdx.x < 2560) {
    const int bid = blockIdx.x - 512;
    const int b = bid >> 9;
    const int r2 = bid & 511;
    const int d0 = (r2 & 15) * 64, s0 = (r2 >> 4) * 32;
    const int sr = t >> 3, dc = (t & 7) * 8;
    const float* p = states + ((size_t)b * S_ + s0 + sr) * D_ + d0 + dc;
    float4 a = *(const float4*)p, bb = *(const float4*)(p + 4);
    union { uint4 v; u16 s[8]; } pk;
    pk.s[0] = f2bf(a.x); pk.s[1] = f2bf(a.y); pk.s[2] = f2bf(a.z); pk.s[3] = f2bf(a.w);
    pk.s[4] = f2bf(bb.x); pk.s[5] = f2bf(bb.y); pk.s[6] = f2bf(bb.z); pk.s[7] = f2bf(bb.w);
    *(uint4*)(sbf + ((size_t)b * S_ + s0 + sr) * D_ + d0 + dc) = pk.v;
#pragma unroll
    for (int i = 0; i < 8; ++i) tile[sr][dc + i] = pk.s[i];
    __syncthreads();
    const int dr = t >> 2, sc = (t & 3) * 8;
    union { uint4 v; u16 s[8]; } st;
#pragma unroll
    for (int i = 0; i < 8; ++i) st.s[i] = tile[sc + i][dr];
    *(uint4*)(sbfT + ((size_t)b * D_ + d0 + dr) * S_ + s0 + sc) = st.v;
  } else {
    const int idx = blockIdx.x - 2560;            // 0..255
    const int c0 = (idx & 3) * 256, r0 = ((idx >> 2) & 15) * 8, k0 = (idx >> 6) * 128;
    for (int i = t; i < 8 * 128; i += 256) {
      const int rl = i >> 7, kk = i & 127;
      q[rl][kk] = query[(size_t)(r0 + rl) * H_ + k0 + kk];
    }
    __syncthreads();
    const int col = c0 + t;
    float acc[8] = {};
    for (int kk = 0; kk < 128; ++kk) {
      const float w = Wq[(size_t)(k0 + kk) * D_ + col];
#pragma unroll
      for (int r = 0; r < 8; ++r) acc[r] = fmaf(q[r][kk], w, acc[r]);
    }
    const float bb = (k0 == 0) ? bq[col] : 0.f;
#pragma unroll
    for (int r = 0; r < 8; ++r)
      atomicAdd(&qf[(size_t)(r0 + r) * D_ + col], TWO_LOG2E * (acc[r] + bb));
  }
}

__global__ __launch_bounds__(256) void f2e_sfgemm(const u16* __restrict__ A, const u16* __restrict__ BT,
                                                  u16* __restrict__ Cb) {
  __shared__ __align__(16) u16 sA[128 * 64];   // 16 KB, row stride 64 u16
  __shared__ __align__(16) u16 sB[64 * 64];    // 8 KB
  const int bm0 = blockIdx.y * 128, bn0 = blockIdx.x * 64;
  const int t = threadIdx.x;
  const int wv = t >> 6, lane = t & 63;
  const int wm = (wv >> 1) * 64, wn = (wv & 1) * 32;
  const int fm = lane & 15, fq = lane >> 4;
  const int srow = lane >> 3, sp = lane & 7;   // staging: 8 rows x 8 chunks per inst

  floatx4 acc[4][2];
  const floatx4 fz = {0.f, 0.f, 0.f, 0.f};
#pragma unroll
  for (int i = 0; i < 4; ++i) { acc[i][0] = fz; acc[i][1] = fz; }

  for (int k0 = 0; k0 < D_; k0 += 64) {
    __syncthreads();                           // prev tile reads done
#pragma unroll
    for (int j = 0; j < 4; ++j) {              // A: rows wv*32 + j*8 + srow
      const int r = wv * 32 + j * 8 + srow;
      const int c = sp ^ (r & 7);
      ld_g2l_16(A + (size_t)(bm0 + r) * D_ + k0 + c * 8, &sA[(wv * 32 + j * 8) * 64]);
    }
#pragma unroll
    for (int j = 0; j < 2; ++j) {              // B: rows wv*16 + j*8 + srow
      const int r = wv * 16 + j * 8 + srow;
      const int c = sp ^ (r & 7);
      ld_g2l_16(BT + (size_t)(bn0 + r) * D_ + k0 + c * 8, &sB[(wv * 16 + j * 8) * 64]);
    }
    __syncthreads();                           // vmcnt(0) drains the async loads
#pragma unroll
    for (int win = 0; win < 2; ++win) {
      bf16x8 af[4], bfr[2];
#pragma unroll
      for (int i = 0; i < 4; ++i) {
        const int R = wm + i * 16 + fm;
        af[i] = *(const bf16x8*)&sA[R * 64 + ((win * 4 + fq) ^ (R & 7)) * 8];
      }
#pragma unroll
      for (int j = 0; j < 2; ++j) {
        const int R = wn + j * 16 + fm;
        bfr[j] = *(const bf16x8*)&sB[R * 64 + ((win * 4 + fq) ^ (R & 7)) * 8];
      }
#pragma unroll
      for (int i = 0; i < 4; ++i)
#pragma unroll
        for (int j = 0; j < 2; ++j)
          acc[i][j] = __builtin_amdgcn_mfma_f32_16x16x32_bf16(af[i], bfr[j], acc[i][j], 0, 0, 0);
    }
  }
#pragma unroll
  for (int i = 0; i < 4; ++i)
#pragma unroll
    for (int j = 0; j < 2; ++j)
#pragma unroll
      for (int r = 0; r < 4; ++r) {
        const int row = bm0 + wm + i * 16 + fq * 4 + r;   // col=lane&15, row=quad*4+reg (m89)
        const int col = bn0 + wn + j * 16 + fm;
        Cb[(size_t)row * D_ + col] = f2bf(TWO_LOG2E * acc[i][j][r]);
      }
}

__global__ __launch_bounds__(256, 6) void f3f_align(const float* __restrict__ qf, const u16* __restrict__ sfb,
                                                    const float* __restrict__ v, float* __restrict__ alg) {
  const int wid = (blockIdx.x * 256 + threadIdx.x) >> 6;  // b*1024+s
  const int lane = threadIdx.x & 63;
  const int b = wid >> 10, s = wid & 1023;
  const int t0 = blockIdx.y * 16;
  float vr[16], sr[16];
  {
    union { uint4 v[2]; u16 s[16]; } u;
    const uint4* sp = (const uint4*)(sfb + (size_t)wid * D_ + lane * 16);
    u.v[0] = sp[0]; u.v[1] = sp[1];
    const float* vp = v + lane * 16;
#pragma unroll
    for (int c = 0; c < 4; ++c) {
      float4 w = *(const float4*)(vp + 4 * c);
      vr[4 * c + 0] = w.x; vr[4 * c + 1] = w.y; vr[4 * c + 2] = w.z; vr[4 * c + 3] = w.w;
    }
#pragma unroll
    for (int j = 0; j < 16; ++j) sr[j] = bf2f(u.s[j]);
  }
  float sum[16];
#pragma unroll
  for (int tt = 0; tt < 16; ++tt) sum[tt] = 0.f;

  const float* qbase = qf + ((size_t)(b * T_ + t0)) * D_ + lane * 16;
  for (int tt = 0; tt < 16; ++tt) {
    const float4* qp = (const float4*)(qbase + (size_t)tt * D_);
    float acc = 0.f;
#pragma unroll
    for (int c = 0; c < 4; ++c) {
      float4 q4 = qp[c];
      float xs[4] = {q4.x, q4.y, q4.z, q4.w};
#pragma unroll
      for (int u2 = 0; u2 < 4; ++u2) {
        const int j = 4 * c + u2;
        const float x = xs[u2] + sr[j];                        // prescaled by 2log2e
        const float e = __builtin_amdgcn_exp2f(x);
        acc = fmaf(vr[j], fmaf(-2.f, __builtin_amdgcn_rcpf(e + 1.f), 1.f), acc);
      }
    }
    sum[tt] = acc;
  }
#pragma unroll
  for (int off = 32; off > 0; off >>= 1)
#pragma unroll
    for (int tt = 0; tt < 16; ++tt) sum[tt] += __shfl_xor(sum[tt], off);
  if (lane == 0) {
#pragma unroll
    for (int tt = 0; tt < 16; ++tt)
      alg[((size_t)(b * T_ + t0 + tt)) * S_ + s] = sum[tt];
  }
}

__global__ __launch_bounds__(256) void f4b_softmax(const float* __restrict__ alg, const int* __restrict__ mask,
                                                   float* __restrict__ out_at, u16* __restrict__ pbf) {
  const int r = blockIdx.x;                    // b*T+t
  const int b = r >> 5, t = r & 31;
  const int tid = threadIdx.x;
  __shared__ float red[256];
  float a[4];
#pragma unroll
  for (int jj = 0; jj < 4; ++jj) {
    const int s = tid + 256 * jj;
    const float x = alg[(size_t)r * S_ + s];
    a[jj] = (mask[(size_t)b * S_ + s] != 0) ? x : -3.0e38f;
  }
  float m = fmaxf(fmaxf(a[0], a[1]), fmaxf(a[2], a[3]));
  red[tid] = m; __syncthreads();
  for (int st = 128; st > 0; st >>= 1) { if (tid < st) red[tid] = fmaxf(red[tid], red[tid + st]); __syncthreads(); }
  m = red[0]; __syncthreads();
  float e[4], lsum = 0.f;
#pragma unroll
  for (int jj = 0; jj < 4; ++jj) {
    e[jj] = (a[jj] > -1.0e38f) ? expf(a[jj] - m) : 0.f;
    lsum += e[jj];
  }
  red[tid] = lsum; __syncthreads();
  for (int st = 128; st > 0; st >>= 1) { if (tid < st) red[tid] += red[tid + st]; __syncthreads(); }
  const float rs = 1.f / red[0];
#pragma unroll
  for (int jj = 0; jj < 4; ++jj) {
    const int s = tid + 256 * jj;
    const float p = e[jj] * rs;
    out_at[((size_t)b * S_ + s) * T_ + t] = p;
    pbf[(size_t)r * S_ + s] = f2bf(p);
  }
}

__global__ __launch_bounds__(256) void f5c_context(const u16* __restrict__ pbf, const u16* __restrict__ sbfT,
                                                   float* __restrict__ ctx) {
  const int b = blockIdx.x >> 4, dt = blockIdx.x & 15;
  const int wv = threadIdx.x >> 6, lane = threadIdx.x & 63;
  const int n0 = dt * 64 + wv * 16;
  const int fm = lane & 15, fq = lane >> 4;
  const floatx4 fz = {0.f, 0.f, 0.f, 0.f};
  floatx4 acc0 = fz, acc1 = fz;
  const u16* pa0 = pbf + ((size_t)b * T_ + fm) * S_ + fq * 8;
  const u16* pa1 = pbf + ((size_t)b * T_ + 16 + fm) * S_ + fq * 8;
  const u16* pb  = sbfT + ((size_t)b * D_ + n0 + fm) * S_ + fq * 8;
#pragma unroll 4
  for (int k0 = 0; k0 < S_; k0 += 32) {
    bf16x8 a0 = *(const bf16x8*)(pa0 + k0);
    bf16x8 a1 = *(const bf16x8*)(pa1 + k0);
    bf16x8 bb = *(const bf16x8*)(pb + k0);
    acc0 = __builtin_amdgcn_mfma_f32_16x16x32_bf16(a0, bb, acc0, 0, 0, 0);
    acc1 = __builtin_amdgcn_mfma_f32_16x16x32_bf16(a1, bb, acc1, 0, 0, 0);
  }
  const int col = n0 + fm;
#pragma unroll
  for (int r = 0; r < 4; ++r) {
    ctx[((size_t)b * T_ + fq * 4 + r) * D_ + col] = acc0[r];
    ctx[((size_t)b * T_ + 16 + fq * 4 + r) * D_ + col] = acc1[r];
  }
}

__global__ __launch_bounds__(256) void f6b_outproj(const float* __restrict__ ctx, const float* __restrict__ query,
                                                   const float* __restrict__ Wc, const float* __restrict__ bc,
                                                   float* __restrict__ out_hid) {
  __shared__ float cq[16][128];
  const int c0 = blockIdx.x * 128, r0 = blockIdx.y * 16, k0 = blockIdx.z * 128;
  const int tid = threadIdx.x;
  const int cl = tid & 127, rh = tid >> 7;
  for (int i = tid; i < 16 * 128; i += 256) {
    const int rl = i >> 7, kk = i & 127;
    const int k = k0 + kk, row = r0 + rl;
    cq[rl][kk] = (k < D_) ? ctx[(size_t)row * D_ + k] : query[(size_t)row * H_ + k - D_];
  }
  __syncthreads();
  float acc[8] = {};
  for (int kk = 0; kk < 128; ++kk) {
    const float w = Wc[(size_t)(k0 + kk) * H_ + c0 + cl];
#pragma unroll
    for (int rr = 0; rr < 8; ++rr) acc[rr] = fmaf(cq[rh * 8 + rr][kk], w, acc[rr]);
  }
  const float bb = (blockIdx.z == 0) ? bc[c0 + cl] : 0.f;
#pragma unroll
  for (int rr = 0; rr < 8; ++rr)
    atomicAdd(&out_hid[(size_t)(r0 + rh * 8 + rr) * H_ + c0 + cl], acc[rr] + bb);
}

// ================= TIER-1/2 EXTRAS =================

__global__ __launch_bounds__(256) void kc_cvt(const float* __restrict__ in, u16* __restrict__ out) {
  const size_t i0 = ((size_t)blockIdx.x * 256 + threadIdx.x) * 8;
  float4 a = *(const float4*)(in + i0);
  float4 b = *(const float4*)(in + i0 + 4);
  union { uint4 v; u16 s[8]; } r;
  r.s[0] = f2bf(a.x); r.s[1] = f2bf(a.y); r.s[2] = f2bf(a.z); r.s[3] = f2bf(a.w);
  r.s[4] = f2bf(b.x); r.s[5] = f2bf(b.y); r.s[6] = f2bf(b.z); r.s[7] = f2bf(b.w);
  *(uint4*)(out + i0) = r.v;
}

__global__ __launch_bounds__(256) void f0_transpose(const float* __restrict__ Ws, u16* __restrict__ WsT) {
  __shared__ u16 tile[32][65];
  const int n0 = blockIdx.x * 64, k0 = blockIdx.y * 32;
  const int t = threadIdx.x;
  {
    const int kr = t >> 3, nc = (t & 7) * 8;
    const float* p = Ws + (size_t)(k0 + kr) * D_ + n0 + nc;
    float4 a = *(const float4*)p, b = *(const float4*)(p + 4);
    tile[kr][nc + 0] = f2bf(a.x); tile[kr][nc + 1] = f2bf(a.y);
    tile[kr][nc + 2] = f2bf(a.z); tile[kr][nc + 3] = f2bf(a.w);
    tile[kr][nc + 4] = f2bf(b.x); tile[kr][nc + 5] = f2bf(b.y);
    tile[kr][nc + 6] = f2bf(b.z); tile[kr][nc + 7] = f2bf(b.w);
  }
  __syncthreads();
  {
    const int nr = t >> 2, kc = (t & 3) * 8;
    union { uint4 v; u16 s[8]; } st;
#pragma unroll
    for (int i = 0; i < 8; ++i) st.s[i] = tile[kc + i][nr];
    *(uint4*)(WsT + (size_t)(n0 + nr) * D_ + k0 + kc) = st.v;
  }
}

__global__ __launch_bounds__(256) void f1b_qf(const float* __restrict__ query, const float* __restrict__ Wq,
                                              const float* __restrict__ bq, float* __restrict__ qf) {
  __shared__ float q[8][128];
  const int c0 = blockIdx.x * 256, r0 = blockIdx.y * 8, k0 = blockIdx.z * 128;
  const int tid = threadIdx.x;
  for (int i = tid; i < 8 * 128; i += 256) {
    const int rl = i >> 7, kk = i & 127;
    q[rl][kk] = query[(size_t)(r0 + rl) * H_ + k0 + kk];
  }
  __syncthreads();
  const int col = c0 + tid;
  float acc[8] = {};
  for (int kk = 0; kk < 128; ++kk) {
    const float w = Wq[(size_t)(k0 + kk) * D_ + col];
#pragma unroll
    for (int r = 0; r < 8; ++r) acc[r] = fmaf(q[r][kk], w, acc[r]);
  }
  const float bb = (blockIdx.z == 0) ? bq[col] : 0.f;
#pragma unroll
  for (int r = 0; r < 8; ++r)
    atomicAdd(&qf[(size_t)(r0 + r) * D_ + col], TWO_LOG2E * (acc[r] + bb));
}

__global__ __launch_bounds__(256) void f2c_sfgemm(const u16* __restrict__ A, const u16* __restrict__ BT,
                                                  u16* __restrict__ Cb) {
  __shared__ __align__(16) u16 sA[128 * 40];
  __shared__ __align__(16) u16 sB[64 * 40];
  const int bm0 = blockIdx.y * 128, bn0 = blockIdx.x * 64;
  const int t = threadIdx.x;
  const int wv = t >> 6, lane = t & 63;
  const int wm = (wv >> 1) * 64, wn = (wv & 1) * 32;
  const int fm = lane & 15, fq = lane >> 4;
  const int arow = t >> 1, akc = (t & 1) * 16;
  const int brow = t >> 2, bkc = (t & 3) * 8;
  floatx4 acc[4][2];
  const floatx4 fz = {0.f, 0.f, 0.f, 0.f};
#pragma unroll
  for (int i = 0; i < 4; ++i) { acc[i][0] = fz; acc[i][1] = fz; }
  const uint4* gA = (const uint4*)(A + (size_t)(bm0 + arow) * D_ + akc);
  const uint4* gB = (const uint4*)(BT + (size_t)(bn0 + brow) * D_ + bkc);
  for (int k0 = 0; k0 < D_; k0 += 32) {
    uint4 va0 = gA[k0 >> 3];
    uint4 va1 = gA[(k0 >> 3) + 1];
    uint4 vb = gB[k0 >> 3];
    __syncthreads();
    *(uint4*)&sA[arow * 40 + akc] = va0;
    *(uint4*)&sA[arow * 40 + akc + 8] = va1;
    *(uint4*)&sB[brow * 40 + bkc] = vb;
    __syncthreads();
    bf16x8 af[4], bfr[2];
#pragma unroll
    for (int i = 0; i < 4; ++i) af[i] = *(const bf16x8*)&sA[(wm + i * 16 + fm) * 40 + fq * 8];
#pragma unroll
    for (int j = 0; j < 2; ++j) bfr[j] = *(const bf16x8*)&sB[(wn + j * 16 + fm) * 40 + fq * 8];
#pragma unroll
    for (int i = 0; i < 4; ++i)
#pragma unroll
      for (int j = 0; j < 2; ++j)
        acc[i][j] = __builtin_amdgcn_mfma_f32_16x16x32_bf16(af[i], bfr[j], acc[i][j], 0, 0, 0);
  }
#pragma unroll
  for (int i = 0; i < 4; ++i)
#pragma unroll
    for (int j = 0; j < 2; ++j)
#pragma unroll
      for (int r = 0; r < 4; ++r) {
        const int row = bm0 + wm + i * 16 + fq * 4 + r;
        const int col = bn0 + wn + j * 16 + fm;
        Cb[(size_t)row * D_ + col] = f2bf(TWO_LOG2E * acc[i][j][r]);
      }
}

__global__ __launch_bounds__(256) void f2d_sfgemm(const float* __restrict__ A, const u16* __restrict__ BT,
                                                  u16* __restrict__ Cb) {
  __shared__ __align__(16) u16 sA[128 * 40];
  __shared__ __align__(16) u16 sB[64 * 40];
  const int bm0 = blockIdx.y * 128, bn0 = blockIdx.x * 64;
  const int t = threadIdx.x;
  const int wv = t >> 6, lane = t & 63;
  const int wm = (wv >> 1) * 64, wn = (wv & 1) * 32;
  const int fm = lane & 15, fq = lane >> 4;
  const int arow = t >> 1, akc = (t & 1) * 16;
  const int brow = t >> 2, bkc = (t & 3) * 8;
  floatx4 acc[4][2];
  const floatx4 fz = {0.f, 0.f, 0.f, 0.f};
#pragma unroll
  for (int i = 0; i < 4; ++i) { acc[i][0] = fz; acc[i][1] = fz; }
  const float* gA = A + (size_t)(bm0 + arow) * D_ + akc;
  const uint4* gB = (const uint4*)(BT + (size_t)(bn0 + brow) * D_ + bkc);
  for (int k0 = 0; k0 < D_; k0 += 32) {
    float4 a0 = *(const float4*)(gA + k0);
    float4 a1 = *(const float4*)(gA + k0 + 4);
    float4 a2 = *(const float4*)(gA + k0 + 8);
    float4 a3 = *(const float4*)(gA + k0 + 12);
    uint4 vb = gB[k0 >> 3];
    union { uint4 v[2]; u16 s[16]; } pa;
    pa.s[0] = f2bf(a0.x); pa.s[1] = f2bf(a0.y); pa.s[2] = f2bf(a0.z); pa.s[3] = f2bf(a0.w);
    pa.s[4] = f2bf(a1.x); pa.s[5] = f2bf(a1.y); pa.s[6] = f2bf(a1.z); pa.s[7] = f2bf(a1.w);
    pa.s[8] = f2bf(a2.x); pa.s[9] = f2bf(a2.y); pa.s[10] = f2bf(a2.z); pa.s[11] = f2bf(a2.w);
    pa.s[12] = f2bf(a3.x); pa.s[13] = f2bf(a3.y); pa.s[14] = f2bf(a3.z); pa.s[15] = f2bf(a3.w);
    __syncthreads();
    *(uint4*)&sA[arow * 40 + akc] = pa.v[0];
    *(uint4*)&sA[arow * 40 + akc + 8] = pa.v[1];
    *(uint4*)&sB[brow * 40 + bkc] = vb;
    __syncthreads();
    bf16x8 af[4], bfr[2];
#pragma unroll
    for (int i = 0; i < 4; ++i) af[i] = *(const bf16x8*)&sA[(wm + i * 16 + fm) * 40 + fq * 8];
#pragma unroll
    for (int j = 0; j < 2; ++j) bfr[j] = *(const bf16x8*)&sB[(wn + j * 16 + fm) * 40 + fq * 8];
#pragma unroll
    for (int i = 0; i < 4; ++i)
#pragma unroll
      for (int j = 0; j < 2; ++j)
        acc[i][j] = __builtin_amdgcn_mfma_f32_16x16x32_bf16(af[i], bfr[j], acc[i][j], 0, 0, 0);
  }
#pragma unroll
  for (int i = 0; i < 4; ++i)
#pragma unroll
    for (int j = 0; j < 2; ++j)
#pragma unroll
      for (int r = 0; r < 4; ++r) {
        const int row = bm0 + wm + i * 16 + fq * 4 + r;
        const int col = bn0 + wn + j * 16 + fm;
        Cb[(size_t)row * D_ + col] = f2bf(TWO_LOG2E * acc[i][j][r]);
      }
}

__global__ __launch_bounds__(256) void f4_softmax(const float* __restrict__ alg, const int* __restrict__ mask,
                                                  float* __restrict__ attn) {
  const int r = blockIdx.x;
  const int b = r >> 5;
  const int tid = threadIdx.x;
  __shared__ float red[256];
  float a[4];
#pragma unroll
  for (int jj = 0; jj < 4; ++jj) {
    const int s = tid + 256 * jj;
    const float x = alg[(size_t)r * S_ + s];
    a[jj] = (mask[(size_t)b * S_ + s] != 0) ? x : -3.0e38f;
  }
  float m = fmaxf(fmaxf(a[0], a[1]), fmaxf(a[2], a[3]));
  red[tid] = m; __syncthreads();
  for (int st = 128; st > 0; st >>= 1) { if (tid < st) red[tid] = fmaxf(red[tid], red[tid + st]); __syncthreads(); }
  m = red[0]; __syncthreads();
  float e[4], lsum = 0.f;
#pragma unroll
  for (int jj = 0; jj < 4; ++jj) {
    e[jj] = (a[jj] > -1.0e38f) ? expf(a[jj] - m) : 0.f;
    lsum += e[jj];
  }
  red[tid] = lsum; __syncthreads();
  for (int st = 128; st > 0; st >>= 1) { if (tid < st) red[tid] += red[tid + st]; __syncthreads(); }
  const float rs = 1.f / red[0];
#pragma unroll
  for (int jj = 0; jj < 4; ++jj)
    attn[(size_t)r * S_ + tid + 256 * jj] = e[jj] * rs;
}

__global__ __launch_bounds__(256) void f5b_context(const float* __restrict__ attn, const u16* __restrict__ sbf,
                                                   float* __restrict__ ctx, float* __restrict__ out_at) {
  __shared__ float at[16][64];
  const int s0 = blockIdx.x * 64, t0 = blockIdx.y * 16, b = blockIdx.z;
  const int tid = threadIdx.x;
  for (int i = tid; i < 16 * 64; i += 256) {
    const int tl = i >> 6, sl = i & 63;
    at[tl][sl] = attn[(size_t)(b * T_ + t0 + tl) * S_ + s0 + sl];
  }
  __syncthreads();
  for (int i = tid; i < 64 * 16; i += 256) {
    const int sl = i >> 4, tl = i & 15;
    out_at[((size_t)b * S_ + s0 + sl) * T_ + t0 + tl] = at[tl][sl];
  }
  float acc[16][4] = {};
  for (int sl = 0; sl < 64; ++sl) {
    const u16* srow = sbf + ((size_t)b * S_ + s0 + sl) * D_ + tid;
    float sv[4];
#pragma unroll
    for (int jj = 0; jj < 4; ++jj) sv[jj] = bf2f(srow[256 * jj]);
#pragma unroll
    for (int tl = 0; tl < 16; ++tl) {
      const float w = at[tl][sl];
#pragma unroll
      for (int jj = 0; jj < 4; ++jj) acc[tl][jj] = fmaf(w, sv[jj], acc[tl][jj]);
    }
  }
#pragma unroll
  for (int tl = 0; tl < 16; ++tl)
#pragma unroll
    for (int jj = 0; jj < 4; ++jj)
      atomicAdd(&ctx[(size_t)(b * T_ + t0 + tl) * D_ + tid + 256 * jj], acc[tl][jj]);
}

__global__ __launch_bounds__(256) void f5_context(const float* __restrict__ attn, const float* __restrict__ states,
                                                  float* __restrict__ ctx, float* __restrict__ out_at) {
  __shared__ float at[16][64];
  const int s0 = blockIdx.x * 64, t0 = blockIdx.y * 16, b = blockIdx.z;
  const int tid = threadIdx.x;
  for (int i = tid; i < 16 * 64; i += 256) {
    const int tl = i >> 6, sl = i & 63;
    at[tl][sl] = attn[(size_t)(b * T_ + t0 + tl) * S_ + s0 + sl];
  }
  __syncthreads();
  for (int i = tid; i < 64 * 16; i += 256) {
    const int sl = i >> 4, tl = i & 15;
    out_at[((size_t)b * S_ + s0 + sl) * T_ + t0 + tl] = at[tl][sl];
  }
  float acc[16][4] = {};
  for (int sl = 0; sl < 64; ++sl) {
    const float* srow = states + ((size_t)b * S_ + s0 + sl) * D_ + tid;
    float sv[4];
#pragma unroll
    for (int jj = 0; jj < 4; ++jj) sv[jj] = srow[256 * jj];
#pragma unroll
    for (int tl = 0; tl < 16; ++tl) {
      const float w = at[tl][sl];
#pragma unroll
      for (int jj = 0; jj < 4; ++jj) acc[tl][jj] = fmaf(w, sv[jj], acc[tl][jj]);
    }
  }
#pragma unroll
  for (int tl = 0; tl < 16; ++tl)
#pragma unroll
    for (int jj = 0; jj < 4; ++jj)
      atomicAdd(&ctx[(size_t)(b * T_ + t0 + tl) * D_ + tid + 256 * jj], acc[tl][jj]);
}

// ================= FALLBACK (round-7, passing) =================

__global__ __launch_bounds__(256) void k1_qf(const float* __restrict__ query, const float* __restrict__ Wq,
                                             const float* __restrict__ bq, float* __restrict__ qf) {
  const int r = blockIdx.x;
  const int tid = threadIdx.x;
  __shared__ float q[H_];
  for (int i = tid; i < H_; i += 256) q[i] = query[(size_t)r * H_ + i];
  __syncthreads();
#pragma unroll
  for (int jj = 0; jj < 4; ++jj) {
    const int j = tid + 256 * jj;
    float acc = bq[j];
    for (int k = 0; k < H_; ++k) acc = fmaf(q[k], Wq[(size_t)k * D_ + j], acc);
    qf[(size_t)r * D_ + j] = acc;
  }
}

__global__ __launch_bounds__(256) void k23_align(const float* __restrict__ states, const float* __restrict__ Ws,
                                                 const float* __restrict__ v, const float* __restrict__ qf,
                                                 float* __restrict__ alg) {
  const int b = blockIdx.x >> 6;
  const int s0 = (blockIdx.x & 63) * 16;
  const int tid = threadIdx.x, lane = tid & 63, wv = tid >> 6;
  __shared__ u16 stL[16 * D_];
  __shared__ float vvL[D_];
  __shared__ float red[16 * 4];
  for (int i = tid; i < 16 * D_; i += 256) {
    const int row = i >> 10, col = i & (D_ - 1);
    stL[i] = f2bf(states[((size_t)b * S_ + s0 + row) * D_ + col]);
  }
  for (int i = tid; i < D_; i += 256) vvL[i] = v[i];
  __syncthreads();
  float acc[64];
#pragma unroll
  for (int i = 0; i < 64; ++i) acc[i] = 0.f;
#pragma unroll 4
  for (int k = 0; k < D_; ++k) {
    float wsv[4];
#pragma unroll
    for (int jj = 0; jj < 4; ++jj) wsv[jj] = Ws[(size_t)k * D_ + tid + 256 * jj];
#pragma unroll
    for (int i = 0; i < 16; ++i) {
      const float sv = bf2f(stL[i * D_ + k]);
#pragma unroll
      for (int jj = 0; jj < 4; ++jj) acc[i * 4 + jj] = fmaf(sv, wsv[jj], acc[i * 4 + jj]);
    }
  }
  for (int t = 0; t < T_; ++t) {
    float qv[4];
#pragma unroll
    for (int jj = 0; jj < 4; ++jj) qv[jj] = qf[((size_t)b * T_ + t) * D_ + tid + 256 * jj];
    float part[16];
#pragma unroll
    for (int i = 0; i < 16; ++i) {
      float p = 0.f;
#pragma unroll
      for (int jj = 0; jj < 4; ++jj)
        p = fmaf(vvL[tid + 256 * jj], tanhf(qv[jj] + acc[i * 4 + jj]), p);
      part[i] = p;
    }
#pragma unroll
    for (int i = 0; i < 16; ++i) {
      float x = part[i];
#pragma unroll
      for (int off = 32; off > 0; off >>= 1) x += __shfl_xor(x, off);
      if (lane == 0) red[i * 4 + wv] = x;
    }
    __syncthreads();
    if (tid < 16)
      alg[((size_t)b * T_ + t) * S_ + s0 + tid] =
          red[tid * 4 + 0] + red[tid * 4 + 1] + red[tid * 4 + 2] + red[tid * 4 + 3];
    __syncthreads();
  }
}

__global__ __launch_bounds__(256) void k4_softmax(const float* __restrict__ alg, const int* __restrict__ mask,
                                                  float* __restrict__ attn) {
  const int r = blockIdx.x;
  const int b = r >> 5;
  const int tid = threadIdx.x;
  __shared__ float red[256];
  float a[4];
#pragma unroll
  for (int jj = 0; jj < 4; ++jj) {
    const int s = tid + 256 * jj;
    const float x = alg[(size_t)r * S_ + s];
    a[jj] = (mask[(size_t)b * S_ + s] != 0) ? x : -3.0e38f;
  }
  float m = fmaxf(fmaxf(a[0], a[1]), fmaxf(a[2], a[3]));
  red[tid] = m; __syncthreads();
  for (int st = 128; st > 0; st >>= 1) { if (tid < st) red[tid] = fmaxf(red[tid], red[tid + st]); __syncthreads(); }
  m = red[0]; __syncthreads();
  float e[4], lsum = 0.f;
#pragma unroll
  for (int jj = 0; jj < 4; ++jj) {
    e[jj] = (a[jj] > -1.0e38f) ? expf(a[jj] - m) : 0.f;
    lsum += e[jj];
  }
  red[tid] = lsum; __syncthreads();
  for (int st = 128; st > 0; st >>= 1) { if (tid < st) red[tid] += red[tid + st]; __syncthreads(); }
  const float rs = 1.f / red[0];
#pragma unroll
  for (int jj = 0; jj < 4; ++jj)
    attn[(size_t)r * S_ + tid + 256 * jj] = e[jj] * rs;
}

__global__ __launch_bounds__(256) void k56_ctx_proj(const float* __restrict__ attn, const float* __restrict__ states,
                                                    const float* __restrict__ query, const float* __restrict__ Wc,
                                                    const float* __restrict__ bc,
                                                    float* __restrict__ out_ctx, float* __restrict__ out_hid,
                                                    float* __restrict__ out_at) {
  const int r = blockIdx.x;
  const int b = r >> 5, t = r & (T_ - 1);
  const int tid = threadIdx.x;
  __shared__ float pr[S_];
  __shared__ float cq[D_ + H_];
  for (int s = tid; s < S_; s += 256) pr[s] = attn[(size_t)r * S_ + s];
  __syncthreads();
  for (int s = tid; s < S_; s += 256) out_at[((size_t)b * S_ + s) * T_ + t] = pr[s];
  float acc[4] = {0.f, 0.f, 0.f, 0.f};
  for (int s = 0; s < S_; ++s) {
    const float w = pr[s];
    const float* srow = states + ((size_t)b * S_ + s) * D_ + tid;
#pragma unroll
    for (int jj = 0; jj < 4; ++jj) acc[jj] = fmaf(w, srow[256 * jj], acc[jj]);
  }
#pragma unroll
  for (int jj = 0; jj < 4; ++jj) {
    cq[tid + 256 * jj] = acc[jj];
    out_ctx[(size_t)r * D_ + tid + 256 * jj] = acc[jj];
  }
  for (int i = tid; i < H_; i += 256) cq[D_ + i] = query[(size_t)r * H_ + i];
  __syncthreads();
#pragma unroll
  for (int jj = 0; jj < 2; ++jj) {
    const int n = tid + 256 * jj;
    float h = bc[n];
    for (int k = 0; k < D_ + H_; ++k) h = fmaf(cq[k], Wc[(size_t)k * H_ + n], h);
    out_hid[(size_t)r * H_ + n] = h;
  }
}

extern "C" void kernel_launch(void* const* d_in, const int* in_sizes, int n_in,
                              void* d_out, int out_size, void* d_ws, size_t ws_size,
                              hipStream_t stream) {
  const float* query  = (const float*)d_in[0];
  const float* states = (const float*)d_in[1];
  const int*   mask   = (const int*)d_in[2];
  const float* Wq     = (const float*)d_in[3];
  const float* bq     = (const float*)d_in[4];
  const float* Ws     = (const float*)d_in[5];
  const float* v      = (const float*)d_in[6];
  const float* Wc     = (const float*)d_in[7];
  const float* bc     = (const float*)d_in[8];

  float* A  = (float*)d_out;               // ctx(final)
  float* Bh = A + (size_t)BT_ * D_;        // hidden
  float* C  = Bh + (size_t)BT_ * H_;       // attn_t

  char* ws = (char*)d_ws;
  u16*   sfb  = (u16*)(ws + 0);
  u16*   WsT  = (u16*)(ws + 8388608);
  float* alg  = (float*)(ws + 10485760);
  u16*   sbf  = (u16*)(ws + 11010048);
  u16*   sbfT = (u16*)(ws + 19398656);
  u16*   pbf  = (u16*)(ws + 27787264);

  const size_t WS_T1 = 11010048;
  const size_t WS_T2 = 19398656;
  const size_t WS_T3 = 28049408;
  const size_t WS_T4 = 36962816;   // + Es16 (8.4MB) + Eq (512KB) + rsum (512B); qfp reuses [0,2MB)

  if (ws_size >= WS_T4) {
    // ---------- tier 4 ----------
    float* qfp  = (float*)(ws + 0);        // 2 MB: 4 x 512KB qf split-K partials
    u16*   Es16 = (u16*)(ws + 28049408);   // 8.4 MB bf16 exp2(scale*sf)
    float* Eq4  = (float*)(ws + 36438016); // 512 KB fp32 exp2(scale*qf)
    float* rsum = (float*)(ws + 36962304); // 512 B fp32 softmax row sums
    (void)hipMemsetAsync(Bh, 0, (size_t)BT_ * H_ * 4, stream);   // hidden zero (atomics)
    prep_fused6<<<2944, 256, 0, stream>>>(states, Ws, query, Wq, bq, Wc, bc,
                                          sbf, sbfT, WsT, qfp, rsum, Bh);
    f2i_sfgemm<<<dim3(16, 32), 256, 0, stream>>>(sbf, WsT, qfp, Eq4, Es16);
    f3k_align<<<256, 256, 0, stream>>>(Eq4, Es16, v, mask, pbf, rsum);
    f5e_context<<<256, 256, 0, stream>>>(pbf, sbfT, rsum, A, C);
    f6c_outproj<<<dim3(4, 8, 8), 256, 0, stream>>>(A, Wc, Bh);
  } else if (ws_size >= WS_T3) {
    // ---------- tier 3 ----------
    (void)hipMemsetAsync(A, 0, (size_t)(BT_ * D_ + BT_ * H_) * 4, stream);  // qf + hidden zero
    prep_fused<<<2816, 256, 0, stream>>>(states, Ws, query, Wq, bq, sbf, sbfT, WsT, A);
    f2e_sfgemm<<<dim3(16, 32), 256, 0, stream>>>(sbf, WsT, sfb);
    f3f_align<<<dim3(1024, 2), 256, 0, stream>>>(A, sfb, v, alg);
    f4b_softmax<<<BT_, 256, 0, stream>>>(alg, mask, C, pbf);
    f5c_context<<<64, 256, 0, stream>>>(pbf, sbfT, A);
    f6b_outproj<<<dim3(4, 8, 12), 256, 0, stream>>>(A, query, Wc, bc, Bh);
  } else if (ws_size >= WS_T1) {
    // ---------- tier 1/2 ----------
    float* attn = alg;
    (void)hipMemsetAsync(A, 0, (size_t)(BT_ * D_ + BT_ * H_) * 4, stream);
    f1b_qf<<<dim3(4, 16, 4), 256, 0, stream>>>(query, Wq, bq, A);
    f0_transpose<<<dim3(16, 32), 256, 0, stream>>>(Ws, WsT);
    const int tier2 = (ws_size >= WS_T2);
    if (tier2) {
      kc_cvt<<<2048, 256, 0, stream>>>(states, sbf);
      f2c_sfgemm<<<dim3(16, 32), 256, 0, stream>>>(sbf, WsT, sfb);
    } else {
      f2d_sfgemm<<<dim3(16, 32), 256, 0, stream>>>(states, WsT, sfb);
    }
    f3f_align<<<dim3(1024, 2), 256, 0, stream>>>(A, sfb, v, C);
    (void)hipMemsetAsync(A, 0, (size_t)BT_ * D_ * 4, stream);
    f4_softmax<<<BT_, 256, 0, stream>>>(C, mask, attn);
    if (tier2)
      f5b_context<<<dim3(16, 2, 4), 256, 0, stream>>>(attn, sbf, A, C);
    else
      f5_context<<<dim3(16, 2, 4), 256, 0, stream>>>(attn, states, A, C);
    f6b_outproj<<<dim3(4, 8, 12), 256, 0, stream>>>(A, query, Wc, bc, Bh);
  } else {
    // ---------- fallback ----------
    k1_qf<<<BT_, 256, 0, stream>>>(query, Wq, bq, A);
    k23_align<<<B_ * (S_ / 16), 256, 0, stream>>>(states, Ws, v, A, C);
    k4_softmax<<<BT_, 256, 0, stream>>>(C, mask, A);
    k56_ctx_proj<<<BT_, 256, 0, stream>>>(A, states, query, Wc, bc, A, Bh, C);
  }
}

// Round 9
// 159.898 us; speedup vs baseline: 1.1517x; 1.0388x over previous
//
#include <hip/hip_runtime.h>
#include <math.h>

// Bahdanau additive attention. B=4, T=32, S=1024, H=512, D=2H=1024.
// Inputs fp32 (mask int32), OUTPUT fp32 flat:
//   context (4,32,1024) | hidden (4,32,512) | attn_t (4,1024,32)
// Round 24: R21 config (verified 164.5/166.1) + f3l occupancy fix: f3k ran at
// 1 wave/SIMD (256 blks x 4 waves on 1024 SIMDs -- rcp-latency-bound, no TLP).
// f3l splits t into halves via blockIdx.y: grid (256,2), 4 s x 16 t per wave.
// Eq L2 traffic UNCHANGED (2048 waves x 16 rows = 1024 x 32); waves/SIMD -> 2.
// Chain: memset(Bh) + prep(2944) + f2i(512) + f3l(256x2) + f5e(256) + f6c(256).
// d_out overlay: A[0,131072): ctx(final)  B[131072,196608): hidden(memset)
//                C[196608,327680): attn_t(final)

typedef unsigned short u16;
typedef __bf16 bf16x8 __attribute__((ext_vector_type(8)));
typedef float floatx4 __attribute__((ext_vector_type(4)));

#define B_ 4
#define T_ 32
#define S_ 1024
#define H_ 512
#define D_ 1024
#define BT_ 128
#define TWO_LOG2E 2.8853900817779268f   // tanh(y) = 1 - 2/(exp2(2*log2e*y)+1)
#define LOG2E 1.4426950408889634f

__device__ __forceinline__ float bf2f(u16 u) {
  unsigned int i = ((unsigned int)u) << 16;
  return __builtin_bit_cast(float, i);
}
__device__ __forceinline__ u16 f2bf(float f) {
  unsigned int i = __builtin_bit_cast(unsigned int, f);
  i += 0x7fffu + ((i >> 16) & 1u);  // RNE
  return (u16)(i >> 16);
}
__device__ __forceinline__ void ld_g2l_16(const u16* g, u16* l) {
  __builtin_amdgcn_global_load_lds((__attribute__((address_space(1))) void*)(u16*)g,
                                   (__attribute__((address_space(3))) void*)l, 16, 0, 0);
}

// ================= TIER-4 KERNELS =================

// ---- PREP6: heavy blocks FIRST so light blocks backfill (no serial tail).
//      [0,256)    qf split-K -> qfp partials (plain stores);
//      [256,384)  hidden query-part split-K atomics -> Bh (+bc on slice 0);
//      [384,896)  Ws^T -> WsT bf16 (block 384 zeroes rowsum);
//      [896,2944) states -> sbf + sbfT.
__global__ __launch_bounds__(256) void prep_fused6(const float* __restrict__ states, const float* __restrict__ Ws,
                                                   const float* __restrict__ query, const float* __restrict__ Wq,
                                                   const float* __restrict__ bq,
                                                   const float* __restrict__ Wc, const float* __restrict__ bc,
                                                   u16* __restrict__ sbf, u16* __restrict__ sbfT,
                                                   u16* __restrict__ WsT, float* __restrict__ qfp,
                                                   float* __restrict__ rowsum, float* __restrict__ hid) {
  __shared__ u16 tile[32][65];
  __shared__ float q[8][128];
  const int t = threadIdx.x;
  if (blockIdx.x < 256) {
    const int idx = blockIdx.x;                   // 0..255: qf split-K partials
    const int c0 = (idx & 3) * 256, r0 = ((idx >> 2) & 15) * 8, ks = idx >> 6;
    const int k0 = ks * 128;
    for (int i = t; i < 8 * 128; i += 256) {
      const int rl = i >> 7, kk = i & 127;
      q[rl][kk] = query[(size_t)(r0 + rl) * H_ + k0 + kk];
    }
    __syncthreads();
    const int col = c0 + t;
    float acc[8] = {};
    for (int kk = 0; kk < 128; ++kk) {
      const float w = Wq[(size_t)(k0 + kk) * D_ + col];
#pragma unroll
      for (int r = 0; r < 8; ++r) acc[r] = fmaf(q[r][kk], w, acc[r]);
    }
    const float bb = (ks == 0) ? bq[col] : 0.f;
    float* dst = qfp + (size_t)ks * (BT_ * D_);
#pragma unroll
    for (int r = 0; r < 8; ++r)
      dst[(size_t)(r0 + r) * D_ + col] = TWO_LOG2E * (acc[r] + bb);
  } else if (blockIdx.x < 384) {
    const int idx = blockIdx.x - 256;             // 0..127: hidden query-part
    const int c0 = (idx & 1) * 256, r0 = ((idx >> 1) & 15) * 8, ks = idx >> 5;
    const int k0 = ks * 128;
    for (int i = t; i < 8 * 128; i += 256) {
      const int rl = i >> 7, kk = i & 127;
      q[rl][kk] = query[(size_t)(r0 + rl) * H_ + k0 + kk];
    }
    __syncthreads();
    const int col = c0 + t;
    float acc[8] = {};
    for (int kk = 0; kk < 128; ++kk) {
      const float w = Wc[(size_t)(D_ + k0 + kk) * H_ + col];
#pragma unroll
      for (int r = 0; r < 8; ++r) acc[r] = fmaf(q[r][kk], w, acc[r]);
    }
    const float bb = (ks == 0) ? bc[col] : 0.f;
#pragma unroll
    for (int r = 0; r < 8; ++r)
      atomicAdd(&hid[(size_t)(r0 + r) * H_ + col], acc[r] + bb);
  } else if (blockIdx.x < 896) {
    const int bid = blockIdx.x - 384;             // 0..511: Ws transpose
    if (bid == 0 && t < 128) rowsum[t] = 0.f;     // zero rsum (read only by f3l)
    const int n0 = (bid & 15) * 64, k0 = (bid >> 4) * 32;
    const int kr = t >> 3, nc = (t & 7) * 8;
    const float* p = Ws + (size_t)(k0 + kr) * D_ + n0 + nc;
    float4 a = *(const float4*)p, b = *(const float4*)(p + 4);
    tile[kr][nc + 0] = f2bf(a.x); tile[kr][nc + 1] = f2bf(a.y);
    tile[kr][nc + 2] = f2bf(a.z); tile[kr][nc + 3] = f2bf(a.w);
    tile[kr][nc + 4] = f2bf(b.x); tile[kr][nc + 5] = f2bf(b.y);
    tile[kr][nc + 6] = f2bf(b.z); tile[kr][nc + 7] = f2bf(b.w);
    __syncthreads();
    const int nr = t >> 2, kc = (t & 3) * 8;
    union { uint4 v; u16 s[8]; } st;
#pragma unroll
    for (int i = 0; i < 8; ++i) st.s[i] = tile[kc + i][nr];
    *(uint4*)(WsT + (size_t)(n0 + nr) * D_ + k0 + kc) = st.v;
  } else {
    const int bid = blockIdx.x - 896;             // 0..2047: states cvt+transpose
    const int b = bid >> 9;
    const int r2 = bid & 511;
    const int d0 = (r2 & 15) * 64, s0 = (r2 >> 4) * 32;
    const int sr = t >> 3, dc = (t & 7) * 8;
    const float* p = states + ((size_t)b * S_ + s0 + sr) * D_ + d0 + dc;
    float4 a = *(const float4*)p, bb = *(const float4*)(p + 4);
    union { uint4 v; u16 s[8]; } pk;
    pk.s[0] = f2bf(a.x); pk.s[1] = f2bf(a.y); pk.s[2] = f2bf(a.z); pk.s[3] = f2bf(a.w);
    pk.s[4] = f2bf(bb.x); pk.s[5] = f2bf(bb.y); pk.s[6] = f2bf(bb.z); pk.s[7] = f2bf(bb.w);
    *(uint4*)(sbf + ((size_t)b * S_ + s0 + sr) * D_ + d0 + dc) = pk.v;
#pragma unroll
    for (int i = 0; i < 8; ++i) tile[sr][dc + i] = pk.s[i];
    __syncthreads();
    const int dr = t >> 2, sc = (t & 3) * 8;
    union { uint4 v; u16 s[8]; } st;
#pragma unroll
    for (int i = 0; i < 8; ++i) st.s[i] = tile[sc + i][dr];
    *(uint4*)(sbfT + ((size_t)b * D_ + d0 + dr) * S_ + s0 + sc) = st.v;
  }
}

// ---- F2i: Es = bf16(exp2(2log2e*(sbf @ Ws))); prologue Eq = exp2(sum qfp[ks]).
// Double-buffered global_load_lds prefetch, counted vmcnt(6), raw s_barrier;
// XOR-swizzled LDS reads.
__device__ __forceinline__ void f2f_stage(const u16* __restrict__ A, const u16* __restrict__ BT,
                                          u16* sAb, u16* sBb, int bm0, int bn0, int k0,
                                          int wv, int srow, int sp) {
#pragma unroll
  for (int j = 0; j < 4; ++j) {                  // A: rows wv*32 + j*8 + srow
    const int r = wv * 32 + j * 8 + srow;
    const int c = sp ^ (r & 7);
    ld_g2l_16(A + (size_t)(bm0 + r) * D_ + k0 + c * 8, sAb + (wv * 32 + j * 8) * 64);
  }
#pragma unroll
  for (int j = 0; j < 2; ++j) {                  // B: rows wv*16 + j*8 + srow
    const int r = wv * 16 + j * 8 + srow;
    const int c = sp ^ (r & 7);
    ld_g2l_16(BT + (size_t)(bn0 + r) * D_ + k0 + c * 8, sBb + (wv * 16 + j * 8) * 64);
  }
}

__device__ __forceinline__ void f2f_compute(const u16* sAb, const u16* sBb,
                                            int wm, int wn, int fm, int fq, floatx4 (&acc)[4][2]) {
#pragma unroll
  for (int win = 0; win < 2; ++win) {
    bf16x8 af[4], bfr[2];
#pragma unroll
    for (int i = 0; i < 4; ++i) {
      const int R = wm + i * 16 + fm;
      af[i] = *(const bf16x8*)&sAb[R * 64 + ((win * 4 + fq) ^ (R & 7)) * 8];
    }
#pragma unroll
    for (int j = 0; j < 2; ++j) {
      const int R = wn + j * 16 + fm;
      bfr[j] = *(const bf16x8*)&sBb[R * 64 + ((win * 4 + fq) ^ (R & 7)) * 8];
    }
#pragma unroll
    for (int i = 0; i < 4; ++i)
#pragma unroll
      for (int j = 0; j < 2; ++j)
        acc[i][j] = __builtin_amdgcn_mfma_f32_16x16x32_bf16(af[i], bfr[j], acc[i][j], 0, 0, 0);
  }
}

__global__ __launch_bounds__(256) void f2i_sfgemm(const u16* __restrict__ A, const u16* __restrict__ BT,
                                                  const float* __restrict__ qfp, float* __restrict__ Eq,
                                                  u16* __restrict__ Es) {
  __shared__ __align__(16) u16 sA[2][128 * 64];  // 2 x 16 KB
  __shared__ __align__(16) u16 sB[2][64 * 64];   // 2 x 8 KB
  const int bm0 = blockIdx.y * 128, bn0 = blockIdx.x * 64;
  const int t = threadIdx.x;
  const int wv = t >> 6, lane = t & 63;
  const int wm = (wv >> 1) * 64, wn = (wv & 1) * 32;
  const int fm = lane & 15, fq = lane >> 4;
  const int srow = lane >> 3, sp = lane & 7;

  // Eq transform: 512 blocks x 256 threads = 131072 = BT_*D_ elems.
  {
    const int bid = blockIdx.y * 16 + blockIdx.x;
    const int idx = bid * 256 + t;
    const float s = qfp[idx] + qfp[BT_ * D_ + idx] +
                    qfp[2 * BT_ * D_ + idx] + qfp[3 * BT_ * D_ + idx];
    Eq[idx] = __builtin_amdgcn_exp2f(s);         // prescaled by 2log2e
  }

  floatx4 acc[4][2];
  const floatx4 fz = {0.f, 0.f, 0.f, 0.f};
#pragma unroll
  for (int i = 0; i < 4; ++i) { acc[i][0] = fz; acc[i][1] = fz; }

  f2f_stage(A, BT, sA[0], sB[0], bm0, bn0, 0, wv, srow, sp);
#pragma unroll 1
  for (int k0 = 0; k0 < D_; k0 += 128) {
    // even phase: compute buf0, prefetch buf1(k0+64)
    f2f_stage(A, BT, sA[1], sB[1], bm0, bn0, k0 + 64, wv, srow, sp);
    asm volatile("s_waitcnt vmcnt(6)" ::: "memory");   // buf0's 6 loads landed
    __builtin_amdgcn_s_barrier();
    f2f_compute(sA[0], sB[0], wm, wn, fm, fq, acc);
    __builtin_amdgcn_s_barrier();                      // all waves done reading buf0
    // odd phase: compute buf1, prefetch buf0(k0+128)
    if (k0 + 128 < D_) {
      f2f_stage(A, BT, sA[0], sB[0], bm0, bn0, k0 + 128, wv, srow, sp);
      asm volatile("s_waitcnt vmcnt(6)" ::: "memory"); // buf1's 6 loads landed
    } else {
      asm volatile("s_waitcnt vmcnt(0)" ::: "memory");
    }
    __builtin_amdgcn_s_barrier();
    f2f_compute(sA[1], sB[1], wm, wn, fm, fq, acc);
    __builtin_amdgcn_s_barrier();
  }
#pragma unroll
  for (int i = 0; i < 4; ++i)
#pragma unroll
    for (int j = 0; j < 2; ++j)
#pragma unroll
      for (int r = 0; r < 4; ++r) {
        const int row = bm0 + wm + i * 16 + fq * 4 + r;   // col=lane&15, row=quad*4+reg (m89)
        const int col = bn0 + wn + j * 16 + fm;
        Es[(size_t)row * D_ + col] = f2bf(__builtin_amdgcn_exp2f(TWO_LOG2E * acc[i][j][r]));
      }
}

// ---- F3l: E = exp(alg), alg = sumv + sum_j vm2_j*rcp(fma(Eq,Es,1)).
// No-max softmax. 4 s-values x 16 t-rows per wave (t-half by blockIdx.y):
// same Eq L2 traffic as f3k but 2x waves -> 2 waves/SIMD hides rcp latency.
__global__ __launch_bounds__(256) void f3l_align(const float* __restrict__ Eq, const u16* __restrict__ Es,
                                                 const float* __restrict__ v, const int* __restrict__ mask,
                                                 u16* __restrict__ pbf, float* __restrict__ rowsum) {
  __shared__ float red[16][4];
  const int wv = threadIdx.x >> 6, lane = threadIdx.x & 63;
  const int w = blockIdx.x * 4 + wv;                      // 0..1023
  const int b = w >> 8;                                   // 256 waves per batch
  const int s0 = (w & 255) * 4;
  const int t0 = blockIdx.y * 16;
  const int m0 = mask[(size_t)b * S_ + s0 + 0];
  const int m1 = mask[(size_t)b * S_ + s0 + 1];
  const int m2 = mask[(size_t)b * S_ + s0 + 2];
  const int m3 = mask[(size_t)b * S_ + s0 + 3];
  float vm2[16], es0[16], es1[16], es2[16], es3[16];
  float sumv = 0.f;
  {
    union { uint4 u[2]; u16 h[16]; } u0, u1, u2, u3;
    const uint4* ep0 = (const uint4*)(Es + ((size_t)b * S_ + s0 + 0) * D_ + lane * 16);
    const uint4* ep1 = (const uint4*)(Es + ((size_t)b * S_ + s0 + 1) * D_ + lane * 16);
    const uint4* ep2 = (const uint4*)(Es + ((size_t)b * S_ + s0 + 2) * D_ + lane * 16);
    const uint4* ep3 = (const uint4*)(Es + ((size_t)b * S_ + s0 + 3) * D_ + lane * 16);
    u0.u[0] = ep0[0]; u0.u[1] = ep0[1];
    u1.u[0] = ep1[0]; u1.u[1] = ep1[1];
    u2.u[0] = ep2[0]; u2.u[1] = ep2[1];
    u3.u[0] = ep3[0]; u3.u[1] = ep3[1];
    const float4* vp = (const float4*)(v + lane * 16);
#pragma unroll
    for (int c = 0; c < 4; ++c) {
      const float4 w4 = vp[c];
      vm2[4 * c + 0] = -2.f * w4.x; vm2[4 * c + 1] = -2.f * w4.y;
      vm2[4 * c + 2] = -2.f * w4.z; vm2[4 * c + 3] = -2.f * w4.w;
      sumv += w4.x + w4.y + w4.z + w4.w;
    }
#pragma unroll
    for (int j = 0; j < 16; ++j) {
      es0[j] = bf2f(u0.h[j]); es1[j] = bf2f(u1.h[j]);
      es2[j] = bf2f(u2.h[j]); es3[j] = bf2f(u3.h[j]);
    }
  }
  const float* qbase = Eq + ((size_t)(b * T_ + t0)) * D_ + lane * 16;
  for (int tc = 0; tc < 4; ++tc) {               // 4 chunks of 4 t-rows (16 t total)
    float sa[4], sb[4], sc[4], sd[4];
#pragma unroll
    for (int ti = 0; ti < 4; ++ti) {
      const float4* qp = (const float4*)(qbase + (size_t)(tc * 4 + ti) * D_);
      float a0 = sumv, a1 = sumv, a2 = sumv, a3 = sumv;
#pragma unroll
      for (int c = 0; c < 4; ++c) {
        const float4 q4 = qp[c];
        const float xs[4] = {q4.x, q4.y, q4.z, q4.w};
#pragma unroll
        for (int u2 = 0; u2 < 4; ++u2) {
          const int j = 4 * c + u2;
          a0 = fmaf(vm2[j], __builtin_amdgcn_rcpf(fmaf(xs[u2], es0[j], 1.f)), a0);
          a1 = fmaf(vm2[j], __builtin_amdgcn_rcpf(fmaf(xs[u2], es1[j], 1.f)), a1);
          a2 = fmaf(vm2[j], __builtin_amdgcn_rcpf(fmaf(xs[u2], es2[j], 1.f)), a2);
          a3 = fmaf(vm2[j], __builtin_amdgcn_rcpf(fmaf(xs[u2], es3[j], 1.f)), a3);
        }
      }
      sa[ti] = a0; sb[ti] = a1; sc[ti] = a2; sd[ti] = a3;
    }
#pragma unroll
    for (int off = 32; off > 0; off >>= 1)
#pragma unroll
      for (int ti = 0; ti < 4; ++ti) {
        sa[ti] += __shfl_xor(sa[ti], off);
        sb[ti] += __shfl_xor(sb[ti], off);
        sc[ti] += __shfl_xor(sc[ti], off);
        sd[ti] += __shfl_xor(sd[ti], off);
      }
    if (lane == 0) {
#pragma unroll
      for (int ti = 0; ti < 4; ++ti) {
        const int tl = tc * 4 + ti;              // local t in [0,16)
        const int tt = t0 + tl;
        const float e0 = m0 ? __builtin_amdgcn_exp2f(sa[ti] * LOG2E) : 0.f;
        const float e1 = m1 ? __builtin_amdgcn_exp2f(sb[ti] * LOG2E) : 0.f;
        const float e2 = m2 ? __builtin_amdgcn_exp2f(sc[ti] * LOG2E) : 0.f;
        const float e3 = m3 ? __builtin_amdgcn_exp2f(sd[ti] * LOG2E) : 0.f;
        const u16 p0 = f2bf(e0), p1 = f2bf(e1), p2 = f2bf(e2), p3 = f2bf(e3);
        uint2 pk;
        pk.x = (unsigned int)p0 | ((unsigned int)p1 << 16);
        pk.y = (unsigned int)p2 | ((unsigned int)p3 << 16);
        *(uint2*)&pbf[((size_t)(b * T_ + tt)) * S_ + s0] = pk;
        red[tl][wv] = bf2f(p0) + bf2f(p1) + bf2f(p2) + bf2f(p3);
      }
    }
  }
  __syncthreads();
  if (threadIdx.x < 16) {
    const int bb = blockIdx.x >> 6;              // 64 x-blocks per batch
    const float rs = red[threadIdx.x][0] + red[threadIdx.x][1] +
                     red[threadIdx.x][2] + red[threadIdx.x][3];
    atomicAdd(&rowsum[bb * 32 + t0 + threadIdx.x], rs);
  }
}

// ---- F5e: ctx = (E @ states)/rowsum. 256 blocks (16 ctx-cols each); 4 waves
// split S into 256-chunks, LDS-reduce; normalization + attn_t slice folded.
__global__ __launch_bounds__(256) void f5e_context(const u16* __restrict__ pbf, const u16* __restrict__ sbfT,
                                                   const float* __restrict__ rowsum,
                                                   float* __restrict__ ctx, float* __restrict__ out_at) {
  __shared__ float rinv[32];
  __shared__ float red[4][64][9];
  const int b = blockIdx.x >> 6, dt = blockIdx.x & 63;
  const int wv = threadIdx.x >> 6, lane = threadIdx.x & 63;
  if (threadIdx.x < 32) rinv[threadIdx.x] = 1.f / rowsum[b * 32 + threadIdx.x];
  const int n0 = dt * 16;
  const int fm = lane & 15, fq = lane >> 4;
  const floatx4 fz = {0.f, 0.f, 0.f, 0.f};
  floatx4 acc0 = fz, acc1 = fz;
  const u16* pa0 = pbf + ((size_t)b * T_ + fm) * S_ + wv * 256 + fq * 8;
  const u16* pa1 = pa0 + (size_t)16 * S_;
  const u16* pb  = sbfT + ((size_t)b * D_ + n0 + fm) * S_ + wv * 256 + fq * 8;
#pragma unroll
  for (int k0 = 0; k0 < 256; k0 += 32) {
    bf16x8 a0 = *(const bf16x8*)(pa0 + k0);
    bf16x8 a1 = *(const bf16x8*)(pa1 + k0);
    bf16x8 bb = *(const bf16x8*)(pb + k0);
    acc0 = __builtin_amdgcn_mfma_f32_16x16x32_bf16(a0, bb, acc0, 0, 0, 0);
    acc1 = __builtin_amdgcn_mfma_f32_16x16x32_bf16(a1, bb, acc1, 0, 0, 0);
  }
#pragma unroll
  for (int r = 0; r < 4; ++r) {
    red[wv][lane][r] = acc0[r];
    red[wv][lane][4 + r] = acc1[r];
  }
  __syncthreads();
  // attn_t slice: s in [dt*16, dt*16+16), all 32 t. All threads.
  const int s0a = dt * 16;
  for (int i = threadIdx.x; i < 512; i += 256) {
    const int tt = i & 31, sl = i >> 5;
    const float e = bf2f(pbf[((size_t)(b * T_ + tt)) * S_ + s0a + sl]);
    out_at[((size_t)(b * S_ + s0a + sl)) * T_ + tt] = e * rinv[tt];
  }
  if (wv == 0) {
#pragma unroll
    for (int r = 0; r < 4; ++r) {
      const float v0 = red[0][lane][r] + red[1][lane][r] + red[2][lane][r] + red[3][lane][r];
      const float v1 = red[0][lane][4 + r] + red[1][lane][4 + r] +
                       red[2][lane][4 + r] + red[3][lane][4 + r];
      const int t0r = fq * 4 + r;
      ctx[((size_t)b * T_ + t0r) * D_ + n0 + fm] = v0 * rinv[t0r];
      ctx[((size_t)b * T_ + 16 + t0r) * D_ + n0 + fm] = v1 * rinv[16 + t0r];
    }
  }
}

// ---- F6c: hidden += ctx_kslice @ Wc[0:1024] (query part + bias done in prep). ----
__global__ __launch_bounds__(256) void f6c_outproj(const float* __restrict__ ctx,
                                                   const float* __restrict__ Wc,
                                                   float* __restrict__ out_hid) {
  __shared__ float cq[16][128];
  const int c0 = blockIdx.x * 128, r0 = blockIdx.y * 16, k0 = blockIdx.z * 128;
  const int tid = threadIdx.x;
  const int cl = tid & 127, rh = tid >> 7;
  for (int i = tid; i < 16 * 128; i += 256) {
    const int rl = i >> 7, kk = i & 127;
    cq[rl][kk] = ctx[(size_t)(r0 + rl) * D_ + k0 + kk];
  }
  __syncthreads();
  float acc[8] = {};
  for (int kk = 0; kk < 128; ++kk) {
    const float w = Wc[(size_t)(k0 + kk) * H_ + c0 + cl];
#pragma unroll
    for (int rr = 0; rr < 8; ++rr) acc[rr] = fmaf(cq[rh * 8 + rr][kk], w, acc[rr]);
  }
#pragma unroll
  for (int rr = 0; rr < 8; ++rr)
    atomicAdd(&out_hid[(size_t)(r0 + rh * 8 + rr) * H_ + c0 + cl], acc[rr]);
}

// ================= TIER-3 KERNELS =================

__global__ __launch_bounds__(256) void prep_fused(const float* __restrict__ states, const float* __restrict__ Ws,
                                                  const float* __restrict__ query, const float* __restrict__ Wq,
                                                  const float* __restrict__ bq,
                                                  u16* __restrict__ sbf, u16* __restrict__ sbfT,
                                                  u16* __restrict__ WsT, float* __restrict__ qf) {
  __shared__ u16 tile[32][65];
  __shared__ float q[8][128];
  const int t = threadIdx.x;
  if (blockIdx.x < 512) {
    const int n0 = (blockIdx.x & 15) * 64, k0 = (blockIdx.x >> 4) * 32;
    const int kr = t >> 3, nc = (t & 7) * 8;
    const float* p = Ws + (size_t)(k0 + kr) * D_ + n0 + nc;
    float4 a = *(const float4*)p, b = *(const float4*)(p + 4);
    tile[kr][nc + 0] = f2bf(a.x); tile[kr][nc + 1] = f2bf(a.y);
    tile[kr][nc + 2] = f2bf(a.z); tile[kr][nc + 3] = f2bf(a.w);
    tile[kr][nc + 4] = f2bf(b.x); tile[kr][nc + 5] = f2bf(b.y);
    tile[kr][nc + 6] = f2bf(b.z); tile[kr][nc + 7] = f2bf(b.w);
    __syncthreads();
    const int nr = t >> 2, kc = (t & 3) * 8;
    union { uint4 v; u16 s[8]; } st;
#pragma unroll
    for (int i = 0; i < 8; ++i) st.s[i] = tile[kc + i][nr];
    *(uint4*)(WsT + (size_t)(n0 + nr) * D_ + k0 + kc) = st.v;
  } else if (blockIdx.x < 2560) {
    const int bid = blockIdx.x - 512;
    const int b = bid >> 9;
    const int r2 = bid & 511;
    const int d0 = (r2 & 15) * 64, s0 = (r2 >> 4) * 32;
    const int sr = t >> 3, dc = (t & 7) * 8;
    const float* p = states + ((size_t)b * S_ + s0 + sr) * D_ + d0 + dc;
    float4 a = *(const float4*)p, bb = *(const float4*)(p + 4);
    union { uint4 v; u16 s[8]; } pk;
    pk.s[0] = f2bf(a.x); pk.s[1] = f2bf(a.y); pk.s[2] = f2bf(a.z); pk.s[3] = f2bf(a.w);
    pk.s[4] = f2bf(bb.x); pk.s[5] = f2bf(bb.y); pk.s[6] = f2bf(bb.z); pk.s[7] = f2bf(bb.w);
    *(uint4*)(sbf + ((size_t)b * S_ + s0 + sr) * D_ + d0 + dc) = pk.v;
#pragma unroll
    for (int i = 0; i < 8; ++i) tile[sr][dc + i] = pk.s[i];
    __syncthreads();
    const int dr = t >> 2, sc = (t & 3) * 8;
    union { uint4 v; u16 s[8]; } st;
#pragma unroll
    for (int i = 0; i < 8; ++i) st.s[i] = tile[sc + i][dr];
    *(uint4*)(sbfT + ((size_t)b * D_ + d0 + dr) * S_ + s0 + sc) = st.v;
  } else {
    const int idx = blockIdx.x - 2560;            // 0..255
    const int c0 = (idx & 3) * 256, r0 = ((idx >> 2) & 15) * 8, k0 = (idx >> 6) * 128;
    for (int i = t; i < 8 * 128; i += 256) {
      const int rl = i >> 7, kk = i & 127;
      q[rl][kk] = query[(size_t)(r0 + rl) * H_ + k0 + kk];
    }
    __syncthreads();
    const int col = c0 + t;
    float acc[8] = {};
    for (int kk = 0; kk < 128; ++kk) {
      const float w = Wq[(size_t)(k0 + kk) * D_ + col];
#pragma unroll
      for (int r = 0; r < 8; ++r) acc[r] = fmaf(q[r][kk], w, acc[r]);
    }
    const float bb = (k0 == 0) ? bq[col] : 0.f;
#pragma unroll
    for (int r = 0; r < 8; ++r)
      atomicAdd(&qf[(size_t)(r0 + r) * D_ + col], TWO_LOG2E * (acc[r] + bb));
  }
}

__global__ __launch_bounds__(256) void f2e_sfgemm(const u16* __restrict__ A, const u16* __restrict__ BT,
                                                  u16* __restrict__ Cb) {
  __shared__ __align__(16) u16 sA[128 * 64];   // 16 KB, row stride 64 u16
  __shared__ __align__(16) u16 sB[64 * 64];    // 8 KB
  const int bm0 = blockIdx.y * 128, bn0 = blockIdx.x * 64;
  const int t = threadIdx.x;
  const int wv = t >> 6, lane = t & 63;
  const int wm = (wv >> 1) * 64, wn = (wv & 1) * 32;
  const int fm = lane & 15, fq = lane >> 4;
  const int srow = lane >> 3, sp = lane & 7;   // staging: 8 rows x 8 chunks per inst

  floatx4 acc[4][2];
  const floatx4 fz = {0.f, 0.f, 0.f, 0.f};
#pragma unroll
  for (int i = 0; i < 4; ++i) { acc[i][0] = fz; acc[i][1] = fz; }

  for (int k0 = 0; k0 < D_; k0 += 64) {
    __syncthreads();                           // prev tile reads done
#pragma unroll
    for (int j = 0; j < 4; ++j) {              // A: rows wv*32 + j*8 + srow
      const int r = wv * 32 + j * 8 + srow;
      const int c = sp ^ (r & 7);
      ld_g2l_16(A + (size_t)(bm0 + r) * D_ + k0 + c * 8, &sA[(wv * 32 + j * 8) * 64]);
    }
#pragma unroll
    for (int j = 0; j < 2; ++j) {              // B: rows wv*16 + j*8 + srow
      const int r = wv * 16 + j * 8 + srow;
      const int c = sp ^ (r & 7);
      ld_g2l_16(BT + (size_t)(bn0 + r) * D_ + k0 + c * 8, &sB[(wv * 16 + j * 8) * 64]);
    }
    __syncthreads();                           // vmcnt(0) drains the async loads
#pragma unroll
    for (int win = 0; win < 2; ++win) {
      bf16x8 af[4], bfr[2];
#pragma unroll
      for (int i = 0; i < 4; ++i) {
        const int R = wm + i * 16 + fm;
        af[i] = *(const bf16x8*)&sA[R * 64 + ((win * 4 + fq) ^ (R & 7)) * 8];
      }
#pragma unroll
      for (int j = 0; j < 2; ++j) {
        const int R = wn + j * 16 + fm;
        bfr[j] = *(const bf16x8*)&sB[R * 64 + ((win * 4 + fq) ^ (R & 7)) * 8];
      }
#pragma unroll
      for (int i = 0; i < 4; ++i)
#pragma unroll
        for (int j = 0; j < 2; ++j)
          acc[i][j] = __builtin_amdgcn_mfma_f32_16x16x32_bf16(af[i], bfr[j], acc[i][j], 0, 0, 0);
    }
  }
#pragma unroll
  for (int i = 0; i < 4; ++i)
#pragma unroll
    for (int j = 0; j < 2; ++j)
#pragma unroll
      for (int r = 0; r < 4; ++r) {
        const int row = bm0 + wm + i * 16 + fq * 4 + r;   // col=lane&15, row=quad*4+reg (m89)
        const int col = bn0 + wn + j * 16 + fm;
        Cb[(size_t)row * D_ + col] = f2bf(TWO_LOG2E * acc[i][j][r]);
      }
}

__global__ __launch_bounds__(256, 6) void f3f_align(const float* __restrict__ qf, const u16* __restrict__ sfb,
                                                    const float* __restrict__ v, float* __restrict__ alg) {
  const int wid = (blockIdx.x * 256 + threadIdx.x) >> 6;  // b*1024+s
  const int lane = threadIdx.x & 63;
  const int b = wid >> 10, s = wid & 1023;
  const int t0 = blockIdx.y * 16;
  float vr[16], sr[16];
  {
    union { uint4 v[2]; u16 s[16]; } u;
    const uint4* sp = (const uint4*)(sfb + (size_t)wid * D_ + lane * 16);
    u.v[0] = sp[0]; u.v[1] = sp[1];
    const float* vp = v + lane * 16;
#pragma unroll
    for (int c = 0; c < 4; ++c) {
      float4 w = *(const float4*)(vp + 4 * c);
      vr[4 * c + 0] = w.x; vr[4 * c + 1] = w.y; vr[4 * c + 2] = w.z; vr[4 * c + 3] = w.w;
    }
#pragma unroll
    for (int j = 0; j < 16; ++j) sr[j] = bf2f(u.s[j]);
  }
  float sum[16];
#pragma unroll
  for (int tt = 0; tt < 16; ++tt) sum[tt] = 0.f;

  const float* qbase = qf + ((size_t)(b * T_ + t0)) * D_ + lane * 16;
  for (int tt = 0; tt < 16; ++tt) {
    const float4* qp = (const float4*)(qbase + (size_t)tt * D_);
    float acc = 0.f;
#pragma unroll
    for (int c = 0; c < 4; ++c) {
      float4 q4 = qp[c];
      float xs[4] = {q4.x, q4.y, q4.z, q4.w};
#pragma unroll
      for (int u2 = 0; u2 < 4; ++u2) {
        const int j = 4 * c + u2;
        const float x = xs[u2] + sr[j];                        // prescaled by 2log2e
        const float e = __builtin_amdgcn_exp2f(x);
        acc = fmaf(vr[j], fmaf(-2.f, __builtin_amdgcn_rcpf(e + 1.f), 1.f), acc);
      }
    }
    sum[tt] = acc;
  }
#pragma unroll
  for (int off = 32; off > 0; off >>= 1)
#pragma unroll
    for (int tt = 0; tt < 16; ++tt) sum[tt] += __shfl_xor(sum[tt], off);
  if (lane == 0) {
#pragma unroll
    for (int tt = 0; tt < 16; ++tt)
      alg[((size_t)(b * T_ + t0 + tt)) * S_ + s] = sum[tt];
  }
}

__global__ __launch_bounds__(256) void f4b_softmax(const float* __restrict__ alg, const int* __restrict__ mask,
                                                   float* __restrict__ out_at, u16* __restrict__ pbf) {
  const int r = blockIdx.x;                    // b*T+t
  const int b = r >> 5, t = r & 31;
  const int tid = threadIdx.x;
  __shared__ float red[256];
  float a[4];
#pragma unroll
  for (int jj = 0; jj < 4; ++jj) {
    const int s = tid + 256 * jj;
    const float x = alg[(size_t)r * S_ + s];
    a[jj] = (mask[(size_t)b * S_ + s] != 0) ? x : -3.0e38f;
  }
  float m = fmaxf(fmaxf(a[0], a[1]), fmaxf(a[2], a[3]));
  red[tid] = m; __syncthreads();
  for (int st = 128; st > 0; st >>= 1) { if (tid < st) red[tid] = fmaxf(red[tid], red[tid + st]); __syncthreads(); }
  m = red[0]; __syncthreads();
  float e[4], lsum = 0.f;
#pragma unroll
  for (int jj = 0; jj < 4; ++jj) {
    e[jj] = (a[jj] > -1.0e38f) ? expf(a[jj] - m) : 0.f;
    lsum += e[jj];
  }
  red[tid] = lsum; __syncthreads();
  for (int st = 128; st > 0; st >>= 1) { if (tid < st) red[tid] += red[tid + st]; __syncthreads(); }
  const float rs = 1.f / red[0];
#pragma unroll
  for (int jj = 0; jj < 4; ++jj) {
    const int s = tid + 256 * jj;
    const float p = e[jj] * rs;
    out_at[((size_t)b * S_ + s) * T_ + t] = p;
    pbf[(size_t)r * S_ + s] = f2bf(p);
  }
}

__global__ __launch_bounds__(256) void f5c_context(const u16* __restrict__ pbf, const u16* __restrict__ sbfT,
                                                   float* __restrict__ ctx) {
  const int b = blockIdx.x >> 4, dt = blockIdx.x & 15;
  const int wv = threadIdx.x >> 6, lane = threadIdx.x & 63;
  const int n0 = dt * 64 + wv * 16;
  const int fm = lane & 15, fq = lane >> 4;
  const floatx4 fz = {0.f, 0.f, 0.f, 0.f};
  floatx4 acc0 = fz, acc1 = fz;
  const u16* pa0 = pbf + ((size_t)b * T_ + fm) * S_ + fq * 8;
  const u16* pa1 = pbf + ((size_t)b * T_ + 16 + fm) * S_ + fq * 8;
  const u16* pb  = sbfT + ((size_t)b * D_ + n0 + fm) * S_ + fq * 8;
#pragma unroll 4
  for (int k0 = 0; k0 < S_; k0 += 32) {
    bf16x8 a0 = *(const bf16x8*)(pa0 + k0);
    bf16x8 a1 = *(const bf16x8*)(pa1 + k0);
    bf16x8 bb = *(const bf16x8*)(pb + k0);
    acc0 = __builtin_amdgcn_mfma_f32_16x16x32_bf16(a0, bb, acc0, 0, 0, 0);
    acc1 = __builtin_amdgcn_mfma_f32_16x16x32_bf16(a1, bb, acc1, 0, 0, 0);
  }
  const int col = n0 + fm;
#pragma unroll
  for (int r = 0; r < 4; ++r) {
    ctx[((size_t)b * T_ + fq * 4 + r) * D_ + col] = acc0[r];
    ctx[((size_t)b * T_ + 16 + fq * 4 + r) * D_ + col] = acc1[r];
  }
}

__global__ __launch_bounds__(256) void f6b_outproj(const float* __restrict__ ctx, const float* __restrict__ query,
                                                   const float* __restrict__ Wc, const float* __restrict__ bc,
                                                   float* __restrict__ out_hid) {
  __shared__ float cq[16][128];
  const int c0 = blockIdx.x * 128, r0 = blockIdx.y * 16, k0 = blockIdx.z * 128;
  const int tid = threadIdx.x;
  const int cl = tid & 127, rh = tid >> 7;
  for (int i = tid; i < 16 * 128; i += 256) {
    const int rl = i >> 7, kk = i & 127;
    const int k = k0 + kk, row = r0 + rl;
    cq[rl][kk] = (k < D_) ? ctx[(size_t)row * D_ + k] : query[(size_t)row * H_ + k - D_];
  }
  __syncthreads();
  float acc[8] = {};
  for (int kk = 0; kk < 128; ++kk) {
    const float w = Wc[(size_t)(k0 + kk) * H_ + c0 + cl];
#pragma unroll
    for (int rr = 0; rr < 8; ++rr) acc[rr] = fmaf(cq[rh * 8 + rr][kk], w, acc[rr]);
  }
  const float bb = (blockIdx.z == 0) ? bc[c0 + cl] : 0.f;
#pragma unroll
  for (int rr = 0; rr < 8; ++rr)
    atomicAdd(&out_hid[(size_t)(r0 + rh * 8 + rr) * H_ + c0 + cl], acc[rr] + bb);
}

// ================= TIER-1/2 EXTRAS =================

__global__ __launch_bounds__(256) void kc_cvt(const float* __restrict__ in, u16* __restrict__ out) {
  const size_t i0 = ((size_t)blockIdx.x * 256 + threadIdx.x) * 8;
  float4 a = *(const float4*)(in + i0);
  float4 b = *(const float4*)(in + i0 + 4);
  union { uint4 v; u16 s[8]; } r;
  r.s[0] = f2bf(a.x); r.s[1] = f2bf(a.y); r.s[2] = f2bf(a.z); r.s[3] = f2bf(a.w);
  r.s[4] = f2bf(b.x); r.s[5] = f2bf(b.y); r.s[6] = f2bf(b.z); r.s[7] = f2bf(b.w);
  *(uint4*)(out + i0) = r.v;
}

__global__ __launch_bounds__(256) void f0_transpose(const float* __restrict__ Ws, u16* __restrict__ WsT) {
  __shared__ u16 tile[32][65];
  const int n0 = blockIdx.x * 64, k0 = blockIdx.y * 32;
  const int t = threadIdx.x;
  {
    const int kr = t >> 3, nc = (t & 7) * 8;
    const float* p = Ws + (size_t)(k0 + kr) * D_ + n0 + nc;
    float4 a = *(const float4*)p, b = *(const float4*)(p + 4);
    tile[kr][nc + 0] = f2bf(a.x); tile[kr][nc + 1] = f2bf(a.y);
    tile[kr][nc + 2] = f2bf(a.z); tile[kr][nc + 3] = f2bf(a.w);
    tile[kr][nc + 4] = f2bf(b.x); tile[kr][nc + 5] = f2bf(b.y);
    tile[kr][nc + 6] = f2bf(b.z); tile[kr][nc + 7] = f2bf(b.w);
  }
  __syncthreads();
  {
    const int nr = t >> 2, kc = (t & 3) * 8;
    union { uint4 v; u16 s[8]; } st;
#pragma unroll
    for (int i = 0; i < 8; ++i) st.s[i] = tile[kc + i][nr];
    *(uint4*)(WsT + (size_t)(n0 + nr) * D_ + k0 + kc) = st.v;
  }
}

__global__ __launch_bounds__(256) void f1b_qf(const float* __restrict__ query, const float* __restrict__ Wq,
                                              const float* __restrict__ bq, float* __restrict__ qf) {
  __shared__ float q[8][128];
  const int c0 = blockIdx.x * 256, r0 = blockIdx.y * 8, k0 = blockIdx.z * 128;
  const int tid = threadIdx.x;
  for (int i = tid; i < 8 * 128; i += 256) {
    const int rl = i >> 7, kk = i & 127;
    q[rl][kk] = query[(size_t)(r0 + rl) * H_ + k0 + kk];
  }
  __syncthreads();
  const int col = c0 + tid;
  float acc[8] = {};
  for (int kk = 0; kk < 128; ++kk) {
    const float w = Wq[(size_t)(k0 + kk) * D_ + col];
#pragma unroll
    for (int r = 0; r < 8; ++r) acc[r] = fmaf(q[r][kk], w, acc[r]);
  }
  const float bb = (blockIdx.z == 0) ? bq[col] : 0.f;
#pragma unroll
  for (int r = 0; r < 8; ++r)
    atomicAdd(&qf[(size_t)(r0 + r) * D_ + col], TWO_LOG2E * (acc[r] + bb));
}

__global__ __launch_bounds__(256) void f2c_sfgemm(const u16* __restrict__ A, const u16* __restrict__ BT,
                                                  u16* __restrict__ Cb) {
  __shared__ __align__(16) u16 sA[128 * 40];
  __shared__ __align__(16) u16 sB[64 * 40];
  const int bm0 = blockIdx.y * 128, bn0 = blockIdx.x * 64;
  const int t = threadIdx.x;
  const int wv = t >> 6, lane = t & 63;
  const int wm = (wv >> 1) * 64, wn = (wv & 1) * 32;
  const int fm = lane & 15, fq = lane >> 4;
  const int arow = t >> 1, akc = (t & 1) * 16;
  const int brow = t >> 2, bkc = (t & 3) * 8;
  floatx4 acc[4][2];
  const floatx4 fz = {0.f, 0.f, 0.f, 0.f};
#pragma unroll
  for (int i = 0; i < 4; ++i) { acc[i][0] = fz; acc[i][1] = fz; }
  const uint4* gA = (const uint4*)(A + (size_t)(bm0 + arow) * D_ + akc);
  const uint4* gB = (const uint4*)(BT + (size_t)(bn0 + brow) * D_ + bkc);
  for (int k0 = 0; k0 < D_; k0 += 32) {
    uint4 va0 = gA[k0 >> 3];
    uint4 va1 = gA[(k0 >> 3) + 1];
    uint4 vb = gB[k0 >> 3];
    __syncthreads();
    *(uint4*)&sA[arow * 40 + akc] = va0;
    *(uint4*)&sA[arow * 40 + akc + 8] = va1;
    *(uint4*)&sB[brow * 40 + bkc] = vb;
    __syncthreads();
    bf16x8 af[4], bfr[2];
#pragma unroll
    for (int i = 0; i < 4; ++i) af[i] = *(const bf16x8*)&sA[(wm + i * 16 + fm) * 40 + fq * 8];
#pragma unroll
    for (int j = 0; j < 2; ++j) bfr[j] = *(const bf16x8*)&sB[(wn + j * 16 + fm) * 40 + fq * 8];
#pragma unroll
    for (int i = 0; i < 4; ++i)
#pragma unroll
      for (int j = 0; j < 2; ++j)
        acc[i][j] = __builtin_amdgcn_mfma_f32_16x16x32_bf16(af[i], bfr[j], acc[i][j], 0, 0, 0);
  }
#pragma unroll
  for (int i = 0; i < 4; ++i)
#pragma unroll
    for (int j = 0; j < 2; ++j)
#pragma unroll
      for (int r = 0; r < 4; ++r) {
        const int row = bm0 + wm + i * 16 + fq * 4 + r;
        const int col = bn0 + wn + j * 16 + fm;
        Cb[(size_t)row * D_ + col] = f2bf(TWO_LOG2E * acc[i][j][r]);
      }
}

__global__ __launch_bounds__(256) void f2d_sfgemm(const float* __restrict__ A, const u16* __restrict__ BT,
                                                  u16* __restrict__ Cb) {
  __shared__ __align__(16) u16 sA[128 * 40];
  __shared__ __align__(16) u16 sB[64 * 40];
  const int bm0 = blockIdx.y * 128, bn0 = blockIdx.x * 64;
  const int t = threadIdx.x;
  const int wv = t >> 6, lane = t & 63;
  const int wm = (wv >> 1) * 64, wn = (wv & 1) * 32;
  const int fm = lane & 15, fq = lane >> 4;
  const int arow = t >> 1, akc = (t & 1) * 16;
  const int brow = t >> 2, bkc = (t & 3) * 8;
  floatx4 acc[4][2];
  const floatx4 fz = {0.f, 0.f, 0.f, 0.f};
#pragma unroll
  for (int i = 0; i < 4; ++i) { acc[i][0] = fz; acc[i][1] = fz; }
  const float* gA = A + (size_t)(bm0 + arow) * D_ + akc;
  const uint4* gB = (const uint4*)(BT + (size_t)(bn0 + brow) * D_ + bkc);
  for (int k0 = 0; k0 < D_; k0 += 32) {
    float4 a0 = *(const float4*)(gA + k0);
    float4 a1 = *(const float4*)(gA + k0 + 4);
    float4 a2 = *(const float4*)(gA + k0 + 8);
    float4 a3 = *(const float4*)(gA + k0 + 12);
    uint4 vb = gB[k0 >> 3];
    union { uint4 v[2]; u16 s[16]; } pa;
    pa.s[0] = f2bf(a0.x); pa.s[1] = f2bf(a0.y); pa.s[2] = f2bf(a0.z); pa.s[3] = f2bf(a0.w);
    pa.s[4] = f2bf(a1.x); pa.s[5] = f2bf(a1.y); pa.s[6] = f2bf(a1.z); pa.s[7] = f2bf(a1.w);
    pa.s[8] = f2bf(a2.x); pa.s[9] = f2bf(a2.y); pa.s[10] = f2bf(a2.z); pa.s[11] = f2bf(a2.w);
    pa.s[12] = f2bf(a3.x); pa.s[13] = f2bf(a3.y); pa.s[14] = f2bf(a3.z); pa.s[15] = f2bf(a3.w);
    __syncthreads();
    *(uint4*)&sA[arow * 40 + akc] = pa.v[0];
    *(uint4*)&sA[arow * 40 + akc + 8] = pa.v[1];
    *(uint4*)&sB[brow * 40 + bkc] = vb;
    __syncthreads();
    bf16x8 af[4], bfr[2];
#pragma unroll
    for (int i = 0; i < 4; ++i) af[i] = *(const bf16x8*)&sA[(wm + i * 16 + fm) * 40 + fq * 8];
#pragma unroll
    for (int j = 0; j < 2; ++j) bfr[j] = *(const bf16x8*)&sB[(wn + j * 16 + fm) * 40 + fq * 8];
#pragma unroll
    for (int i = 0; i < 4; ++i)
#pragma unroll
      for (int j = 0; j < 2; ++j)
        acc[i][j] = __builtin_amdgcn_mfma_f32_16x16x32_bf16(af[i], bfr[j], acc[i][j], 0, 0, 0);
  }
#pragma unroll
  for (int i = 0; i < 4; ++i)
#pragma unroll
    for (int j = 0; j < 2; ++j)
#pragma unroll
      for (int r = 0; r < 4; ++r) {
        const int row = bm0 + wm + i * 16 + fq * 4 + r;
        const int col = bn0 + wn + j * 16 + fm;
        Cb[(size_t)row * D_ + col] = f2bf(TWO_LOG2E * acc[i][j][r]);
      }
}

__global__ __launch_bounds__(256) void f4_softmax(const float* __restrict__ alg, const int* __restrict__ mask,
                                                  float* __restrict__ attn) {
  const int r = blockIdx.x;
  const int b = r >> 5;
  const int tid = threadIdx.x;
  __shared__ float red[256];
  float a[4];
#pragma unroll
  for (int jj = 0; jj < 4; ++jj) {
    const int s = tid + 256 * jj;
    const float x = alg[(size_t)r * S_ + s];
    a[jj] = (mask[(size_t)b * S_ + s] != 0) ? x : -3.0e38f;
  }
  float m = fmaxf(fmaxf(a[0], a[1]), fmaxf(a[2], a[3]));
  red[tid] = m; __syncthreads();
  for (int st = 128; st > 0; st >>= 1) { if (tid < st) red[tid] = fmaxf(red[tid], red[tid + st]); __syncthreads(); }
  m = red[0]; __syncthreads();
  float e[4], lsum = 0.f;
#pragma unroll
  for (int jj = 0; jj < 4; ++jj) {
    e[jj] = (a[jj] > -1.0e38f) ? expf(a[jj] - m) : 0.f;
    lsum += e[jj];
  }
  red[tid] = lsum; __syncthreads();
  for (int st = 128; st > 0; st >>= 1) { if (tid < st) red[tid] += red[tid + st]; __syncthreads(); }
  const float rs = 1.f / red[0];
#pragma unroll
  for (int jj = 0; jj < 4; ++jj)
    attn[(size_t)r * S_ + tid + 256 * jj] = e[jj] * rs;
}

__global__ __launch_bounds__(256) void f5b_context(const float* __restrict__ attn, const u16* __restrict__ sbf,
                                                   float* __restrict__ ctx, float* __restrict__ out_at) {
  __shared__ float at[16][64];
  const int s0 = blockIdx.x * 64, t0 = blockIdx.y * 16, b = blockIdx.z;
  const int tid = threadIdx.x;
  for (int i = tid; i < 16 * 64; i += 256) {
    const int tl = i >> 6, sl = i & 63;
    at[tl][sl] = attn[(size_t)(b * T_ + t0 + tl) * S_ + s0 + sl];
  }
  __syncthreads();
  for (int i = tid; i < 64 * 16; i += 256) {
    const int sl = i >> 4, tl = i & 15;
    out_at[((size_t)b * S_ + s0 + sl) * T_ + t0 + tl] = at[tl][sl];
  }
  float acc[16][4] = {};
  for (int sl = 0; sl < 64; ++sl) {
    const u16* srow = sbf + ((size_t)b * S_ + s0 + sl) * D_ + tid;
    float sv[4];
#pragma unroll
    for (int jj = 0; jj < 4; ++jj) sv[jj] = bf2f(srow[256 * jj]);
#pragma unroll
    for (int tl = 0; tl < 16; ++tl) {
      const float w = at[tl][sl];
#pragma unroll
      for (int jj = 0; jj < 4; ++jj) acc[tl][jj] = fmaf(w, sv[jj], acc[tl][jj]);
    }
  }
#pragma unroll
  for (int tl = 0; tl < 16; ++tl)
#pragma unroll
    for (int jj = 0; jj < 4; ++jj)
      atomicAdd(&ctx[(size_t)(b * T_ + t0 + tl) * D_ + tid + 256 * jj], acc[tl][jj]);
}

__global__ __launch_bounds__(256) void f5_context(const float* __restrict__ attn, const float* __restrict__ states,
                                                  float* __restrict__ ctx, float* __restrict__ out_at) {
  __shared__ float at[16][64];
  const int s0 = blockIdx.x * 64, t0 = blockIdx.y * 16, b = blockIdx.z;
  const int tid = threadIdx.x;
  for (int i = tid; i < 16 * 64; i += 256) {
    const int tl = i >> 6, sl = i & 63;
    at[tl][sl] = attn[(size_t)(b * T_ + t0 + tl) * S_ + s0 + sl];
  }
  __syncthreads();
  for (int i = tid; i < 64 * 16; i += 256) {
    const int sl = i >> 4, tl = i & 15;
    out_at[((size_t)b * S_ + s0 + sl) * T_ + t0 + tl] = at[tl][sl];
  }
  float acc[16][4] = {};
  for (int sl = 0; sl < 64; ++sl) {
    const float* srow = states + ((size_t)b * S_ + s0 + sl) * D_ + tid;
    float sv[4];
#pragma unroll
    for (int jj = 0; jj < 4; ++jj) sv[jj] = srow[256 * jj];
#pragma unroll
    for (int tl = 0; tl < 16; ++tl) {
      const float w = at[tl][sl];
#pragma unroll
      for (int jj = 0; jj < 4; ++jj) acc[tl][jj] = fmaf(w, sv[jj], acc[tl][jj]);
    }
  }
#pragma unroll
  for (int tl = 0; tl < 16; ++tl)
#pragma unroll
    for (int jj = 0; jj < 4; ++jj)
      atomicAdd(&ctx[(size_t)(b * T_ + t0 + tl) * D_ + tid + 256 * jj], acc[tl][jj]);
}

// ================= FALLBACK (round-7, passing) =================

__global__ __launch_bounds__(256) void k1_qf(const float* __restrict__ query, const float* __restrict__ Wq,
                                             const float* __restrict__ bq, float* __restrict__ qf) {
  const int r = blockIdx.x;
  const int tid = threadIdx.x;
  __shared__ float q[H_];
  for (int i = tid; i < H_; i += 256) q[i] = query[(size_t)r * H_ + i];
  __syncthreads();
#pragma unroll
  for (int jj = 0; jj < 4; ++jj) {
    const int j = tid + 256 * jj;
    float acc = bq[j];
    for (int k = 0; k < H_; ++k) acc = fmaf(q[k], Wq[(size_t)k * D_ + j], acc);
    qf[(size_t)r * D_ + j] = acc;
  }
}

__global__ __launch_bounds__(256) void k23_align(const float* __restrict__ states, const float* __restrict__ Ws,
                                                 const float* __restrict__ v, const float* __restrict__ qf,
                                                 float* __restrict__ alg) {
  const int b = blockIdx.x >> 6;
  const int s0 = (blockIdx.x & 63) * 16;
  const int tid = threadIdx.x, lane = tid & 63, wv = tid >> 6;
  __shared__ u16 stL[16 * D_];
  __shared__ float vvL[D_];
  __shared__ float red[16 * 4];
  for (int i = tid; i < 16 * D_; i += 256) {
    const int row = i >> 10, col = i & (D_ - 1);
    stL[i] = f2bf(states[((size_t)b * S_ + s0 + row) * D_ + col]);
  }
  for (int i = tid; i < D_; i += 256) vvL[i] = v[i];
  __syncthreads();
  float acc[64];
#pragma unroll
  for (int i = 0; i < 64; ++i) acc[i] = 0.f;
#pragma unroll 4
  for (int k = 0; k < D_; ++k) {
    float wsv[4];
#pragma unroll
    for (int jj = 0; jj < 4; ++jj) wsv[jj] = Ws[(size_t)k * D_ + tid + 256 * jj];
#pragma unroll
    for (int i = 0; i < 16; ++i) {
      const float sv = bf2f(stL[i * D_ + k]);
#pragma unroll
      for (int jj = 0; jj < 4; ++jj) acc[i * 4 + jj] = fmaf(sv, wsv[jj], acc[i * 4 + jj]);
    }
  }
  for (int t = 0; t < T_; ++t) {
    float qv[4];
#pragma unroll
    for (int jj = 0; jj < 4; ++jj) qv[jj] = qf[((size_t)b * T_ + t) * D_ + tid + 256 * jj];
    float part[16];
#pragma unroll
    for (int i = 0; i < 16; ++i) {
      float p = 0.f;
#pragma unroll
      for (int jj = 0; jj < 4; ++jj)
        p = fmaf(vvL[tid + 256 * jj], tanhf(qv[jj] + acc[i * 4 + jj]), p);
      part[i] = p;
    }
#pragma unroll
    for (int i = 0; i < 16; ++i) {
      float x = part[i];
#pragma unroll
      for (int off = 32; off > 0; off >>= 1) x += __shfl_xor(x, off);
      if (lane == 0) red[i * 4 + wv] = x;
    }
    __syncthreads();
    if (tid < 16)
      alg[((size_t)b * T_ + t) * S_ + s0 + tid] =
          red[tid * 4 + 0] + red[tid * 4 + 1] + red[tid * 4 + 2] + red[tid * 4 + 3];
    __syncthreads();
  }
}

__global__ __launch_bounds__(256) void k4_softmax(const float* __restrict__ alg, const int* __restrict__ mask,
                                                  float* __restrict__ attn) {
  const int r = blockIdx.x;
  const int b = r >> 5;
  const int tid = threadIdx.x;
  __shared__ float red[256];
  float a[4];
#pragma unroll
  for (int jj = 0; jj < 4; ++jj) {
    const int s = tid + 256 * jj;
    const float x = alg[(size_t)r * S_ + s];
    a[jj] = (mask[(size_t)b * S_ + s] != 0) ? x : -3.0e38f;
  }
  float m = fmaxf(fmaxf(a[0], a[1]), fmaxf(a[2], a[3]));
  red[tid] = m; __syncthreads();
  for (int st = 128; st > 0; st >>= 1) { if (tid < st) red[tid] = fmaxf(red[tid], red[tid + st]); __syncthreads(); }
  m = red[0]; __syncthreads();
  float e[4], lsum = 0.f;
#pragma unroll
  for (int jj = 0; jj < 4; ++jj) {
    e[jj] = (a[jj] > -1.0e38f) ? expf(a[jj] - m) : 0.f;
    lsum += e[jj];
  }
  red[tid] = lsum; __syncthreads();
  for (int st = 128; st > 0; st >>= 1) { if (tid < st) red[tid] += red[tid + st]; __syncthreads(); }
  const float rs = 1.f / red[0];
#pragma unroll
  for (int jj = 0; jj < 4; ++jj)
    attn[(size_t)r * S_ + tid + 256 * jj] = e[jj] * rs;
}

__global__ __launch_bounds__(256) void k56_ctx_proj(const float* __restrict__ attn, const float* __restrict__ states,
                                                    const float* __restrict__ query, const float* __restrict__ Wc,
                                                    const float* __restrict__ bc,
                                                    float* __restrict__ out_ctx, float* __restrict__ out_hid,
                                                    float* __restrict__ out_at) {
  const int r = blockIdx.x;
  const int b = r >> 5, t = r & (T_ - 1);
  const int tid = threadIdx.x;
  __shared__ float pr[S_];
  __shared__ float cq[D_ + H_];
  for (int s = tid; s < S_; s += 256) pr[s] = attn[(size_t)r * S_ + s];
  __syncthreads();
  for (int s = tid; s < S_; s += 256) out_at[((size_t)b * S_ + s) * T_ + t] = pr[s];
  float acc[4] = {0.f, 0.f, 0.f, 0.f};
  for (int s = 0; s < S_; ++s) {
    const float w = pr[s];
    const float* srow = states + ((size_t)b * S_ + s) * D_ + tid;
#pragma unroll
    for (int jj = 0; jj < 4; ++jj) acc[jj] = fmaf(w, srow[256 * jj], acc[jj]);
  }
#pragma unroll
  for (int jj = 0; jj < 4; ++jj) {
    cq[tid + 256 * jj] = acc[jj];
    out_ctx[(size_t)r * D_ + tid + 256 * jj] = acc[jj];
  }
  for (int i = tid; i < H_; i += 256) cq[D_ + i] = query[(size_t)r * H_ + i];
  __syncthreads();
#pragma unroll
  for (int jj = 0; jj < 2; ++jj) {
    const int n = tid + 256 * jj;
    float h = bc[n];
    for (int k = 0; k < D_ + H_; ++k) h = fmaf(cq[k], Wc[(size_t)k * H_ + n], h);
    out_hid[(size_t)r * H_ + n] = h;
  }
}

extern "C" void kernel_launch(void* const* d_in, const int* in_sizes, int n_in,
                              void* d_out, int out_size, void* d_ws, size_t ws_size,
                              hipStream_t stream) {
  const float* query  = (const float*)d_in[0];
  const float* states = (const float*)d_in[1];
  const int*   mask   = (const int*)d_in[2];
  const float* Wq     = (const float*)d_in[3];
  const float* bq     = (const float*)d_in[4];
  const float* Ws     = (const float*)d_in[5];
  const float* v      = (const float*)d_in[6];
  const float* Wc     = (const float*)d_in[7];
  const float* bc     = (const float*)d_in[8];

  float* A  = (float*)d_out;               // ctx(final)
  float* Bh = A + (size_t)BT_ * D_;        // hidden
  float* C  = Bh + (size_t)BT_ * H_;       // attn_t

  char* ws = (char*)d_ws;
  u16*   sfb  = (u16*)(ws + 0);
  u16*   WsT  = (u16*)(ws + 8388608);
  float* alg  = (float*)(ws + 10485760);
  u16*   sbf  = (u16*)(ws + 11010048);
  u16*   sbfT = (u16*)(ws + 19398656);
  u16*   pbf  = (u16*)(ws + 27787264);

  const size_t WS_T1 = 11010048;
  const size_t WS_T2 = 19398656;
  const size_t WS_T3 = 28049408;
  const size_t WS_T4 = 36962816;   // + Es16 (8.4MB) + Eq (512KB) + rsum (512B); qfp reuses [0,2MB)

  if (ws_size >= WS_T4) {
    // ---------- tier 4 ----------
    float* qfp  = (float*)(ws + 0);        // 2 MB: 4 x 512KB qf split-K partials
    u16*   Es16 = (u16*)(ws + 28049408);   // 8.4 MB bf16 exp2(scale*sf)
    float* Eq4  = (float*)(ws + 36438016); // 512 KB fp32 exp2(scale*qf)
    float* rsum = (float*)(ws + 36962304); // 512 B fp32 softmax row sums
    (void)hipMemsetAsync(Bh, 0, (size_t)BT_ * H_ * 4, stream);   // hidden zero (atomics)
    prep_fused6<<<2944, 256, 0, stream>>>(states, Ws, query, Wq, bq, Wc, bc,
                                          sbf, sbfT, WsT, qfp, rsum, Bh);
    f2i_sfgemm<<<dim3(16, 32), 256, 0, stream>>>(sbf, WsT, qfp, Eq4, Es16);
    f3l_align<<<dim3(256, 2), 256, 0, stream>>>(Eq4, Es16, v, mask, pbf, rsum);
    f5e_context<<<256, 256, 0, stream>>>(pbf, sbfT, rsum, A, C);
    f6c_outproj<<<dim3(4, 8, 8), 256, 0, stream>>>(A, Wc, Bh);
  } else if (ws_size >= WS_T3) {
    // ---------- tier 3 ----------
    (void)hipMemsetAsync(A, 0, (size_t)(BT_ * D_ + BT_ * H_) * 4, stream);  // qf + hidden zero
    prep_fused<<<2816, 256, 0, stream>>>(states, Ws, query, Wq, bq, sbf, sbfT, WsT, A);
    f2e_sfgemm<<<dim3(16, 32), 256, 0, stream>>>(sbf, WsT, sfb);
    f3f_align<<<dim3(1024, 2), 256, 0, stream>>>(A, sfb, v, alg);
    f4b_softmax<<<BT_, 256, 0, stream>>>(alg, mask, C, pbf);
    f5c_context<<<64, 256, 0, stream>>>(pbf, sbfT, A);
    f6b_outproj<<<dim3(4, 8, 12), 256, 0, stream>>>(A, query, Wc, bc, Bh);
  } else if (ws_size >= WS_T1) {
    // ---------- tier 1/2 ----------
    float* attn = alg;
    (void)hipMemsetAsync(A, 0, (size_t)(BT_ * D_ + BT_ * H_) * 4, stream);
    f1b_qf<<<dim3(4, 16, 4), 256, 0, stream>>>(query, Wq, bq, A);
    f0_transpose<<<dim3(16, 32), 256, 0, stream>>>(Ws, WsT);
    const int tier2 = (ws_size >= WS_T2);
    if (tier2) {
      kc_cvt<<<2048, 256, 0, stream>>>(states, sbf);
      f2c_sfgemm<<<dim3(16, 32), 256, 0, stream>>>(sbf, WsT, sfb);
    } else {
      f2d_sfgemm<<<dim3(16, 32), 256, 0, stream>>>(states, WsT, sfb);
    }
    f3f_align<<<dim3(1024, 2), 256, 0, stream>>>(A, sfb, v, C);
    (void)hipMemsetAsync(A, 0, (size_t)BT_ * D_ * 4, stream);
    f4_softmax<<<BT_, 256, 0, stream>>>(C, mask, attn);
    if (tier2)
      f5b_context<<<dim3(16, 2, 4), 256, 0, stream>>>(attn, sbf, A, C);
    else
      f5_context<<<dim3(16, 2, 4), 256, 0, stream>>>(attn, states, A, C);
    f6b_outproj<<<dim3(4, 8, 12), 256, 0, stream>>>(A, query, Wc, bc, Bh);
  } else {
    // ---------- fallback ----------
    k1_qf<<<BT_, 256, 0, stream>>>(query, Wq, bq, A);
    k23_align<<<B_ * (S_ / 16), 256, 0, stream>>>(states, Ws, v, A, C);
    k4_softmax<<<BT_, 256, 0, stream>>>(C, mask, A);
    k56_ctx_proj<<<BT_, 256, 0, stream>>>(A, states, query, Wc, bc, A, Bh, C);
  }
}

// Round 10
// 158.621 us; speedup vs baseline: 1.1610x; 1.0081x over previous
//
#include <hip/hip_runtime.h>
#include <math.h>

// Bahdanau additive attention. B=4, T=32, S=1024, H=512, D=2H=1024.
// Inputs fp32 (mask int32), OUTPUT fp32 flat:
//   context (4,32,1024) | hidden (4,32,512) | attn_t (4,1024,32)
// Round 25: R24 (measured 159.9 best) + de-atomic hidQ via the R19-validated
// partials pattern: prep's hidQ blocks plain-store 4 K-partials -> hidp[ks];
// f2k prologue sums them (+Eq exp2 as before) and plain-stores Bh. Kills the
// Bh memset dispatch and prep's 512K atomics. f6c atomics accumulate on top
// (stream-ordered after f2k). 5 dispatches, 0 memsets.
// Chain: prep(2944) + f2k(512) + f3l(256x2) + f5e(256) + f6c(256).
// d_out overlay: A[0,131072): ctx(final)  B[131072,196608): hidden(f2k-init)
//                C[196608,327680): attn_t(final)

typedef unsigned short u16;
typedef __bf16 bf16x8 __attribute__((ext_vector_type(8)));
typedef float floatx4 __attribute__((ext_vector_type(4)));

#define B_ 4
#define T_ 32
#define S_ 1024
#define H_ 512
#define D_ 1024
#define BT_ 128
#define TWO_LOG2E 2.8853900817779268f   // tanh(y) = 1 - 2/(exp2(2*log2e*y)+1)
#define LOG2E 1.4426950408889634f

__device__ __forceinline__ float bf2f(u16 u) {
  unsigned int i = ((unsigned int)u) << 16;
  return __builtin_bit_cast(float, i);
}
__device__ __forceinline__ u16 f2bf(float f) {
  unsigned int i = __builtin_bit_cast(unsigned int, f);
  i += 0x7fffu + ((i >> 16) & 1u);  // RNE
  return (u16)(i >> 16);
}
__device__ __forceinline__ void ld_g2l_16(const u16* g, u16* l) {
  __builtin_amdgcn_global_load_lds((__attribute__((address_space(1))) void*)(u16*)g,
                                   (__attribute__((address_space(3))) void*)l, 16, 0, 0);
}

// ================= TIER-4 KERNELS =================

// ---- PREP8: heavy blocks FIRST so light blocks backfill (no serial tail).
//      [0,256)    qf split-K -> qfp partials (plain stores);
//      [256,384)  hidden query-part split-K -> hidp partials (plain stores);
//      [384,896)  Ws^T -> WsT bf16 (block 384 zeroes rowsum);
//      [896,2944) states -> sbf + sbfT.
__global__ __launch_bounds__(256) void prep_fused8(const float* __restrict__ states, const float* __restrict__ Ws,
                                                   const float* __restrict__ query, const float* __restrict__ Wq,
                                                   const float* __restrict__ bq,
                                                   const float* __restrict__ Wc, const float* __restrict__ bc,
                                                   u16* __restrict__ sbf, u16* __restrict__ sbfT,
                                                   u16* __restrict__ WsT, float* __restrict__ qfp,
                                                   float* __restrict__ rowsum, float* __restrict__ hidp) {
  __shared__ u16 tile[32][65];
  __shared__ float q[8][128];
  const int t = threadIdx.x;
  if (blockIdx.x < 256) {
    const int idx = blockIdx.x;                   // 0..255: qf split-K partials
    const int c0 = (idx & 3) * 256, r0 = ((idx >> 2) & 15) * 8, ks = idx >> 6;
    const int k0 = ks * 128;
    for (int i = t; i < 8 * 128; i += 256) {
      const int rl = i >> 7, kk = i & 127;
      q[rl][kk] = query[(size_t)(r0 + rl) * H_ + k0 + kk];
    }
    __syncthreads();
    const int col = c0 + t;
    float acc[8] = {};
    for (int kk = 0; kk < 128; ++kk) {
      const float w = Wq[(size_t)(k0 + kk) * D_ + col];
#pragma unroll
      for (int r = 0; r < 8; ++r) acc[r] = fmaf(q[r][kk], w, acc[r]);
    }
    const float bb = (ks == 0) ? bq[col] : 0.f;
    float* dst = qfp + (size_t)ks * (BT_ * D_);
#pragma unroll
    for (int r = 0; r < 8; ++r)
      dst[(size_t)(r0 + r) * D_ + col] = TWO_LOG2E * (acc[r] + bb);
  } else if (blockIdx.x < 384) {
    const int idx = blockIdx.x - 256;             // 0..127: hidden query-part partials
    const int c0 = (idx & 1) * 256, r0 = ((idx >> 1) & 15) * 8, ks = idx >> 5;
    const int k0 = ks * 128;
    for (int i = t; i < 8 * 128; i += 256) {
      const int rl = i >> 7, kk = i & 127;
      q[rl][kk] = query[(size_t)(r0 + rl) * H_ + k0 + kk];
    }
    __syncthreads();
    const int col = c0 + t;
    float acc[8] = {};
    for (int kk = 0; kk < 128; ++kk) {
      const float w = Wc[(size_t)(D_ + k0 + kk) * H_ + col];
#pragma unroll
      for (int r = 0; r < 8; ++r) acc[r] = fmaf(q[r][kk], w, acc[r]);
    }
    const float bb = (ks == 0) ? bc[col] : 0.f;
    float* dst = hidp + (size_t)ks * (BT_ * H_);
#pragma unroll
    for (int r = 0; r < 8; ++r)
      dst[(size_t)(r0 + r) * H_ + col] = acc[r] + bb;
  } else if (blockIdx.x < 896) {
    const int bid = blockIdx.x - 384;             // 0..511: Ws transpose
    if (bid == 0 && t < 128) rowsum[t] = 0.f;     // zero rsum (read only by f3l)
    const int n0 = (bid & 15) * 64, k0 = (bid >> 4) * 32;
    const int kr = t >> 3, nc = (t & 7) * 8;
    const float* p = Ws + (size_t)(k0 + kr) * D_ + n0 + nc;
    float4 a = *(const float4*)p, b = *(const float4*)(p + 4);
    tile[kr][nc + 0] = f2bf(a.x); tile[kr][nc + 1] = f2bf(a.y);
    tile[kr][nc + 2] = f2bf(a.z); tile[kr][nc + 3] = f2bf(a.w);
    tile[kr][nc + 4] = f2bf(b.x); tile[kr][nc + 5] = f2bf(b.y);
    tile[kr][nc + 6] = f2bf(b.z); tile[kr][nc + 7] = f2bf(b.w);
    __syncthreads();
    const int nr = t >> 2, kc = (t & 3) * 8;
    union { uint4 v; u16 s[8]; } st;
#pragma unroll
    for (int i = 0; i < 8; ++i) st.s[i] = tile[kc + i][nr];
    *(uint4*)(WsT + (size_t)(n0 + nr) * D_ + k0 + kc) = st.v;
  } else {
    const int bid = blockIdx.x - 896;             // 0..2047: states cvt+transpose
    const int b = bid >> 9;
    const int r2 = bid & 511;
    const int d0 = (r2 & 15) * 64, s0 = (r2 >> 4) * 32;
    const int sr = t >> 3, dc = (t & 7) * 8;
    const float* p = states + ((size_t)b * S_ + s0 + sr) * D_ + d0 + dc;
    float4 a = *(const float4*)p, bb = *(const float4*)(p + 4);
    union { uint4 v; u16 s[8]; } pk;
    pk.s[0] = f2bf(a.x); pk.s[1] = f2bf(a.y); pk.s[2] = f2bf(a.z); pk.s[3] = f2bf(a.w);
    pk.s[4] = f2bf(bb.x); pk.s[5] = f2bf(bb.y); pk.s[6] = f2bf(bb.z); pk.s[7] = f2bf(bb.w);
    *(uint4*)(sbf + ((size_t)b * S_ + s0 + sr) * D_ + d0 + dc) = pk.v;
#pragma unroll
    for (int i = 0; i < 8; ++i) tile[sr][dc + i] = pk.s[i];
    __syncthreads();
    const int dr = t >> 2, sc = (t & 3) * 8;
    union { uint4 v; u16 s[8]; } st;
#pragma unroll
    for (int i = 0; i < 8; ++i) st.s[i] = tile[sc + i][dr];
    *(uint4*)(sbfT + ((size_t)b * D_ + d0 + dr) * S_ + s0 + sc) = st.v;
  }
}

// ---- F2k: Es = bf16(exp2(2log2e*(sbf @ Ws))); prologue: Eq = exp2(sum qfp),
// Bh = sum hidp (plain store; f6c atomics accumulate on top). Double-buffered
// global_load_lds prefetch, counted vmcnt(6), raw s_barrier; XOR-swizzled LDS.
__device__ __forceinline__ void f2f_stage(const u16* __restrict__ A, const u16* __restrict__ BT,
                                          u16* sAb, u16* sBb, int bm0, int bn0, int k0,
                                          int wv, int srow, int sp) {
#pragma unroll
  for (int j = 0; j < 4; ++j) {                  // A: rows wv*32 + j*8 + srow
    const int r = wv * 32 + j * 8 + srow;
    const int c = sp ^ (r & 7);
    ld_g2l_16(A + (size_t)(bm0 + r) * D_ + k0 + c * 8, sAb + (wv * 32 + j * 8) * 64);
  }
#pragma unroll
  for (int j = 0; j < 2; ++j) {                  // B: rows wv*16 + j*8 + srow
    const int r = wv * 16 + j * 8 + srow;
    const int c = sp ^ (r & 7);
    ld_g2l_16(BT + (size_t)(bn0 + r) * D_ + k0 + c * 8, sBb + (wv * 16 + j * 8) * 64);
  }
}

__device__ __forceinline__ void f2f_compute(const u16* sAb, const u16* sBb,
                                            int wm, int wn, int fm, int fq, floatx4 (&acc)[4][2]) {
#pragma unroll
  for (int win = 0; win < 2; ++win) {
    bf16x8 af[4], bfr[2];
#pragma unroll
    for (int i = 0; i < 4; ++i) {
      const int R = wm + i * 16 + fm;
      af[i] = *(const bf16x8*)&sAb[R * 64 + ((win * 4 + fq) ^ (R & 7)) * 8];
    }
#pragma unroll
    for (int j = 0; j < 2; ++j) {
      const int R = wn + j * 16 + fm;
      bfr[j] = *(const bf16x8*)&sBb[R * 64 + ((win * 4 + fq) ^ (R & 7)) * 8];
    }
#pragma unroll
    for (int i = 0; i < 4; ++i)
#pragma unroll
      for (int j = 0; j < 2; ++j)
        acc[i][j] = __builtin_amdgcn_mfma_f32_16x16x32_bf16(af[i], bfr[j], acc[i][j], 0, 0, 0);
  }
}

__global__ __launch_bounds__(256) void f2k_sfgemm(const u16* __restrict__ A, const u16* __restrict__ BT,
                                                  const float* __restrict__ qfp, const float* __restrict__ hidp,
                                                  float* __restrict__ Eq, float* __restrict__ hid,
                                                  u16* __restrict__ Es) {
  __shared__ __align__(16) u16 sA[2][128 * 64];  // 2 x 16 KB
  __shared__ __align__(16) u16 sB[2][64 * 64];   // 2 x 8 KB
  const int bm0 = blockIdx.y * 128, bn0 = blockIdx.x * 64;
  const int t = threadIdx.x;
  const int wv = t >> 6, lane = t & 63;
  const int wm = (wv >> 1) * 64, wn = (wv & 1) * 32;
  const int fm = lane & 15, fq = lane >> 4;
  const int srow = lane >> 3, sp = lane & 7;

  // Prologue: Eq (512 blks x 256 thr = 131072 = BT_*D_) and Bh (first 256 blks).
  {
    const int bid = blockIdx.y * 16 + blockIdx.x;
    const int idx = bid * 256 + t;
    const float s = qfp[idx] + qfp[BT_ * D_ + idx] +
                    qfp[2 * BT_ * D_ + idx] + qfp[3 * BT_ * D_ + idx];
    Eq[idx] = __builtin_amdgcn_exp2f(s);         // prescaled by 2log2e
    if (bid < 256) {
      const int h = bid * 256 + t;               // 65536 = BT_*H_ elems
      hid[h] = hidp[h] + hidp[BT_ * H_ + h] +
               hidp[2 * BT_ * H_ + h] + hidp[3 * BT_ * H_ + h];
    }
  }

  floatx4 acc[4][2];
  const floatx4 fz = {0.f, 0.f, 0.f, 0.f};
#pragma unroll
  for (int i = 0; i < 4; ++i) { acc[i][0] = fz; acc[i][1] = fz; }

  f2f_stage(A, BT, sA[0], sB[0], bm0, bn0, 0, wv, srow, sp);
#pragma unroll 1
  for (int k0 = 0; k0 < D_; k0 += 128) {
    // even phase: compute buf0, prefetch buf1(k0+64)
    f2f_stage(A, BT, sA[1], sB[1], bm0, bn0, k0 + 64, wv, srow, sp);
    asm volatile("s_waitcnt vmcnt(6)" ::: "memory");   // buf0's 6 loads landed
    __builtin_amdgcn_s_barrier();
    f2f_compute(sA[0], sB[0], wm, wn, fm, fq, acc);
    __builtin_amdgcn_s_barrier();                      // all waves done reading buf0
    // odd phase: compute buf1, prefetch buf0(k0+128)
    if (k0 + 128 < D_) {
      f2f_stage(A, BT, sA[0], sB[0], bm0, bn0, k0 + 128, wv, srow, sp);
      asm volatile("s_waitcnt vmcnt(6)" ::: "memory"); // buf1's 6 loads landed
    } else {
      asm volatile("s_waitcnt vmcnt(0)" ::: "memory");
    }
    __builtin_amdgcn_s_barrier();
    f2f_compute(sA[1], sB[1], wm, wn, fm, fq, acc);
    __builtin_amdgcn_s_barrier();
  }
#pragma unroll
  for (int i = 0; i < 4; ++i)
#pragma unroll
    for (int j = 0; j < 2; ++j)
#pragma unroll
      for (int r = 0; r < 4; ++r) {
        const int row = bm0 + wm + i * 16 + fq * 4 + r;   // col=lane&15, row=quad*4+reg (m89)
        const int col = bn0 + wn + j * 16 + fm;
        Es[(size_t)row * D_ + col] = f2bf(__builtin_amdgcn_exp2f(TWO_LOG2E * acc[i][j][r]));
      }
}

// ---- F3l: E = exp(alg), alg = sumv + sum_j vm2_j*rcp(fma(Eq,Es,1)).
// No-max softmax. 4 s-values x 16 t-rows per wave (t-half by blockIdx.y):
// 2 waves/SIMD hides rcp latency; Eq L2 traffic unchanged.
__global__ __launch_bounds__(256) void f3l_align(const float* __restrict__ Eq, const u16* __restrict__ Es,
                                                 const float* __restrict__ v, const int* __restrict__ mask,
                                                 u16* __restrict__ pbf, float* __restrict__ rowsum) {
  __shared__ float red[16][4];
  const int wv = threadIdx.x >> 6, lane = threadIdx.x & 63;
  const int w = blockIdx.x * 4 + wv;                      // 0..1023
  const int b = w >> 8;                                   // 256 waves per batch
  const int s0 = (w & 255) * 4;
  const int t0 = blockIdx.y * 16;
  const int m0 = mask[(size_t)b * S_ + s0 + 0];
  const int m1 = mask[(size_t)b * S_ + s0 + 1];
  const int m2 = mask[(size_t)b * S_ + s0 + 2];
  const int m3 = mask[(size_t)b * S_ + s0 + 3];
  float vm2[16], es0[16], es1[16], es2[16], es3[16];
  float sumv = 0.f;
  {
    union { uint4 u[2]; u16 h[16]; } u0, u1, u2, u3;
    const uint4* ep0 = (const uint4*)(Es + ((size_t)b * S_ + s0 + 0) * D_ + lane * 16);
    const uint4* ep1 = (const uint4*)(Es + ((size_t)b * S_ + s0 + 1) * D_ + lane * 16);
    const uint4* ep2 = (const uint4*)(Es + ((size_t)b * S_ + s0 + 2) * D_ + lane * 16);
    const uint4* ep3 = (const uint4*)(Es + ((size_t)b * S_ + s0 + 3) * D_ + lane * 16);
    u0.u[0] = ep0[0]; u0.u[1] = ep0[1];
    u1.u[0] = ep1[0]; u1.u[1] = ep1[1];
    u2.u[0] = ep2[0]; u2.u[1] = ep2[1];
    u3.u[0] = ep3[0]; u3.u[1] = ep3[1];
    const float4* vp = (const float4*)(v + lane * 16);
#pragma unroll
    for (int c = 0; c < 4; ++c) {
      const float4 w4 = vp[c];
      vm2[4 * c + 0] = -2.f * w4.x; vm2[4 * c + 1] = -2.f * w4.y;
      vm2[4 * c + 2] = -2.f * w4.z; vm2[4 * c + 3] = -2.f * w4.w;
      sumv += w4.x + w4.y + w4.z + w4.w;
    }
#pragma unroll
    for (int j = 0; j < 16; ++j) {
      es0[j] = bf2f(u0.h[j]); es1[j] = bf2f(u1.h[j]);
      es2[j] = bf2f(u2.h[j]); es3[j] = bf2f(u3.h[j]);
    }
  }
  const float* qbase = Eq + ((size_t)(b * T_ + t0)) * D_ + lane * 16;
  for (int tc = 0; tc < 4; ++tc) {               // 4 chunks of 4 t-rows (16 t total)
    float sa[4], sb[4], sc[4], sd[4];
#pragma unroll
    for (int ti = 0; ti < 4; ++ti) {
      const float4* qp = (const float4*)(qbase + (size_t)(tc * 4 + ti) * D_);
      float a0 = sumv, a1 = sumv, a2 = sumv, a3 = sumv;
#pragma unroll
      for (int c = 0; c < 4; ++c) {
        const float4 q4 = qp[c];
        const float xs[4] = {q4.x, q4.y, q4.z, q4.w};
#pragma unroll
        for (int u2 = 0; u2 < 4; ++u2) {
          const int j = 4 * c + u2;
          a0 = fmaf(vm2[j], __builtin_amdgcn_rcpf(fmaf(xs[u2], es0[j], 1.f)), a0);
          a1 = fmaf(vm2[j], __builtin_amdgcn_rcpf(fmaf(xs[u2], es1[j], 1.f)), a1);
          a2 = fmaf(vm2[j], __builtin_amdgcn_rcpf(fmaf(xs[u2], es2[j], 1.f)), a2);
          a3 = fmaf(vm2[j], __builtin_amdgcn_rcpf(fmaf(xs[u2], es3[j], 1.f)), a3);
        }
      }
      sa[ti] = a0; sb[ti] = a1; sc[ti] = a2; sd[ti] = a3;
    }
#pragma unroll
    for (int off = 32; off > 0; off >>= 1)
#pragma unroll
      for (int ti = 0; ti < 4; ++ti) {
        sa[ti] += __shfl_xor(sa[ti], off);
        sb[ti] += __shfl_xor(sb[ti], off);
        sc[ti] += __shfl_xor(sc[ti], off);
        sd[ti] += __shfl_xor(sd[ti], off);
      }
    if (lane == 0) {
#pragma unroll
      for (int ti = 0; ti < 4; ++ti) {
        const int tl = tc * 4 + ti;              // local t in [0,16)
        const int tt = t0 + tl;
        const float e0 = m0 ? __builtin_amdgcn_exp2f(sa[ti] * LOG2E) : 0.f;
        const float e1 = m1 ? __builtin_amdgcn_exp2f(sb[ti] * LOG2E) : 0.f;
        const float e2 = m2 ? __builtin_amdgcn_exp2f(sc[ti] * LOG2E) : 0.f;
        const float e3 = m3 ? __builtin_amdgcn_exp2f(sd[ti] * LOG2E) : 0.f;
        const u16 p0 = f2bf(e0), p1 = f2bf(e1), p2 = f2bf(e2), p3 = f2bf(e3);
        uint2 pk;
        pk.x = (unsigned int)p0 | ((unsigned int)p1 << 16);
        pk.y = (unsigned int)p2 | ((unsigned int)p3 << 16);
        *(uint2*)&pbf[((size_t)(b * T_ + tt)) * S_ + s0] = pk;
        red[tl][wv] = bf2f(p0) + bf2f(p1) + bf2f(p2) + bf2f(p3);
      }
    }
  }
  __syncthreads();
  if (threadIdx.x < 16) {
    const int bb = blockIdx.x >> 6;              // 64 x-blocks per batch
    const float rs = red[threadIdx.x][0] + red[threadIdx.x][1] +
                     red[threadIdx.x][2] + red[threadIdx.x][3];
    atomicAdd(&rowsum[bb * 32 + t0 + threadIdx.x], rs);
  }
}

// ---- F5e: ctx = (E @ states)/rowsum. 256 blocks (16 ctx-cols each); 4 waves
// split S into 256-chunks, LDS-reduce; normalization + attn_t slice folded.
__global__ __launch_bounds__(256) void f5e_context(const u16* __restrict__ pbf, const u16* __restrict__ sbfT,
                                                   const float* __restrict__ rowsum,
                                                   float* __restrict__ ctx, float* __restrict__ out_at) {
  __shared__ float rinv[32];
  __shared__ float red[4][64][9];
  const int b = blockIdx.x >> 6, dt = blockIdx.x & 63;
  const int wv = threadIdx.x >> 6, lane = threadIdx.x & 63;
  if (threadIdx.x < 32) rinv[threadIdx.x] = 1.f / rowsum[b * 32 + threadIdx.x];
  const int n0 = dt * 16;
  const int fm = lane & 15, fq = lane >> 4;
  const floatx4 fz = {0.f, 0.f, 0.f, 0.f};
  floatx4 acc0 = fz, acc1 = fz;
  const u16* pa0 = pbf + ((size_t)b * T_ + fm) * S_ + wv * 256 + fq * 8;
  const u16* pa1 = pa0 + (size_t)16 * S_;
  const u16* pb  = sbfT + ((size_t)b * D_ + n0 + fm) * S_ + wv * 256 + fq * 8;
#pragma unroll
  for (int k0 = 0; k0 < 256; k0 += 32) {
    bf16x8 a0 = *(const bf16x8*)(pa0 + k0);
    bf16x8 a1 = *(const bf16x8*)(pa1 + k0);
    bf16x8 bb = *(const bf16x8*)(pb + k0);
    acc0 = __builtin_amdgcn_mfma_f32_16x16x32_bf16(a0, bb, acc0, 0, 0, 0);
    acc1 = __builtin_amdgcn_mfma_f32_16x16x32_bf16(a1, bb, acc1, 0, 0, 0);
  }
#pragma unroll
  for (int r = 0; r < 4; ++r) {
    red[wv][lane][r] = acc0[r];
    red[wv][lane][4 + r] = acc1[r];
  }
  __syncthreads();
  // attn_t slice: s in [dt*16, dt*16+16), all 32 t. All threads.
  const int s0a = dt * 16;
  for (int i = threadIdx.x; i < 512; i += 256) {
    const int tt = i & 31, sl = i >> 5;
    const float e = bf2f(pbf[((size_t)(b * T_ + tt)) * S_ + s0a + sl]);
    out_at[((size_t)(b * S_ + s0a + sl)) * T_ + tt] = e * rinv[tt];
  }
  if (wv == 0) {
#pragma unroll
    for (int r = 0; r < 4; ++r) {
      const float v0 = red[0][lane][r] + red[1][lane][r] + red[2][lane][r] + red[3][lane][r];
      const float v1 = red[0][lane][4 + r] + red[1][lane][4 + r] +
                       red[2][lane][4 + r] + red[3][lane][4 + r];
      const int t0r = fq * 4 + r;
      ctx[((size_t)b * T_ + t0r) * D_ + n0 + fm] = v0 * rinv[t0r];
      ctx[((size_t)b * T_ + 16 + t0r) * D_ + n0 + fm] = v1 * rinv[16 + t0r];
    }
  }
}

// ---- F6c: hidden += ctx_kslice @ Wc[0:1024] (query part + bias stored by f2k). ----
__global__ __launch_bounds__(256) void f6c_outproj(const float* __restrict__ ctx,
                                                   const float* __restrict__ Wc,
                                                   float* __restrict__ out_hid) {
  __shared__ float cq[16][128];
  const int c0 = blockIdx.x * 128, r0 = blockIdx.y * 16, k0 = blockIdx.z * 128;
  const int tid = threadIdx.x;
  const int cl = tid & 127, rh = tid >> 7;
  for (int i = tid; i < 16 * 128; i += 256) {
    const int rl = i >> 7, kk = i & 127;
    cq[rl][kk] = ctx[(size_t)(r0 + rl) * D_ + k0 + kk];
  }
  __syncthreads();
  float acc[8] = {};
  for (int kk = 0; kk < 128; ++kk) {
    const float w = Wc[(size_t)(k0 + kk) * H_ + c0 + cl];
#pragma unroll
    for (int rr = 0; rr < 8; ++rr) acc[rr] = fmaf(cq[rh * 8 + rr][kk], w, acc[rr]);
  }
#pragma unroll
  for (int rr = 0; rr < 8; ++rr)
    atomicAdd(&out_hid[(size_t)(r0 + rh * 8 + rr) * H_ + c0 + cl], acc[rr]);
}

// ================= TIER-3 KERNELS =================

__global__ __launch_bounds__(256) void prep_fused(const float* __restrict__ states, const float* __restrict__ Ws,
                                                  const float* __restrict__ query, const float* __restrict__ Wq,
                                                  const float* __restrict__ bq,
                                                  u16* __restrict__ sbf, u16* __restrict__ sbfT,
                                                  u16* __restrict__ WsT, float* __restrict__ qf) {
  __shared__ u16 tile[32][65];
  __shared__ float q[8][128];
  const int t = threadIdx.x;
  if (blockIdx.x < 512) {
    const int n0 = (blockIdx.x & 15) * 64, k0 = (blockIdx.x >> 4) * 32;
    const int kr = t >> 3, nc = (t & 7) * 8;
    const float* p = Ws + (size_t)(k0 + kr) * D_ + n0 + nc;
    float4 a = *(const float4*)p, b = *(const float4*)(p + 4);
    tile[kr][nc + 0] = f2bf(a.x); tile[kr][nc + 1] = f2bf(a.y);
    tile[kr][nc + 2] = f2bf(a.z); tile[kr][nc + 3] = f2bf(a.w);
    tile[kr][nc + 4] = f2bf(b.x); tile[kr][nc + 5] = f2bf(b.y);
    tile[kr][nc + 6] = f2bf(b.z); tile[kr][nc + 7] = f2bf(b.w);
    __syncthreads();
    const int nr = t >> 2, kc = (t & 3) * 8;
    union { uint4 v; u16 s[8]; } st;
#pragma unroll
    for (int i = 0; i < 8; ++i) st.s[i] = tile[kc + i][nr];
    *(uint4*)(WsT + (size_t)(n0 + nr) * D_ + k0 + kc) = st.v;
  } else if (blockIdx.x < 2560) {
    const int bid = blockIdx.x - 512;
    const int b = bid >> 9;
    const int r2 = bid & 511;
    const int d0 = (r2 & 15) * 64, s0 = (r2 >> 4) * 32;
    const int sr = t >> 3, dc = (t & 7) * 8;
    const float* p = states + ((size_t)b * S_ + s0 + sr) * D_ + d0 + dc;
    float4 a = *(const float4*)p, bb = *(const float4*)(p + 4);
    union { uint4 v; u16 s[8]; } pk;
    pk.s[0] = f2bf(a.x); pk.s[1] = f2bf(a.y); pk.s[2] = f2bf(a.z); pk.s[3] = f2bf(a.w);
    pk.s[4] = f2bf(bb.x); pk.s[5] = f2bf(bb.y); pk.s[6] = f2bf(bb.z); pk.s[7] = f2bf(bb.w);
    *(uint4*)(sbf + ((size_t)b * S_ + s0 + sr) * D_ + d0 + dc) = pk.v;
#pragma unroll
    for (int i = 0; i < 8; ++i) tile[sr][dc + i] = pk.s[i];
    __syncthreads();
    const int dr = t >> 2, sc = (t & 3) * 8;
    union { uint4 v; u16 s[8]; } st;
#pragma unroll
    for (int i = 0; i < 8; ++i) st.s[i] = tile[sc + i][dr];
    *(uint4*)(sbfT + ((size_t)b * D_ + d0 + dr) * S_ + s0 + sc) = st.v;
  } else {
    const int idx = blockIdx.x - 2560;            // 0..255
    const int c0 = (idx & 3) * 256, r0 = ((idx >> 2) & 15) * 8, k0 = (idx >> 6) * 128;
    for (int i = t; i < 8 * 128; i += 256) {
      const int rl = i >> 7, kk = i & 127;
      q[rl][kk] = query[(size_t)(r0 + rl) * H_ + k0 + kk];
    }
    __syncthreads();
    const int col = c0 + t;
    float acc[8] = {};
    for (int kk = 0; kk < 128; ++kk) {
      const float w = Wq[(size_t)(k0 + kk) * D_ + col];
#pragma unroll
      for (int r = 0; r < 8; ++r) acc[r] = fmaf(q[r][kk], w, acc[r]);
    }
    const float bb = (k0 == 0) ? bq[col] : 0.f;
#pragma unroll
    for (int r = 0; r < 8; ++r)
      atomicAdd(&qf[(size_t)(r0 + r) * D_ + col], TWO_LOG2E * (acc[r] + bb));
  }
}

__global__ __launch_bounds__(256) void f2e_sfgemm(const u16* __restrict__ A, const u16* __restrict__ BT,
                                                  u16* __restrict__ Cb) {
  __shared__ __align__(16) u16 sA[128 * 64];   // 16 KB, row stride 64 u16
  __shared__ __align__(16) u16 sB[64 * 64];    // 8 KB
  const int bm0 = blockIdx.y * 128, bn0 = blockIdx.x * 64;
  const int t = threadIdx.x;
  const int wv = t >> 6, lane = t & 63;
  const int wm = (wv >> 1) * 64, wn = (wv & 1) * 32;
  const int fm = lane & 15, fq = lane >> 4;
  const int srow = lane >> 3, sp = lane & 7;   // staging: 8 rows x 8 chunks per inst

  floatx4 acc[4][2];
  const floatx4 fz = {0.f, 0.f, 0.f, 0.f};
#pragma unroll
  for (int i = 0; i < 4; ++i) { acc[i][0] = fz; acc[i][1] = fz; }

  for (int k0 = 0; k0 < D_; k0 += 64) {
    __syncthreads();                           // prev tile reads done
#pragma unroll
    for (int j = 0; j < 4; ++j) {              // A: rows wv*32 + j*8 + srow
      const int r = wv * 32 + j * 8 + srow;
      const int c = sp ^ (r & 7);
      ld_g2l_16(A + (size_t)(bm0 + r) * D_ + k0 + c * 8, &sA[(wv * 32 + j * 8) * 64]);
    }
#pragma unroll
    for (int j = 0; j < 2; ++j) {              // B: rows wv*16 + j*8 + srow
      const int r = wv * 16 + j * 8 + srow;
      const int c = sp ^ (r & 7);
      ld_g2l_16(BT + (size_t)(bn0 + r) * D_ + k0 + c * 8, &sB[(wv * 16 + j * 8) * 64]);
    }
    __syncthreads();                           // vmcnt(0) drains the async loads
#pragma unroll
    for (int win = 0; win < 2; ++win) {
      bf16x8 af[4], bfr[2];
#pragma unroll
      for (int i = 0; i < 4; ++i) {
        const int R = wm + i * 16 + fm;
        af[i] = *(const bf16x8*)&sA[R * 64 + ((win * 4 + fq) ^ (R & 7)) * 8];
      }
#pragma unroll
      for (int j = 0; j < 2; ++j) {
        const int R = wn + j * 16 + fm;
        bfr[j] = *(const bf16x8*)&sB[R * 64 + ((win * 4 + fq) ^ (R & 7)) * 8];
      }
#pragma unroll
      for (int i = 0; i < 4; ++i)
#pragma unroll
        for (int j = 0; j < 2; ++j)
          acc[i][j] = __builtin_amdgcn_mfma_f32_16x16x32_bf16(af[i], bfr[j], acc[i][j], 0, 0, 0);
    }
  }
#pragma unroll
  for (int i = 0; i < 4; ++i)
#pragma unroll
    for (int j = 0; j < 2; ++j)
#pragma unroll
      for (int r = 0; r < 4; ++r) {
        const int row = bm0 + wm + i * 16 + fq * 4 + r;   // col=lane&15, row=quad*4+reg (m89)
        const int col = bn0 + wn + j * 16 + fm;
        Cb[(size_t)row * D_ + col] = f2bf(TWO_LOG2E * acc[i][j][r]);
      }
}

__global__ __launch_bounds__(256, 6) void f3f_align(const float* __restrict__ qf, const u16* __restrict__ sfb,
                                                    const float* __restrict__ v, float* __restrict__ alg) {
  const int wid = (blockIdx.x * 256 + threadIdx.x) >> 6;  // b*1024+s
  const int lane = threadIdx.x & 63;
  const int b = wid >> 10, s = wid & 1023;
  const int t0 = blockIdx.y * 16;
  float vr[16], sr[16];
  {
    union { uint4 v[2]; u16 s[16]; } u;
    const uint4* sp = (const uint4*)(sfb + (size_t)wid * D_ + lane * 16);
    u.v[0] = sp[0]; u.v[1] = sp[1];
    const float* vp = v + lane * 16;
#pragma unroll
    for (int c = 0; c < 4; ++c) {
      float4 w = *(const float4*)(vp + 4 * c);
      vr[4 * c + 0] = w.x; vr[4 * c + 1] = w.y; vr[4 * c + 2] = w.z; vr[4 * c + 3] = w.w;
    }
#pragma unroll
    for (int j = 0; j < 16; ++j) sr[j] = bf2f(u.s[j]);
  }
  float sum[16];
#pragma unroll
  for (int tt = 0; tt < 16; ++tt) sum[tt] = 0.f;

  const float* qbase = qf + ((size_t)(b * T_ + t0)) * D_ + lane * 16;
  for (int tt = 0; tt < 16; ++tt) {
    const float4* qp = (const float4*)(qbase + (size_t)tt * D_);
    float acc = 0.f;
#pragma unroll
    for (int c = 0; c < 4; ++c) {
      float4 q4 = qp[c];
      float xs[4] = {q4.x, q4.y, q4.z, q4.w};
#pragma unroll
      for (int u2 = 0; u2 < 4; ++u2) {
        const int j = 4 * c + u2;
        const float x = xs[u2] + sr[j];                        // prescaled by 2log2e
        const float e = __builtin_amdgcn_exp2f(x);
        acc = fmaf(vr[j], fmaf(-2.f, __builtin_amdgcn_rcpf(e + 1.f), 1.f), acc);
      }
    }
    sum[tt] = acc;
  }
#pragma unroll
  for (int off = 32; off > 0; off >>= 1)
#pragma unroll
    for (int tt = 0; tt < 16; ++tt) sum[tt] += __shfl_xor(sum[tt], off);
  if (lane == 0) {
#pragma unroll
    for (int tt = 0; tt < 16; ++tt)
      alg[((size_t)(b * T_ + t0 + tt)) * S_ + s] = sum[tt];
  }
}

__global__ __launch_bounds__(256) void f4b_softmax(const float* __restrict__ alg, const int* __restrict__ mask,
                                                   float* __restrict__ out_at, u16* __restrict__ pbf) {
  const int r = blockIdx.x;                    // b*T+t
  const int b = r >> 5, t = r & 31;
  const int tid = threadIdx.x;
  __shared__ float red[256];
  float a[4];
#pragma unroll
  for (int jj = 0; jj < 4; ++jj) {
    const int s = tid + 256 * jj;
    const float x = alg[(size_t)r * S_ + s];
    a[jj] = (mask[(size_t)b * S_ + s] != 0) ? x : -3.0e38f;
  }
  float m = fmaxf(fmaxf(a[0], a[1]), fmaxf(a[2], a[3]));
  red[tid] = m; __syncthreads();
  for (int st = 128; st > 0; st >>= 1) { if (tid < st) red[tid] = fmaxf(red[tid], red[tid + st]); __syncthreads(); }
  m = red[0]; __syncthreads();
  float e[4], lsum = 0.f;
#pragma unroll
  for (int jj = 0; jj < 4; ++jj) {
    e[jj] = (a[jj] > -1.0e38f) ? expf(a[jj] - m) : 0.f;
    lsum += e[jj];
  }
  red[tid] = lsum; __syncthreads();
  for (int st = 128; st > 0; st >>= 1) { if (tid < st) red[tid] += red[tid + st]; __syncthreads(); }
  const float rs = 1.f / red[0];
#pragma unroll
  for (int jj = 0; jj < 4; ++jj) {
    const int s = tid + 256 * jj;
    const float p = e[jj] * rs;
    out_at[((size_t)b * S_ + s) * T_ + t] = p;
    pbf[(size_t)r * S_ + s] = f2bf(p);
  }
}

__global__ __launch_bounds__(256) void f5c_context(const u16* __restrict__ pbf, const u16* __restrict__ sbfT,
                                                   float* __restrict__ ctx) {
  const int b = blockIdx.x >> 4, dt = blockIdx.x & 15;
  const int wv = threadIdx.x >> 6, lane = threadIdx.x & 63;
  const int n0 = dt * 64 + wv * 16;
  const int fm = lane & 15, fq = lane >> 4;
  const floatx4 fz = {0.f, 0.f, 0.f, 0.f};
  floatx4 acc0 = fz, acc1 = fz;
  const u16* pa0 = pbf + ((size_t)b * T_ + fm) * S_ + fq * 8;
  const u16* pa1 = pbf + ((size_t)b * T_ + 16 + fm) * S_ + fq * 8;
  const u16* pb  = sbfT + ((size_t)b * D_ + n0 + fm) * S_ + fq * 8;
#pragma unroll 4
  for (int k0 = 0; k0 < S_; k0 += 32) {
    bf16x8 a0 = *(const bf16x8*)(pa0 + k0);
    bf16x8 a1 = *(const bf16x8*)(pa1 + k0);
    bf16x8 bb = *(const bf16x8*)(pb + k0);
    acc0 = __builtin_amdgcn_mfma_f32_16x16x32_bf16(a0, bb, acc0, 0, 0, 0);
    acc1 = __builtin_amdgcn_mfma_f32_16x16x32_bf16(a1, bb, acc1, 0, 0, 0);
  }
  const int col = n0 + fm;
#pragma unroll
  for (int r = 0; r < 4; ++r) {
    ctx[((size_t)b * T_ + fq * 4 + r) * D_ + col] = acc0[r];
    ctx[((size_t)b * T_ + 16 + fq * 4 + r) * D_ + col] = acc1[r];
  }
}

__global__ __launch_bounds__(256) void f6b_outproj(const float* __restrict__ ctx, const float* __restrict__ query,
                                                   const float* __restrict__ Wc, const float* __restrict__ bc,
                                                   float* __restrict__ out_hid) {
  __shared__ float cq[16][128];
  const int c0 = blockIdx.x * 128, r0 = blockIdx.y * 16, k0 = blockIdx.z * 128;
  const int tid = threadIdx.x;
  const int cl = tid & 127, rh = tid >> 7;
  for (int i = tid; i < 16 * 128; i += 256) {
    const int rl = i >> 7, kk = i & 127;
    const int k = k0 + kk, row = r0 + rl;
    cq[rl][kk] = (k < D_) ? ctx[(size_t)row * D_ + k] : query[(size_t)row * H_ + k - D_];
  }
  __syncthreads();
  float acc[8] = {};
  for (int kk = 0; kk < 128; ++kk) {
    const float w = Wc[(size_t)(k0 + kk) * H_ + c0 + cl];
#pragma unroll
    for (int rr = 0; rr < 8; ++rr) acc[rr] = fmaf(cq[rh * 8 + rr][kk], w, acc[rr]);
  }
  const float bb = (blockIdx.z == 0) ? bc[c0 + cl] : 0.f;
#pragma unroll
  for (int rr = 0; rr < 8; ++rr)
    atomicAdd(&out_hid[(size_t)(r0 + rh * 8 + rr) * H_ + c0 + cl], acc[rr] + bb);
}

// ================= TIER-1/2 EXTRAS =================

__global__ __launch_bounds__(256) void kc_cvt(const float* __restrict__ in, u16* __restrict__ out) {
  const size_t i0 = ((size_t)blockIdx.x * 256 + threadIdx.x) * 8;
  float4 a = *(const float4*)(in + i0);
  float4 b = *(const float4*)(in + i0 + 4);
  union { uint4 v; u16 s[8]; } r;
  r.s[0] = f2bf(a.x); r.s[1] = f2bf(a.y); r.s[2] = f2bf(a.z); r.s[3] = f2bf(a.w);
  r.s[4] = f2bf(b.x); r.s[5] = f2bf(b.y); r.s[6] = f2bf(b.z); r.s[7] = f2bf(b.w);
  *(uint4*)(out + i0) = r.v;
}

__global__ __launch_bounds__(256) void f0_transpose(const float* __restrict__ Ws, u16* __restrict__ WsT) {
  __shared__ u16 tile[32][65];
  const int n0 = blockIdx.x * 64, k0 = blockIdx.y * 32;
  const int t = threadIdx.x;
  {
    const int kr = t >> 3, nc = (t & 7) * 8;
    const float* p = Ws + (size_t)(k0 + kr) * D_ + n0 + nc;
    float4 a = *(const float4*)p, b = *(const float4*)(p + 4);
    tile[kr][nc + 0] = f2bf(a.x); tile[kr][nc + 1] = f2bf(a.y);
    tile[kr][nc + 2] = f2bf(a.z); tile[kr][nc + 3] = f2bf(a.w);
    tile[kr][nc + 4] = f2bf(b.x); tile[kr][nc + 5] = f2bf(b.y);
    tile[kr][nc + 6] = f2bf(b.z); tile[kr][nc + 7] = f2bf(b.w);
  }
  __syncthreads();
  {
    const int nr = t >> 2, kc = (t & 3) * 8;
    union { uint4 v; u16 s[8]; } st;
#pragma unroll
    for (int i = 0; i < 8; ++i) st.s[i] = tile[kc + i][nr];
    *(uint4*)(WsT + (size_t)(n0 + nr) * D_ + k0 + kc) = st.v;
  }
}

__global__ __launch_bounds__(256) void f1b_qf(const float* __restrict__ query, const float* __restrict__ Wq,
                                              const float* __restrict__ bq, float* __restrict__ qf) {
  __shared__ float q[8][128];
  const int c0 = blockIdx.x * 256, r0 = blockIdx.y * 8, k0 = blockIdx.z * 128;
  const int tid = threadIdx.x;
  for (int i = tid; i < 8 * 128; i += 256) {
    const int rl = i >> 7, kk = i & 127;
    q[rl][kk] = query[(size_t)(r0 + rl) * H_ + k0 + kk];
  }
  __syncthreads();
  const int col = c0 + tid;
  float acc[8] = {};
  for (int kk = 0; kk < 128; ++kk) {
    const float w = Wq[(size_t)(k0 + kk) * D_ + col];
#pragma unroll
    for (int r = 0; r < 8; ++r) acc[r] = fmaf(q[r][kk], w, acc[r]);
  }
  const float bb = (blockIdx.z == 0) ? bq[col] : 0.f;
#pragma unroll
  for (int r = 0; r < 8; ++r)
    atomicAdd(&qf[(size_t)(r0 + r) * D_ + col], TWO_LOG2E * (acc[r] + bb));
}

__global__ __launch_bounds__(256) void f2c_sfgemm(const u16* __restrict__ A, const u16* __restrict__ BT,
                                                  u16* __restrict__ Cb) {
  __shared__ __align__(16) u16 sA[128 * 40];
  __shared__ __align__(16) u16 sB[64 * 40];
  const int bm0 = blockIdx.y * 128, bn0 = blockIdx.x * 64;
  const int t = threadIdx.x;
  const int wv = t >> 6, lane = t & 63;
  const int wm = (wv >> 1) * 64, wn = (wv & 1) * 32;
  const int fm = lane & 15, fq = lane >> 4;
  const int arow = t >> 1, akc = (t & 1) * 16;
  const int brow = t >> 2, bkc = (t & 3) * 8;
  floatx4 acc[4][2];
  const floatx4 fz = {0.f, 0.f, 0.f, 0.f};
#pragma unroll
  for (int i = 0; i < 4; ++i) { acc[i][0] = fz; acc[i][1] = fz; }
  const uint4* gA = (const uint4*)(A + (size_t)(bm0 + arow) * D_ + akc);
  const uint4* gB = (const uint4*)(BT + (size_t)(bn0 + brow) * D_ + bkc);
  for (int k0 = 0; k0 < D_; k0 += 32) {
    uint4 va0 = gA[k0 >> 3];
    uint4 va1 = gA[(k0 >> 3) + 1];
    uint4 vb = gB[k0 >> 3];
    __syncthreads();
    *(uint4*)&sA[arow * 40 + akc] = va0;
    *(uint4*)&sA[arow * 40 + akc + 8] = va1;
    *(uint4*)&sB[brow * 40 + bkc] = vb;
    __syncthreads();
    bf16x8 af[4], bfr[2];
#pragma unroll
    for (int i = 0; i < 4; ++i) af[i] = *(const bf16x8*)&sA[(wm + i * 16 + fm) * 40 + fq * 8];
#pragma unroll
    for (int j = 0; j < 2; ++j) bfr[j] = *(const bf16x8*)&sB[(wn + j * 16 + fm) * 40 + fq * 8];
#pragma unroll
    for (int i = 0; i < 4; ++i)
#pragma unroll
      for (int j = 0; j < 2; ++j)
        acc[i][j] = __builtin_amdgcn_mfma_f32_16x16x32_bf16(af[i], bfr[j], acc[i][j], 0, 0, 0);
  }
#pragma unroll
  for (int i = 0; i < 4; ++i)
#pragma unroll
    for (int j = 0; j < 2; ++j)
#pragma unroll
      for (int r = 0; r < 4; ++r) {
        const int row = bm0 + wm + i * 16 + fq * 4 + r;
        const int col = bn0 + wn + j * 16 + fm;
        Cb[(size_t)row * D_ + col] = f2bf(TWO_LOG2E * acc[i][j][r]);
      }
}

__global__ __launch_bounds__(256) void f2d_sfgemm(const float* __restrict__ A, const u16* __restrict__ BT,
                                                  u16* __restrict__ Cb) {
  __shared__ __align__(16) u16 sA[128 * 40];
  __shared__ __align__(16) u16 sB[64 * 40];
  const int bm0 = blockIdx.y * 128, bn0 = blockIdx.x * 64;
  const int t = threadIdx.x;
  const int wv = t >> 6, lane = t & 63;
  const int wm = (wv >> 1) * 64, wn = (wv & 1) * 32;
  const int fm = lane & 15, fq = lane >> 4;
  const int arow = t >> 1, akc = (t & 1) * 16;
  const int brow = t >> 2, bkc = (t & 3) * 8;
  floatx4 acc[4][2];
  const floatx4 fz = {0.f, 0.f, 0.f, 0.f};
#pragma unroll
  for (int i = 0; i < 4; ++i) { acc[i][0] = fz; acc[i][1] = fz; }
  const float* gA = A + (size_t)(bm0 + arow) * D_ + akc;
  const uint4* gB = (const uint4*)(BT + (size_t)(bn0 + brow) * D_ + bkc);
  for (int k0 = 0; k0 < D_; k0 += 32) {
    float4 a0 = *(const float4*)(gA + k0);
    float4 a1 = *(const float4*)(gA + k0 + 4);
    float4 a2 = *(const float4*)(gA + k0 + 8);
    float4 a3 = *(const float4*)(gA + k0 + 12);
    uint4 vb = gB[k0 >> 3];
    union { uint4 v[2]; u16 s[16]; } pa;
    pa.s[0] = f2bf(a0.x); pa.s[1] = f2bf(a0.y); pa.s[2] = f2bf(a0.z); pa.s[3] = f2bf(a0.w);
    pa.s[4] = f2bf(a1.x); pa.s[5] = f2bf(a1.y); pa.s[6] = f2bf(a1.z); pa.s[7] = f2bf(a1.w);
    pa.s[8] = f2bf(a2.x); pa.s[9] = f2bf(a2.y); pa.s[10] = f2bf(a2.z); pa.s[11] = f2bf(a2.w);
    pa.s[12] = f2bf(a3.x); pa.s[13] = f2bf(a3.y); pa.s[14] = f2bf(a3.z); pa.s[15] = f2bf(a3.w);
    __syncthreads();
    *(uint4*)&sA[arow * 40 + akc] = pa.v[0];
    *(uint4*)&sA[arow * 40 + akc + 8] = pa.v[1];
    *(uint4*)&sB[brow * 40 + bkc] = vb;
    __syncthreads();
    bf16x8 af[4], bfr[2];
#pragma unroll
    for (int i = 0; i < 4; ++i) af[i] = *(const bf16x8*)&sA[(wm + i * 16 + fm) * 40 + fq * 8];
#pragma unroll
    for (int j = 0; j < 2; ++j) bfr[j] = *(const bf16x8*)&sB[(wn + j * 16 + fm) * 40 + fq * 8];
#pragma unroll
    for (int i = 0; i < 4; ++i)
#pragma unroll
      for (int j = 0; j < 2; ++j)
        acc[i][j] = __builtin_amdgcn_mfma_f32_16x16x32_bf16(af[i], bfr[j], acc[i][j], 0, 0, 0);
  }
#pragma unroll
  for (int i = 0; i < 4; ++i)
#pragma unroll
    for (int j = 0; j < 2; ++j)
#pragma unroll
      for (int r = 0; r < 4; ++r) {
        const int row = bm0 + wm + i * 16 + fq * 4 + r;
        const int col = bn0 + wn + j * 16 + fm;
        Cb[(size_t)row * D_ + col] = f2bf(TWO_LOG2E * acc[i][j][r]);
      }
}

__global__ __launch_bounds__(256) void f4_softmax(const float* __restrict__ alg, const int* __restrict__ mask,
                                                  float* __restrict__ attn) {
  const int r = blockIdx.x;
  const int b = r >> 5;
  const int tid = threadIdx.x;
  __shared__ float red[256];
  float a[4];
#pragma unroll
  for (int jj = 0; jj < 4; ++jj) {
    const int s = tid + 256 * jj;
    const float x = alg[(size_t)r * S_ + s];
    a[jj] = (mask[(size_t)b * S_ + s] != 0) ? x : -3.0e38f;
  }
  float m = fmaxf(fmaxf(a[0], a[1]), fmaxf(a[2], a[3]));
  red[tid] = m; __syncthreads();
  for (int st = 128; st > 0; st >>= 1) { if (tid < st) red[tid] = fmaxf(red[tid], red[tid + st]); __syncthreads(); }
  m = red[0]; __syncthreads();
  float e[4], lsum = 0.f;
#pragma unroll
  for (int jj = 0; jj < 4; ++jj) {
    e[jj] = (a[jj] > -1.0e38f) ? expf(a[jj] - m) : 0.f;
    lsum += e[jj];
  }
  red[tid] = lsum; __syncthreads();
  for (int st = 128; st > 0; st >>= 1) { if (tid < st) red[tid] += red[tid + st]; __syncthreads(); }
  const float rs = 1.f / red[0];
#pragma unroll
  for (int jj = 0; jj < 4; ++jj)
    attn[(size_t)r * S_ + tid + 256 * jj] = e[jj] * rs;
}

__global__ __launch_bounds__(256) void f5b_context(const float* __restrict__ attn, const u16* __restrict__ sbf,
                                                   float* __restrict__ ctx, float* __restrict__ out_at) {
  __shared__ float at[16][64];
  const int s0 = blockIdx.x * 64, t0 = blockIdx.y * 16, b = blockIdx.z;
  const int tid = threadIdx.x;
  for (int i = tid; i < 16 * 64; i += 256) {
    const int tl = i >> 6, sl = i & 63;
    at[tl][sl] = attn[(size_t)(b * T_ + t0 + tl) * S_ + s0 + sl];
  }
  __syncthreads();
  for (int i = tid; i < 64 * 16; i += 256) {
    const int sl = i >> 4, tl = i & 15;
    out_at[((size_t)b * S_ + s0 + sl) * T_ + t0 + tl] = at[tl][sl];
  }
  float acc[16][4] = {};
  for (int sl = 0; sl < 64; ++sl) {
    const u16* srow = sbf + ((size_t)b * S_ + s0 + sl) * D_ + tid;
    float sv[4];
#pragma unroll
    for (int jj = 0; jj < 4; ++jj) sv[jj] = bf2f(srow[256 * jj]);
#pragma unroll
    for (int tl = 0; tl < 16; ++tl) {
      const float w = at[tl][sl];
#pragma unroll
      for (int jj = 0; jj < 4; ++jj) acc[tl][jj] = fmaf(w, sv[jj], acc[tl][jj]);
    }
  }
#pragma unroll
  for (int tl = 0; tl < 16; ++tl)
#pragma unroll
    for (int jj = 0; jj < 4; ++jj)
      atomicAdd(&ctx[(size_t)(b * T_ + t0 + tl) * D_ + tid + 256 * jj], acc[tl][jj]);
}

__global__ __launch_bounds__(256) void f5_context(const float* __restrict__ attn, const float* __restrict__ states,
                                                  float* __restrict__ ctx, float* __restrict__ out_at) {
  __shared__ float at[16][64];
  const int s0 = blockIdx.x * 64, t0 = blockIdx.y * 16, b = blockIdx.z;
  const int tid = threadIdx.x;
  for (int i = tid; i < 16 * 64; i += 256) {
    const int tl = i >> 6, sl = i & 63;
    at[tl][sl] = attn[(size_t)(b * T_ + t0 + tl) * S_ + s0 + sl];
  }
  __syncthreads();
  for (int i = tid; i < 64 * 16; i += 256) {
    const int sl = i >> 4, tl = i & 15;
    out_at[((size_t)b * S_ + s0 + sl) * T_ + t0 + tl] = at[tl][sl];
  }
  float acc[16][4] = {};
  for (int sl = 0; sl < 64; ++sl) {
    const float* srow = states + ((size_t)b * S_ + s0 + sl) * D_ + tid;
    float sv[4];
#pragma unroll
    for (int jj = 0; jj < 4; ++jj) sv[jj] = srow[256 * jj];
#pragma unroll
    for (int tl = 0; tl < 16; ++tl) {
      const float w = at[tl][sl];
#pragma unroll
      for (int jj = 0; jj < 4; ++jj) acc[tl][jj] = fmaf(w, sv[jj], acc[tl][jj]);
    }
  }
#pragma unroll
  for (int tl = 0; tl < 16; ++tl)
#pragma unroll
    for (int jj = 0; jj < 4; ++jj)
      atomicAdd(&ctx[(size_t)(b * T_ + t0 + tl) * D_ + tid + 256 * jj], acc[tl][jj]);
}

// ================= FALLBACK (round-7, passing) =================

__global__ __launch_bounds__(256) void k1_qf(const float* __restrict__ query, const float* __restrict__ Wq,
                                             const float* __restrict__ bq, float* __restrict__ qf) {
  const int r = blockIdx.x;
  const int tid = threadIdx.x;
  __shared__ float q[H_];
  for (int i = tid; i < H_; i += 256) q[i] = query[(size_t)r * H_ + i];
  __syncthreads();
#pragma unroll
  for (int jj = 0; jj < 4; ++jj) {
    const int j = tid + 256 * jj;
    float acc = bq[j];
    for (int k = 0; k < H_; ++k) acc = fmaf(q[k], Wq[(size_t)k * D_ + j], acc);
    qf[(size_t)r * D_ + j] = acc;
  }
}

__global__ __launch_bounds__(256) void k23_align(const float* __restrict__ states, const float* __restrict__ Ws,
                                                 const float* __restrict__ v, const float* __restrict__ qf,
                                                 float* __restrict__ alg) {
  const int b = blockIdx.x >> 6;
  const int s0 = (blockIdx.x & 63) * 16;
  const int tid = threadIdx.x, lane = tid & 63, wv = tid >> 6;
  __shared__ u16 stL[16 * D_];
  __shared__ float vvL[D_];
  __shared__ float red[16 * 4];
  for (int i = tid; i < 16 * D_; i += 256) {
    const int row = i >> 10, col = i & (D_ - 1);
    stL[i] = f2bf(states[((size_t)b * S_ + s0 + row) * D_ + col]);
  }
  for (int i = tid; i < D_; i += 256) vvL[i] = v[i];
  __syncthreads();
  float acc[64];
#pragma unroll
  for (int i = 0; i < 64; ++i) acc[i] = 0.f;
#pragma unroll 4
  for (int k = 0; k < D_; ++k) {
    float wsv[4];
#pragma unroll
    for (int jj = 0; jj < 4; ++jj) wsv[jj] = Ws[(size_t)k * D_ + tid + 256 * jj];
#pragma unroll
    for (int i = 0; i < 16; ++i) {
      const float sv = bf2f(stL[i * D_ + k]);
#pragma unroll
      for (int jj = 0; jj < 4; ++jj) acc[i * 4 + jj] = fmaf(sv, wsv[jj], acc[i * 4 + jj]);
    }
  }
  for (int t = 0; t < T_; ++t) {
    float qv[4];
#pragma unroll
    for (int jj = 0; jj < 4; ++jj) qv[jj] = qf[((size_t)b * T_ + t) * D_ + tid + 256 * jj];
    float part[16];
#pragma unroll
    for (int i = 0; i < 16; ++i) {
      float p = 0.f;
#pragma unroll
      for (int jj = 0; jj < 4; ++jj)
        p = fmaf(vvL[tid + 256 * jj], tanhf(qv[jj] + acc[i * 4 + jj]), p);
      part[i] = p;
    }
#pragma unroll
    for (int i = 0; i < 16; ++i) {
      float x = part[i];
#pragma unroll
      for (int off = 32; off > 0; off >>= 1) x += __shfl_xor(x, off);
      if (lane == 0) red[i * 4 + wv] = x;
    }
    __syncthreads();
    if (tid < 16)
      alg[((size_t)b * T_ + t) * S_ + s0 + tid] =
          red[tid * 4 + 0] + red[tid * 4 + 1] + red[tid * 4 + 2] + red[tid * 4 + 3];
    __syncthreads();
  }
}

__global__ __launch_bounds__(256) void k4_softmax(const float* __restrict__ alg, const int* __restrict__ mask,
                                                  float* __restrict__ attn) {
  const int r = blockIdx.x;
  const int b = r >> 5;
  const int tid = threadIdx.x;
  __shared__ float red[256];
  float a[4];
#pragma unroll
  for (int jj = 0; jj < 4; ++jj) {
    const int s = tid + 256 * jj;
    const float x = alg[(size_t)r * S_ + s];
    a[jj] = (mask[(size_t)b * S_ + s] != 0) ? x : -3.0e38f;
  }
  float m = fmaxf(fmaxf(a[0], a[1]), fmaxf(a[2], a[3]));
  red[tid] = m; __syncthreads();
  for (int st = 128; st > 0; st >>= 1) { if (tid < st) red[tid] = fmaxf(red[tid], red[tid + st]); __syncthreads(); }
  m = red[0]; __syncthreads();
  float e[4], lsum = 0.f;
#pragma unroll
  for (int jj = 0; jj < 4; ++jj) {
    e[jj] = (a[jj] > -1.0e38f) ? expf(a[jj] - m) : 0.f;
    lsum += e[jj];
  }
  red[tid] = lsum; __syncthreads();
  for (int st = 128; st > 0; st >>= 1) { if (tid < st) red[tid] += red[tid + st]; __syncthreads(); }
  const float rs = 1.f / red[0];
#pragma unroll
  for (int jj = 0; jj < 4; ++jj)
    attn[(size_t)r * S_ + tid + 256 * jj] = e[jj] * rs;
}

__global__ __launch_bounds__(256) void k56_ctx_proj(const float* __restrict__ attn, const float* __restrict__ states,
                                                    const float* __restrict__ query, const float* __restrict__ Wc,
                                                    const float* __restrict__ bc,
                                                    float* __restrict__ out_ctx, float* __restrict__ out_hid,
                                                    float* __restrict__ out_at) {
  const int r = blockIdx.x;
  const int b = r >> 5, t = r & (T_ - 1);
  const int tid = threadIdx.x;
  __shared__ float pr[S_];
  __shared__ float cq[D_ + H_];
  for (int s = tid; s < S_; s += 256) pr[s] = attn[(size_t)r * S_ + s];
  __syncthreads();
  for (int s = tid; s < S_; s += 256) out_at[((size_t)b * S_ + s) * T_ + t] = pr[s];
  float acc[4] = {0.f, 0.f, 0.f, 0.f};
  for (int s = 0; s < S_; ++s) {
    const float w = pr[s];
    const float* srow = states + ((size_t)b * S_ + s) * D_ + tid;
#pragma unroll
    for (int jj = 0; jj < 4; ++jj) acc[jj] = fmaf(w, srow[256 * jj], acc[jj]);
  }
#pragma unroll
  for (int jj = 0; jj < 4; ++jj) {
    cq[tid + 256 * jj] = acc[jj];
    out_ctx[(size_t)r * D_ + tid + 256 * jj] = acc[jj];
  }
  for (int i = tid; i < H_; i += 256) cq[D_ + i] = query[(size_t)r * H_ + i];
  __syncthreads();
#pragma unroll
  for (int jj = 0; jj < 2; ++jj) {
    const int n = tid + 256 * jj;
    float h = bc[n];
    for (int k = 0; k < D_ + H_; ++k) h = fmaf(cq[k], Wc[(size_t)k * H_ + n], h);
    out_hid[(size_t)r * H_ + n] = h;
  }
}

extern "C" void kernel_launch(void* const* d_in, const int* in_sizes, int n_in,
                              void* d_out, int out_size, void* d_ws, size_t ws_size,
                              hipStream_t stream) {
  const float* query  = (const float*)d_in[0];
  const float* states = (const float*)d_in[1];
  const int*   mask   = (const int*)d_in[2];
  const float* Wq     = (const float*)d_in[3];
  const float* bq     = (const float*)d_in[4];
  const float* Ws     = (const float*)d_in[5];
  const float* v      = (const float*)d_in[6];
  const float* Wc     = (const float*)d_in[7];
  const float* bc     = (const float*)d_in[8];

  float* A  = (float*)d_out;               // ctx(final)
  float* Bh = A + (size_t)BT_ * D_;        // hidden
  float* C  = Bh + (size_t)BT_ * H_;       // attn_t

  char* ws = (char*)d_ws;
  u16*   sfb  = (u16*)(ws + 0);
  u16*   WsT  = (u16*)(ws + 8388608);
  float* alg  = (float*)(ws + 10485760);
  u16*   sbf  = (u16*)(ws + 11010048);
  u16*   sbfT = (u16*)(ws + 19398656);
  u16*   pbf  = (u16*)(ws + 27787264);

  const size_t WS_T1 = 11010048;
  const size_t WS_T2 = 19398656;
  const size_t WS_T3 = 28049408;
  const size_t WS_T4 = 36962816;   // + Es16 (8.4MB) + Eq (512KB) + rsum (512B); qfp/hidp in [0,3MB)

  if (ws_size >= WS_T4) {
    // ---------- tier 4 ----------
    float* qfp  = (float*)(ws + 0);        // 2 MB: 4 x 512KB qf split-K partials
    float* hidp = (float*)(ws + 2097152);  // 1 MB: 4 x 256KB hidQ split-K partials
    u16*   Es16 = (u16*)(ws + 28049408);   // 8.4 MB bf16 exp2(scale*sf)
    float* Eq4  = (float*)(ws + 36438016); // 512 KB fp32 exp2(scale*qf)
    float* rsum = (float*)(ws + 36962304); // 512 B fp32 softmax row sums
    prep_fused8<<<2944, 256, 0, stream>>>(states, Ws, query, Wq, bq, Wc, bc,
                                          sbf, sbfT, WsT, qfp, rsum, hidp);
    f2k_sfgemm<<<dim3(16, 32), 256, 0, stream>>>(sbf, WsT, qfp, hidp, Eq4, Bh, Es16);
    f3l_align<<<dim3(256, 2), 256, 0, stream>>>(Eq4, Es16, v, mask, pbf, rsum);
    f5e_context<<<256, 256, 0, stream>>>(pbf, sbfT, rsum, A, C);
    f6c_outproj<<<dim3(4, 8, 8), 256, 0, stream>>>(A, Wc, Bh);
  } else if (ws_size >= WS_T3) {
    // ---------- tier 3 ----------
    (void)hipMemsetAsync(A, 0, (size_t)(BT_ * D_ + BT_ * H_) * 4, stream);  // qf + hidden zero
    prep_fused<<<2816, 256, 0, stream>>>(states, Ws, query, Wq, bq, sbf, sbfT, WsT, A);
    f2e_sfgemm<<<dim3(16, 32), 256, 0, stream>>>(sbf, WsT, sfb);
    f3f_align<<<dim3(1024, 2), 256, 0, stream>>>(A, sfb, v, alg);
    f4b_softmax<<<BT_, 256, 0, stream>>>(alg, mask, C, pbf);
    f5c_context<<<64, 256, 0, stream>>>(pbf, sbfT, A);
    f6b_outproj<<<dim3(4, 8, 12), 256, 0, stream>>>(A, query, Wc, bc, Bh);
  } else if (ws_size >= WS_T1) {
    // ---------- tier 1/2 ----------
    float* attn = alg;
    (void)hipMemsetAsync(A, 0, (size_t)(BT_ * D_ + BT_ * H_) * 4, stream);
    f1b_qf<<<dim3(4, 16, 4), 256, 0, stream>>>(query, Wq, bq, A);
    f0_transpose<<<dim3(16, 32), 256, 0, stream>>>(Ws, WsT);
    const int tier2 = (ws_size >= WS_T2);
    if (tier2) {
      kc_cvt<<<2048, 256, 0, stream>>>(states, sbf);
      f2c_sfgemm<<<dim3(16, 32), 256, 0, stream>>>(sbf, WsT, sfb);
    } else {
      f2d_sfgemm<<<dim3(16, 32), 256, 0, stream>>>(states, WsT, sfb);
    }
    f3f_align<<<dim3(1024, 2), 256, 0, stream>>>(A, sfb, v, C);
    (void)hipMemsetAsync(A, 0, (size_t)BT_ * D_ * 4, stream);
    f4_softmax<<<BT_, 256, 0, stream>>>(C, mask, attn);
    if (tier2)
      f5b_context<<<dim3(16, 2, 4), 256, 0, stream>>>(attn, sbf, A, C);
    else
      f5_context<<<dim3(16, 2, 4), 256, 0, stream>>>(attn, states, A, C);
    f6b_outproj<<<dim3(4, 8, 12), 256, 0, stream>>>(A, query, Wc, bc, Bh);
  } else {
    // ---------- fallback ----------
    k1_qf<<<BT_, 256, 0, stream>>>(query, Wq, bq, A);
    k23_align<<<B_ * (S_ / 16), 256, 0, stream>>>(states, Ws, v, A, C);
    k4_softmax<<<BT_, 256, 0, stream>>>(C, mask, A);
    k56_ctx_proj<<<BT_, 256, 0, stream>>>(A, states, query, Wc, bc, A, Bh, C);
  }
}

// Round 11
// 157.408 us; speedup vs baseline: 1.1700x; 1.0077x over previous
//
#include <hip/hip_runtime.h>
#include <math.h>

// Bahdanau additive attention. B=4, T=32, S=1024, H=512, D=2H=1024.
// Inputs fp32 (mask int32), OUTPUT fp32 flat:
//   context (4,32,1024) | hidden (4,32,512) | attn_t (4,1024,32)
// Round 26: R25 (measured 158.6 best) + prep light-block coarsening: states
// cvt+transpose in 64x64 tiles (1024 blocks, 4 indep float4 loads/thread)
// instead of 32x64 (2048 blocks, 2 loads) -- 2x MLP per wave, half the
// per-block latency overhead. LDS 12.4KB < wave-cap threshold (8 blk/CU
// unchanged; R22 lesson checked). Per-element math identical.
// Chain: prep(1920) + f2k(512) + f3l(256x2) + f5e(256) + f6c(256).
// d_out overlay: A[0,131072): ctx(final)  B[131072,196608): hidden(f2k-init)
//                C[196608,327680): attn_t(final)

typedef unsigned short u16;
typedef __bf16 bf16x8 __attribute__((ext_vector_type(8)));
typedef float floatx4 __attribute__((ext_vector_type(4)));

#define B_ 4
#define T_ 32
#define S_ 1024
#define H_ 512
#define D_ 1024
#define BT_ 128
#define TWO_LOG2E 2.8853900817779268f   // tanh(y) = 1 - 2/(exp2(2*log2e*y)+1)
#define LOG2E 1.4426950408889634f

__device__ __forceinline__ float bf2f(u16 u) {
  unsigned int i = ((unsigned int)u) << 16;
  return __builtin_bit_cast(float, i);
}
__device__ __forceinline__ u16 f2bf(float f) {
  unsigned int i = __builtin_bit_cast(unsigned int, f);
  i += 0x7fffu + ((i >> 16) & 1u);  // RNE
  return (u16)(i >> 16);
}
__device__ __forceinline__ void ld_g2l_16(const u16* g, u16* l) {
  __builtin_amdgcn_global_load_lds((__attribute__((address_space(1))) void*)(u16*)g,
                                   (__attribute__((address_space(3))) void*)l, 16, 0, 0);
}

// ================= TIER-4 KERNELS =================

// ---- PREP9: heavy blocks FIRST so light blocks backfill (no serial tail).
//      [0,256)    qf split-K -> qfp partials (plain stores);
//      [256,384)  hidden query-part split-K -> hidp partials (plain stores);
//      [384,896)  Ws^T -> WsT bf16 (block 384 zeroes rowsum);
//      [896,1920) states -> sbf + sbfT in 64x64 tiles (coarsened).
__global__ __launch_bounds__(256) void prep_fused9(const float* __restrict__ states, const float* __restrict__ Ws,
                                                   const float* __restrict__ query, const float* __restrict__ Wq,
                                                   const float* __restrict__ bq,
                                                   const float* __restrict__ Wc, const float* __restrict__ bc,
                                                   u16* __restrict__ sbf, u16* __restrict__ sbfT,
                                                   u16* __restrict__ WsT, float* __restrict__ qfp,
                                                   float* __restrict__ rowsum, float* __restrict__ hidp) {
  __shared__ u16 tile[64][65];                    // 8.3 KB (Ws branch uses [0,32) rows)
  __shared__ float q[8][128];                     // 4 KB; total 12.4 KB < wave-cap limit
  const int t = threadIdx.x;
  if (blockIdx.x < 256) {
    const int idx = blockIdx.x;                   // 0..255: qf split-K partials
    const int c0 = (idx & 3) * 256, r0 = ((idx >> 2) & 15) * 8, ks = idx >> 6;
    const int k0 = ks * 128;
    for (int i = t; i < 8 * 128; i += 256) {
      const int rl = i >> 7, kk = i & 127;
      q[rl][kk] = query[(size_t)(r0 + rl) * H_ + k0 + kk];
    }
    __syncthreads();
    const int col = c0 + t;
    float acc[8] = {};
    for (int kk = 0; kk < 128; ++kk) {
      const float w = Wq[(size_t)(k0 + kk) * D_ + col];
#pragma unroll
      for (int r = 0; r < 8; ++r) acc[r] = fmaf(q[r][kk], w, acc[r]);
    }
    const float bb = (ks == 0) ? bq[col] : 0.f;
    float* dst = qfp + (size_t)ks * (BT_ * D_);
#pragma unroll
    for (int r = 0; r < 8; ++r)
      dst[(size_t)(r0 + r) * D_ + col] = TWO_LOG2E * (acc[r] + bb);
  } else if (blockIdx.x < 384) {
    const int idx = blockIdx.x - 256;             // 0..127: hidden query-part partials
    const int c0 = (idx & 1) * 256, r0 = ((idx >> 1) & 15) * 8, ks = idx >> 5;
    const int k0 = ks * 128;
    for (int i = t; i < 8 * 128; i += 256) {
      const int rl = i >> 7, kk = i & 127;
      q[rl][kk] = query[(size_t)(r0 + rl) * H_ + k0 + kk];
    }
    __syncthreads();
    const int col = c0 + t;
    float acc[8] = {};
    for (int kk = 0; kk < 128; ++kk) {
      const float w = Wc[(size_t)(D_ + k0 + kk) * H_ + col];
#pragma unroll
      for (int r = 0; r < 8; ++r) acc[r] = fmaf(q[r][kk], w, acc[r]);
    }
    const float bb = (ks == 0) ? bc[col] : 0.f;
    float* dst = hidp + (size_t)ks * (BT_ * H_);
#pragma unroll
    for (int r = 0; r < 8; ++r)
      dst[(size_t)(r0 + r) * H_ + col] = acc[r] + bb;
  } else if (blockIdx.x < 896) {
    const int bid = blockIdx.x - 384;             // 0..511: Ws transpose
    if (bid == 0 && t < 128) rowsum[t] = 0.f;     // zero rsum (read only by f3l)
    const int n0 = (bid & 15) * 64, k0 = (bid >> 4) * 32;
    const int kr = t >> 3, nc = (t & 7) * 8;
    const float* p = Ws + (size_t)(k0 + kr) * D_ + n0 + nc;
    float4 a = *(const float4*)p, b = *(const float4*)(p + 4);
    tile[kr][nc + 0] = f2bf(a.x); tile[kr][nc + 1] = f2bf(a.y);
    tile[kr][nc + 2] = f2bf(a.z); tile[kr][nc + 3] = f2bf(a.w);
    tile[kr][nc + 4] = f2bf(b.x); tile[kr][nc + 5] = f2bf(b.y);
    tile[kr][nc + 6] = f2bf(b.z); tile[kr][nc + 7] = f2bf(b.w);
    __syncthreads();
    const int nr = t >> 2, kc = (t & 3) * 8;
    union { uint4 v; u16 s[8]; } st;
#pragma unroll
    for (int i = 0; i < 8; ++i) st.s[i] = tile[kc + i][nr];
    *(uint4*)(WsT + (size_t)(n0 + nr) * D_ + k0 + kc) = st.v;
  } else {
    const int bid = blockIdx.x - 896;             // 0..1023: states cvt+transpose 64x64
    const int b = bid >> 8;
    const int r2 = bid & 255;
    const int d0 = (r2 & 15) * 64, s0 = (r2 >> 4) * 64;
    const int sr = t >> 2, dc = (t & 3) * 16;
    const float4* p = (const float4*)(states + ((size_t)b * S_ + s0 + sr) * D_ + d0 + dc);
    const float4 a0 = p[0], a1 = p[1], a2 = p[2], a3 = p[3];
    union { uint4 v[2]; u16 s[16]; } pk;
    pk.s[0]  = f2bf(a0.x); pk.s[1]  = f2bf(a0.y); pk.s[2]  = f2bf(a0.z); pk.s[3]  = f2bf(a0.w);
    pk.s[4]  = f2bf(a1.x); pk.s[5]  = f2bf(a1.y); pk.s[6]  = f2bf(a1.z); pk.s[7]  = f2bf(a1.w);
    pk.s[8]  = f2bf(a2.x); pk.s[9]  = f2bf(a2.y); pk.s[10] = f2bf(a2.z); pk.s[11] = f2bf(a2.w);
    pk.s[12] = f2bf(a3.x); pk.s[13] = f2bf(a3.y); pk.s[14] = f2bf(a3.z); pk.s[15] = f2bf(a3.w);
    u16* sb = sbf + ((size_t)b * S_ + s0 + sr) * D_ + d0 + dc;
    *(uint4*)sb = pk.v[0];
    *(uint4*)(sb + 8) = pk.v[1];
#pragma unroll
    for (int i = 0; i < 16; ++i) tile[sr][dc + i] = pk.s[i];
    __syncthreads();
    const int dr = t >> 2, sc = (t & 3) * 16;
    union { uint4 v[2]; u16 s[16]; } st;
#pragma unroll
    for (int i = 0; i < 16; ++i) st.s[i] = tile[sc + i][dr];
    u16* sd = sbfT + ((size_t)b * D_ + d0 + dr) * S_ + s0 + sc;
    *(uint4*)sd = st.v[0];
    *(uint4*)(sd + 8) = st.v[1];
  }
}

// ---- F2k: Es = bf16(exp2(2log2e*(sbf @ Ws))); prologue: Eq = exp2(sum qfp),
// Bh = sum hidp (plain store; f6c atomics accumulate on top). Double-buffered
// global_load_lds prefetch, counted vmcnt(6), raw s_barrier; XOR-swizzled LDS.
__device__ __forceinline__ void f2f_stage(const u16* __restrict__ A, const u16* __restrict__ BT,
                                          u16* sAb, u16* sBb, int bm0, int bn0, int k0,
                                          int wv, int srow, int sp) {
#pragma unroll
  for (int j = 0; j < 4; ++j) {                  // A: rows wv*32 + j*8 + srow
    const int r = wv * 32 + j * 8 + srow;
    const int c = sp ^ (r & 7);
    ld_g2l_16(A + (size_t)(bm0 + r) * D_ + k0 + c * 8, sAb + (wv * 32 + j * 8) * 64);
  }
#pragma unroll
  for (int j = 0; j < 2; ++j) {                  // B: rows wv*16 + j*8 + srow
    const int r = wv * 16 + j * 8 + srow;
    const int c = sp ^ (r & 7);
    ld_g2l_16(BT + (size_t)(bn0 + r) * D_ + k0 + c * 8, sBb + (wv * 16 + j * 8) * 64);
  }
}

__device__ __forceinline__ void f2f_compute(const u16* sAb, const u16* sBb,
                                            int wm, int wn, int fm, int fq, floatx4 (&acc)[4][2]) {
#pragma unroll
  for (int win = 0; win < 2; ++win) {
    bf16x8 af[4], bfr[2];
#pragma unroll
    for (int i = 0; i < 4; ++i) {
      const int R = wm + i * 16 + fm;
      af[i] = *(const bf16x8*)&sAb[R * 64 + ((win * 4 + fq) ^ (R & 7)) * 8];
    }
#pragma unroll
    for (int j = 0; j < 2; ++j) {
      const int R = wn + j * 16 + fm;
      bfr[j] = *(const bf16x8*)&sBb[R * 64 + ((win * 4 + fq) ^ (R & 7)) * 8];
    }
#pragma unroll
    for (int i = 0; i < 4; ++i)
#pragma unroll
      for (int j = 0; j < 2; ++j)
        acc[i][j] = __builtin_amdgcn_mfma_f32_16x16x32_bf16(af[i], bfr[j], acc[i][j], 0, 0, 0);
  }
}

__global__ __launch_bounds__(256) void f2k_sfgemm(const u16* __restrict__ A, const u16* __restrict__ BT,
                                                  const float* __restrict__ qfp, const float* __restrict__ hidp,
                                                  float* __restrict__ Eq, float* __restrict__ hid,
                                                  u16* __restrict__ Es) {
  __shared__ __align__(16) u16 sA[2][128 * 64];  // 2 x 16 KB
  __shared__ __align__(16) u16 sB[2][64 * 64];   // 2 x 8 KB
  const int bm0 = blockIdx.y * 128, bn0 = blockIdx.x * 64;
  const int t = threadIdx.x;
  const int wv = t >> 6, lane = t & 63;
  const int wm = (wv >> 1) * 64, wn = (wv & 1) * 32;
  const int fm = lane & 15, fq = lane >> 4;
  const int srow = lane >> 3, sp = lane & 7;

  // Prologue: Eq (512 blks x 256 thr = 131072 = BT_*D_) and Bh (first 256 blks).
  {
    const int bid = blockIdx.y * 16 + blockIdx.x;
    const int idx = bid * 256 + t;
    const float s = qfp[idx] + qfp[BT_ * D_ + idx] +
                    qfp[2 * BT_ * D_ + idx] + qfp[3 * BT_ * D_ + idx];
    Eq[idx] = __builtin_amdgcn_exp2f(s);         // prescaled by 2log2e
    if (bid < 256) {
      const int h = bid * 256 + t;               // 65536 = BT_*H_ elems
      hid[h] = hidp[h] + hidp[BT_ * H_ + h] +
               hidp[2 * BT_ * H_ + h] + hidp[3 * BT_ * H_ + h];
    }
  }

  floatx4 acc[4][2];
  const floatx4 fz = {0.f, 0.f, 0.f, 0.f};
#pragma unroll
  for (int i = 0; i < 4; ++i) { acc[i][0] = fz; acc[i][1] = fz; }

  f2f_stage(A, BT, sA[0], sB[0], bm0, bn0, 0, wv, srow, sp);
#pragma unroll 1
  for (int k0 = 0; k0 < D_; k0 += 128) {
    // even phase: compute buf0, prefetch buf1(k0+64)
    f2f_stage(A, BT, sA[1], sB[1], bm0, bn0, k0 + 64, wv, srow, sp);
    asm volatile("s_waitcnt vmcnt(6)" ::: "memory");   // buf0's 6 loads landed
    __builtin_amdgcn_s_barrier();
    f2f_compute(sA[0], sB[0], wm, wn, fm, fq, acc);
    __builtin_amdgcn_s_barrier();                      // all waves done reading buf0
    // odd phase: compute buf1, prefetch buf0(k0+128)
    if (k0 + 128 < D_) {
      f2f_stage(A, BT, sA[0], sB[0], bm0, bn0, k0 + 128, wv, srow, sp);
      asm volatile("s_waitcnt vmcnt(6)" ::: "memory"); // buf1's 6 loads landed
    } else {
      asm volatile("s_waitcnt vmcnt(0)" ::: "memory");
    }
    __builtin_amdgcn_s_barrier();
    f2f_compute(sA[1], sB[1], wm, wn, fm, fq, acc);
    __builtin_amdgcn_s_barrier();
  }
#pragma unroll
  for (int i = 0; i < 4; ++i)
#pragma unroll
    for (int j = 0; j < 2; ++j)
#pragma unroll
      for (int r = 0; r < 4; ++r) {
        const int row = bm0 + wm + i * 16 + fq * 4 + r;   // col=lane&15, row=quad*4+reg (m89)
        const int col = bn0 + wn + j * 16 + fm;
        Es[(size_t)row * D_ + col] = f2bf(__builtin_amdgcn_exp2f(TWO_LOG2E * acc[i][j][r]));
      }
}

// ---- F3l: E = exp(alg), alg = sumv + sum_j vm2_j*rcp(fma(Eq,Es,1)).
// No-max softmax. 4 s-values x 16 t-rows per wave (t-half by blockIdx.y):
// 2 waves/SIMD hides rcp latency; Eq L2 traffic unchanged.
__global__ __launch_bounds__(256) void f3l_align(const float* __restrict__ Eq, const u16* __restrict__ Es,
                                                 const float* __restrict__ v, const int* __restrict__ mask,
                                                 u16* __restrict__ pbf, float* __restrict__ rowsum) {
  __shared__ float red[16][4];
  const int wv = threadIdx.x >> 6, lane = threadIdx.x & 63;
  const int w = blockIdx.x * 4 + wv;                      // 0..1023
  const int b = w >> 8;                                   // 256 waves per batch
  const int s0 = (w & 255) * 4;
  const int t0 = blockIdx.y * 16;
  const int m0 = mask[(size_t)b * S_ + s0 + 0];
  const int m1 = mask[(size_t)b * S_ + s0 + 1];
  const int m2 = mask[(size_t)b * S_ + s0 + 2];
  const int m3 = mask[(size_t)b * S_ + s0 + 3];
  float vm2[16], es0[16], es1[16], es2[16], es3[16];
  float sumv = 0.f;
  {
    union { uint4 u[2]; u16 h[16]; } u0, u1, u2, u3;
    const uint4* ep0 = (const uint4*)(Es + ((size_t)b * S_ + s0 + 0) * D_ + lane * 16);
    const uint4* ep1 = (const uint4*)(Es + ((size_t)b * S_ + s0 + 1) * D_ + lane * 16);
    const uint4* ep2 = (const uint4*)(Es + ((size_t)b * S_ + s0 + 2) * D_ + lane * 16);
    const uint4* ep3 = (const uint4*)(Es + ((size_t)b * S_ + s0 + 3) * D_ + lane * 16);
    u0.u[0] = ep0[0]; u0.u[1] = ep0[1];
    u1.u[0] = ep1[0]; u1.u[1] = ep1[1];
    u2.u[0] = ep2[0]; u2.u[1] = ep2[1];
    u3.u[0] = ep3[0]; u3.u[1] = ep3[1];
    const float4* vp = (const float4*)(v + lane * 16);
#pragma unroll
    for (int c = 0; c < 4; ++c) {
      const float4 w4 = vp[c];
      vm2[4 * c + 0] = -2.f * w4.x; vm2[4 * c + 1] = -2.f * w4.y;
      vm2[4 * c + 2] = -2.f * w4.z; vm2[4 * c + 3] = -2.f * w4.w;
      sumv += w4.x + w4.y + w4.z + w4.w;
    }
#pragma unroll
    for (int j = 0; j < 16; ++j) {
      es0[j] = bf2f(u0.h[j]); es1[j] = bf2f(u1.h[j]);
      es2[j] = bf2f(u2.h[j]); es3[j] = bf2f(u3.h[j]);
    }
  }
  const float* qbase = Eq + ((size_t)(b * T_ + t0)) * D_ + lane * 16;
  for (int tc = 0; tc < 4; ++tc) {               // 4 chunks of 4 t-rows (16 t total)
    float sa[4], sb[4], sc[4], sd[4];
#pragma unroll
    for (int ti = 0; ti < 4; ++ti) {
      const float4* qp = (const float4*)(qbase + (size_t)(tc * 4 + ti) * D_);
      float a0 = sumv, a1 = sumv, a2 = sumv, a3 = sumv;
#pragma unroll
      for (int c = 0; c < 4; ++c) {
        const float4 q4 = qp[c];
        const float xs[4] = {q4.x, q4.y, q4.z, q4.w};
#pragma unroll
        for (int u2 = 0; u2 < 4; ++u2) {
          const int j = 4 * c + u2;
          a0 = fmaf(vm2[j], __builtin_amdgcn_rcpf(fmaf(xs[u2], es0[j], 1.f)), a0);
          a1 = fmaf(vm2[j], __builtin_amdgcn_rcpf(fmaf(xs[u2], es1[j], 1.f)), a1);
          a2 = fmaf(vm2[j], __builtin_amdgcn_rcpf(fmaf(xs[u2], es2[j], 1.f)), a2);
          a3 = fmaf(vm2[j], __builtin_amdgcn_rcpf(fmaf(xs[u2], es3[j], 1.f)), a3);
        }
      }
      sa[ti] = a0; sb[ti] = a1; sc[ti] = a2; sd[ti] = a3;
    }
#pragma unroll
    for (int off = 32; off > 0; off >>= 1)
#pragma unroll
      for (int ti = 0; ti < 4; ++ti) {
        sa[ti] += __shfl_xor(sa[ti], off);
        sb[ti] += __shfl_xor(sb[ti], off);
        sc[ti] += __shfl_xor(sc[ti], off);
        sd[ti] += __shfl_xor(sd[ti], off);
      }
    if (lane == 0) {
#pragma unroll
      for (int ti = 0; ti < 4; ++ti) {
        const int tl = tc * 4 + ti;              // local t in [0,16)
        const int tt = t0 + tl;
        const float e0 = m0 ? __builtin_amdgcn_exp2f(sa[ti] * LOG2E) : 0.f;
        const float e1 = m1 ? __builtin_amdgcn_exp2f(sb[ti] * LOG2E) : 0.f;
        const float e2 = m2 ? __builtin_amdgcn_exp2f(sc[ti] * LOG2E) : 0.f;
        const float e3 = m3 ? __builtin_amdgcn_exp2f(sd[ti] * LOG2E) : 0.f;
        const u16 p0 = f2bf(e0), p1 = f2bf(e1), p2 = f2bf(e2), p3 = f2bf(e3);
        uint2 pk;
        pk.x = (unsigned int)p0 | ((unsigned int)p1 << 16);
        pk.y = (unsigned int)p2 | ((unsigned int)p3 << 16);
        *(uint2*)&pbf[((size_t)(b * T_ + tt)) * S_ + s0] = pk;
        red[tl][wv] = bf2f(p0) + bf2f(p1) + bf2f(p2) + bf2f(p3);
      }
    }
  }
  __syncthreads();
  if (threadIdx.x < 16) {
    const int bb = blockIdx.x >> 6;              // 64 x-blocks per batch
    const float rs = red[threadIdx.x][0] + red[threadIdx.x][1] +
                     red[threadIdx.x][2] + red[threadIdx.x][3];
    atomicAdd(&rowsum[bb * 32 + t0 + threadIdx.x], rs);
  }
}

// ---- F5e: ctx = (E @ states)/rowsum. 256 blocks (16 ctx-cols each); 4 waves
// split S into 256-chunks, LDS-reduce; normalization + attn_t slice folded.
__global__ __launch_bounds__(256) void f5e_context(const u16* __restrict__ pbf, const u16* __restrict__ sbfT,
                                                   const float* __restrict__ rowsum,
                                                   float* __restrict__ ctx, float* __restrict__ out_at) {
  __shared__ float rinv[32];
  __shared__ float red[4][64][9];
  const int b = blockIdx.x >> 6, dt = blockIdx.x & 63;
  const int wv = threadIdx.x >> 6, lane = threadIdx.x & 63;
  if (threadIdx.x < 32) rinv[threadIdx.x] = 1.f / rowsum[b * 32 + threadIdx.x];
  const int n0 = dt * 16;
  const int fm = lane & 15, fq = lane >> 4;
  const floatx4 fz = {0.f, 0.f, 0.f, 0.f};
  floatx4 acc0 = fz, acc1 = fz;
  const u16* pa0 = pbf + ((size_t)b * T_ + fm) * S_ + wv * 256 + fq * 8;
  const u16* pa1 = pa0 + (size_t)16 * S_;
  const u16* pb  = sbfT + ((size_t)b * D_ + n0 + fm) * S_ + wv * 256 + fq * 8;
#pragma unroll
  for (int k0 = 0; k0 < 256; k0 += 32) {
    bf16x8 a0 = *(const bf16x8*)(pa0 + k0);
    bf16x8 a1 = *(const bf16x8*)(pa1 + k0);
    bf16x8 bb = *(const bf16x8*)(pb + k0);
    acc0 = __builtin_amdgcn_mfma_f32_16x16x32_bf16(a0, bb, acc0, 0, 0, 0);
    acc1 = __builtin_amdgcn_mfma_f32_16x16x32_bf16(a1, bb, acc1, 0, 0, 0);
  }
#pragma unroll
  for (int r = 0; r < 4; ++r) {
    red[wv][lane][r] = acc0[r];
    red[wv][lane][4 + r] = acc1[r];
  }
  __syncthreads();
  // attn_t slice: s in [dt*16, dt*16+16), all 32 t. All threads.
  const int s0a = dt * 16;
  for (int i = threadIdx.x; i < 512; i += 256) {
    const int tt = i & 31, sl = i >> 5;
    const float e = bf2f(pbf[((size_t)(b * T_ + tt)) * S_ + s0a + sl]);
    out_at[((size_t)(b * S_ + s0a + sl)) * T_ + tt] = e * rinv[tt];
  }
  if (wv == 0) {
#pragma unroll
    for (int r = 0; r < 4; ++r) {
      const float v0 = red[0][lane][r] + red[1][lane][r] + red[2][lane][r] + red[3][lane][r];
      const float v1 = red[0][lane][4 + r] + red[1][lane][4 + r] +
                       red[2][lane][4 + r] + red[3][lane][4 + r];
      const int t0r = fq * 4 + r;
      ctx[((size_t)b * T_ + t0r) * D_ + n0 + fm] = v0 * rinv[t0r];
      ctx[((size_t)b * T_ + 16 + t0r) * D_ + n0 + fm] = v1 * rinv[16 + t0r];
    }
  }
}

// ---- F6c: hidden += ctx_kslice @ Wc[0:1024] (query part + bias stored by f2k). ----
__global__ __launch_bounds__(256) void f6c_outproj(const float* __restrict__ ctx,
                                                   const float* __restrict__ Wc,
                                                   float* __restrict__ out_hid) {
  __shared__ float cq[16][128];
  const int c0 = blockIdx.x * 128, r0 = blockIdx.y * 16, k0 = blockIdx.z * 128;
  const int tid = threadIdx.x;
  const int cl = tid & 127, rh = tid >> 7;
  for (int i = tid; i < 16 * 128; i += 256) {
    const int rl = i >> 7, kk = i & 127;
    cq[rl][kk] = ctx[(size_t)(r0 + rl) * D_ + k0 + kk];
  }
  __syncthreads();
  float acc[8] = {};
  for (int kk = 0; kk < 128; ++kk) {
    const float w = Wc[(size_t)(k0 + kk) * H_ + c0 + cl];
#pragma unroll
    for (int rr = 0; rr < 8; ++rr) acc[rr] = fmaf(cq[rh * 8 + rr][kk], w, acc[rr]);
  }
#pragma unroll
  for (int rr = 0; rr < 8; ++rr)
    atomicAdd(&out_hid[(size_t)(r0 + rh * 8 + rr) * H_ + c0 + cl], acc[rr]);
}

// ================= TIER-3 KERNELS =================

__global__ __launch_bounds__(256) void prep_fused(const float* __restrict__ states, const float* __restrict__ Ws,
                                                  const float* __restrict__ query, const float* __restrict__ Wq,
                                                  const float* __restrict__ bq,
                                                  u16* __restrict__ sbf, u16* __restrict__ sbfT,
                                                  u16* __restrict__ WsT, float* __restrict__ qf) {
  __shared__ u16 tile[32][65];
  __shared__ float q[8][128];
  const int t = threadIdx.x;
  if (blockIdx.x < 512) {
    const int n0 = (blockIdx.x & 15) * 64, k0 = (blockIdx.x >> 4) * 32;
    const int kr = t >> 3, nc = (t & 7) * 8;
    const float* p = Ws + (size_t)(k0 + kr) * D_ + n0 + nc;
    float4 a = *(const float4*)p, b = *(const float4*)(p + 4);
    tile[kr][nc + 0] = f2bf(a.x); tile[kr][nc + 1] = f2bf(a.y);
    tile[kr][nc + 2] = f2bf(a.z); tile[kr][nc + 3] = f2bf(a.w);
    tile[kr][nc + 4] = f2bf(b.x); tile[kr][nc + 5] = f2bf(b.y);
    tile[kr][nc + 6] = f2bf(b.z); tile[kr][nc + 7] = f2bf(b.w);
    __syncthreads();
    const int nr = t >> 2, kc = (t & 3) * 8;
    union { uint4 v; u16 s[8]; } st;
#pragma unroll
    for (int i = 0; i < 8; ++i) st.s[i] = tile[kc + i][nr];
    *(uint4*)(WsT + (size_t)(n0 + nr) * D_ + k0 + kc) = st.v;
  } else if (blockIdx.x < 2560) {
    const int bid = blockIdx.x - 512;
    const int b = bid >> 9;
    const int r2 = bid & 511;
    const int d0 = (r2 & 15) * 64, s0 = (r2 >> 4) * 32;
    const int sr = t >> 3, dc = (t & 7) * 8;
    const float* p = states + ((size_t)b * S_ + s0 + sr) * D_ + d0 + dc;
    float4 a = *(const float4*)p, bb = *(const float4*)(p + 4);
    union { uint4 v; u16 s[8]; } pk;
    pk.s[0] = f2bf(a.x); pk.s[1] = f2bf(a.y); pk.s[2] = f2bf(a.z); pk.s[3] = f2bf(a.w);
    pk.s[4] = f2bf(bb.x); pk.s[5] = f2bf(bb.y); pk.s[6] = f2bf(bb.z); pk.s[7] = f2bf(bb.w);
    *(uint4*)(sbf + ((size_t)b * S_ + s0 + sr) * D_ + d0 + dc) = pk.v;
#pragma unroll
    for (int i = 0; i < 8; ++i) tile[sr][dc + i] = pk.s[i];
    __syncthreads();
    const int dr = t >> 2, sc = (t & 3) * 8;
    union { uint4 v; u16 s[8]; } st;
#pragma unroll
    for (int i = 0; i < 8; ++i) st.s[i] = tile[sc + i][dr];
    *(uint4*)(sbfT + ((size_t)b * D_ + d0 + dr) * S_ + s0 + sc) = st.v;
  } else {
    const int idx = blockIdx.x - 2560;            // 0..255
    const int c0 = (idx & 3) * 256, r0 = ((idx >> 2) & 15) * 8, k0 = (idx >> 6) * 128;
    for (int i = t; i < 8 * 128; i += 256) {
      const int rl = i >> 7, kk = i & 127;
      q[rl][kk] = query[(size_t)(r0 + rl) * H_ + k0 + kk];
    }
    __syncthreads();
    const int col = c0 + t;
    float acc[8] = {};
    for (int kk = 0; kk < 128; ++kk) {
      const float w = Wq[(size_t)(k0 + kk) * D_ + col];
#pragma unroll
      for (int r = 0; r < 8; ++r) acc[r] = fmaf(q[r][kk], w, acc[r]);
    }
    const float bb = (k0 == 0) ? bq[col] : 0.f;
#pragma unroll
    for (int r = 0; r < 8; ++r)
      atomicAdd(&qf[(size_t)(r0 + r) * D_ + col], TWO_LOG2E * (acc[r] + bb));
  }
}

__global__ __launch_bounds__(256) void f2e_sfgemm(const u16* __restrict__ A, const u16* __restrict__ BT,
                                                  u16* __restrict__ Cb) {
  __shared__ __align__(16) u16 sA[128 * 64];   // 16 KB, row stride 64 u16
  __shared__ __align__(16) u16 sB[64 * 64];    // 8 KB
  const int bm0 = blockIdx.y * 128, bn0 = blockIdx.x * 64;
  const int t = threadIdx.x;
  const int wv = t >> 6, lane = t & 63;
  const int wm = (wv >> 1) * 64, wn = (wv & 1) * 32;
  const int fm = lane & 15, fq = lane >> 4;
  const int srow = lane >> 3, sp = lane & 7;   // staging: 8 rows x 8 chunks per inst

  floatx4 acc[4][2];
  const floatx4 fz = {0.f, 0.f, 0.f, 0.f};
#pragma unroll
  for (int i = 0; i < 4; ++i) { acc[i][0] = fz; acc[i][1] = fz; }

  for (int k0 = 0; k0 < D_; k0 += 64) {
    __syncthreads();                           // prev tile reads done
#pragma unroll
    for (int j = 0; j < 4; ++j) {              // A: rows wv*32 + j*8 + srow
      const int r = wv * 32 + j * 8 + srow;
      const int c = sp ^ (r & 7);
      ld_g2l_16(A + (size_t)(bm0 + r) * D_ + k0 + c * 8, &sA[(wv * 32 + j * 8) * 64]);
    }
#pragma unroll
    for (int j = 0; j < 2; ++j) {              // B: rows wv*16 + j*8 + srow
      const int r = wv * 16 + j * 8 + srow;
      const int c = sp ^ (r & 7);
      ld_g2l_16(BT + (size_t)(bn0 + r) * D_ + k0 + c * 8, &sB[(wv * 16 + j * 8) * 64]);
    }
    __syncthreads();                           // vmcnt(0) drains the async loads
#pragma unroll
    for (int win = 0; win < 2; ++win) {
      bf16x8 af[4], bfr[2];
#pragma unroll
      for (int i = 0; i < 4; ++i) {
        const int R = wm + i * 16 + fm;
        af[i] = *(const bf16x8*)&sA[R * 64 + ((win * 4 + fq) ^ (R & 7)) * 8];
      }
#pragma unroll
      for (int j = 0; j < 2; ++j) {
        const int R = wn + j * 16 + fm;
        bfr[j] = *(const bf16x8*)&sB[R * 64 + ((win * 4 + fq) ^ (R & 7)) * 8];
      }
#pragma unroll
      for (int i = 0; i < 4; ++i)
#pragma unroll
        for (int j = 0; j < 2; ++j)
          acc[i][j] = __builtin_amdgcn_mfma_f32_16x16x32_bf16(af[i], bfr[j], acc[i][j], 0, 0, 0);
    }
  }
#pragma unroll
  for (int i = 0; i < 4; ++i)
#pragma unroll
    for (int j = 0; j < 2; ++j)
#pragma unroll
      for (int r = 0; r < 4; ++r) {
        const int row = bm0 + wm + i * 16 + fq * 4 + r;   // col=lane&15, row=quad*4+reg (m89)
        const int col = bn0 + wn + j * 16 + fm;
        Cb[(size_t)row * D_ + col] = f2bf(TWO_LOG2E * acc[i][j][r]);
      }
}

__global__ __launch_bounds__(256, 6) void f3f_align(const float* __restrict__ qf, const u16* __restrict__ sfb,
                                                    const float* __restrict__ v, float* __restrict__ alg) {
  const int wid = (blockIdx.x * 256 + threadIdx.x) >> 6;  // b*1024+s
  const int lane = threadIdx.x & 63;
  const int b = wid >> 10, s = wid & 1023;
  const int t0 = blockIdx.y * 16;
  float vr[16], sr[16];
  {
    union { uint4 v[2]; u16 s[16]; } u;
    const uint4* sp = (const uint4*)(sfb + (size_t)wid * D_ + lane * 16);
    u.v[0] = sp[0]; u.v[1] = sp[1];
    const float* vp = v + lane * 16;
#pragma unroll
    for (int c = 0; c < 4; ++c) {
      float4 w = *(const float4*)(vp + 4 * c);
      vr[4 * c + 0] = w.x; vr[4 * c + 1] = w.y; vr[4 * c + 2] = w.z; vr[4 * c + 3] = w.w;
    }
#pragma unroll
    for (int j = 0; j < 16; ++j) sr[j] = bf2f(u.s[j]);
  }
  float sum[16];
#pragma unroll
  for (int tt = 0; tt < 16; ++tt) sum[tt] = 0.f;

  const float* qbase = qf + ((size_t)(b * T_ + t0)) * D_ + lane * 16;
  for (int tt = 0; tt < 16; ++tt) {
    const float4* qp = (const float4*)(qbase + (size_t)tt * D_);
    float acc = 0.f;
#pragma unroll
    for (int c = 0; c < 4; ++c) {
      float4 q4 = qp[c];
      float xs[4] = {q4.x, q4.y, q4.z, q4.w};
#pragma unroll
      for (int u2 = 0; u2 < 4; ++u2) {
        const int j = 4 * c + u2;
        const float x = xs[u2] + sr[j];                        // prescaled by 2log2e
        const float e = __builtin_amdgcn_exp2f(x);
        acc = fmaf(vr[j], fmaf(-2.f, __builtin_amdgcn_rcpf(e + 1.f), 1.f), acc);
      }
    }
    sum[tt] = acc;
  }
#pragma unroll
  for (int off = 32; off > 0; off >>= 1)
#pragma unroll
    for (int tt = 0; tt < 16; ++tt) sum[tt] += __shfl_xor(sum[tt], off);
  if (lane == 0) {
#pragma unroll
    for (int tt = 0; tt < 16; ++tt)
      alg[((size_t)(b * T_ + t0 + tt)) * S_ + s] = sum[tt];
  }
}

__global__ __launch_bounds__(256) void f4b_softmax(const float* __restrict__ alg, const int* __restrict__ mask,
                                                   float* __restrict__ out_at, u16* __restrict__ pbf) {
  const int r = blockIdx.x;                    // b*T+t
  const int b = r >> 5, t = r & 31;
  const int tid = threadIdx.x;
  __shared__ float red[256];
  float a[4];
#pragma unroll
  for (int jj = 0; jj < 4; ++jj) {
    const int s = tid + 256 * jj;
    const float x = alg[(size_t)r * S_ + s];
    a[jj] = (mask[(size_t)b * S_ + s] != 0) ? x : -3.0e38f;
  }
  float m = fmaxf(fmaxf(a[0], a[1]), fmaxf(a[2], a[3]));
  red[tid] = m; __syncthreads();
  for (int st = 128; st > 0; st >>= 1) { if (tid < st) red[tid] = fmaxf(red[tid], red[tid + st]); __syncthreads(); }
  m = red[0]; __syncthreads();
  float e[4], lsum = 0.f;
#pragma unroll
  for (int jj = 0; jj < 4; ++jj) {
    e[jj] = (a[jj] > -1.0e38f) ? expf(a[jj] - m) : 0.f;
    lsum += e[jj];
  }
  red[tid] = lsum; __syncthreads();
  for (int st = 128; st > 0; st >>= 1) { if (tid < st) red[tid] += red[tid + st]; __syncthreads(); }
  const float rs = 1.f / red[0];
#pragma unroll
  for (int jj = 0; jj < 4; ++jj) {
    const int s = tid + 256 * jj;
    const float p = e[jj] * rs;
    out_at[((size_t)b * S_ + s) * T_ + t] = p;
    pbf[(size_t)r * S_ + s] = f2bf(p);
  }
}

__global__ __launch_bounds__(256) void f5c_context(const u16* __restrict__ pbf, const u16* __restrict__ sbfT,
                                                   float* __restrict__ ctx) {
  const int b = blockIdx.x >> 4, dt = blockIdx.x & 15;
  const int wv = threadIdx.x >> 6, lane = threadIdx.x & 63;
  const int n0 = dt * 64 + wv * 16;
  const int fm = lane & 15, fq = lane >> 4;
  const floatx4 fz = {0.f, 0.f, 0.f, 0.f};
  floatx4 acc0 = fz, acc1 = fz;
  const u16* pa0 = pbf + ((size_t)b * T_ + fm) * S_ + fq * 8;
  const u16* pa1 = pbf + ((size_t)b * T_ + 16 + fm) * S_ + fq * 8;
  const u16* pb  = sbfT + ((size_t)b * D_ + n0 + fm) * S_ + fq * 8;
#pragma unroll 4
  for (int k0 = 0; k0 < S_; k0 += 32) {
    bf16x8 a0 = *(const bf16x8*)(pa0 + k0);
    bf16x8 a1 = *(const bf16x8*)(pa1 + k0);
    bf16x8 bb = *(const bf16x8*)(pb + k0);
    acc0 = __builtin_amdgcn_mfma_f32_16x16x32_bf16(a0, bb, acc0, 0, 0, 0);
    acc1 = __builtin_amdgcn_mfma_f32_16x16x32_bf16(a1, bb, acc1, 0, 0, 0);
  }
  const int col = n0 + fm;
#pragma unroll
  for (int r = 0; r < 4; ++r) {
    ctx[((size_t)b * T_ + fq * 4 + r) * D_ + col] = acc0[r];
    ctx[((size_t)b * T_ + 16 + fq * 4 + r) * D_ + col] = acc1[r];
  }
}

__global__ __launch_bounds__(256) void f6b_outproj(const float* __restrict__ ctx, const float* __restrict__ query,
                                                   const float* __restrict__ Wc, const float* __restrict__ bc,
                                                   float* __restrict__ out_hid) {
  __shared__ float cq[16][128];
  const int c0 = blockIdx.x * 128, r0 = blockIdx.y * 16, k0 = blockIdx.z * 128;
  const int tid = threadIdx.x;
  const int cl = tid & 127, rh = tid >> 7;
  for (int i = tid; i < 16 * 128; i += 256) {
    const int rl = i >> 7, kk = i & 127;
    const int k = k0 + kk, row = r0 + rl;
    cq[rl][kk] = (k < D_) ? ctx[(size_t)row * D_ + k] : query[(size_t)row * H_ + k - D_];
  }
  __syncthreads();
  float acc[8] = {};
  for (int kk = 0; kk < 128; ++kk) {
    const float w = Wc[(size_t)(k0 + kk) * H_ + c0 + cl];
#pragma unroll
    for (int rr = 0; rr < 8; ++rr) acc[rr] = fmaf(cq[rh * 8 + rr][kk], w, acc[rr]);
  }
  const float bb = (blockIdx.z == 0) ? bc[c0 + cl] : 0.f;
#pragma unroll
  for (int rr = 0; rr < 8; ++rr)
    atomicAdd(&out_hid[(size_t)(r0 + rh * 8 + rr) * H_ + c0 + cl], acc[rr] + bb);
}

// ================= TIER-1/2 EXTRAS =================

__global__ __launch_bounds__(256) void kc_cvt(const float* __restrict__ in, u16* __restrict__ out) {
  const size_t i0 = ((size_t)blockIdx.x * 256 + threadIdx.x) * 8;
  float4 a = *(const float4*)(in + i0);
  float4 b = *(const float4*)(in + i0 + 4);
  union { uint4 v; u16 s[8]; } r;
  r.s[0] = f2bf(a.x); r.s[1] = f2bf(a.y); r.s[2] = f2bf(a.z); r.s[3] = f2bf(a.w);
  r.s[4] = f2bf(b.x); r.s[5] = f2bf(b.y); r.s[6] = f2bf(b.z); r.s[7] = f2bf(b.w);
  *(uint4*)(out + i0) = r.v;
}

__global__ __launch_bounds__(256) void f0_transpose(const float* __restrict__ Ws, u16* __restrict__ WsT) {
  __shared__ u16 tile[32][65];
  const int n0 = blockIdx.x * 64, k0 = blockIdx.y * 32;
  const int t = threadIdx.x;
  {
    const int kr = t >> 3, nc = (t & 7) * 8;
    const float* p = Ws + (size_t)(k0 + kr) * D_ + n0 + nc;
    float4 a = *(const float4*)p, b = *(const float4*)(p + 4);
    tile[kr][nc + 0] = f2bf(a.x); tile[kr][nc + 1] = f2bf(a.y);
    tile[kr][nc + 2] = f2bf(a.z); tile[kr][nc + 3] = f2bf(a.w);
    tile[kr][nc + 4] = f2bf(b.x); tile[kr][nc + 5] = f2bf(b.y);
    tile[kr][nc + 6] = f2bf(b.z); tile[kr][nc + 7] = f2bf(b.w);
  }
  __syncthreads();
  {
    const int nr = t >> 2, kc = (t & 3) * 8;
    union { uint4 v; u16 s[8]; } st;
#pragma unroll
    for (int i = 0; i < 8; ++i) st.s[i] = tile[kc + i][nr];
    *(uint4*)(WsT + (size_t)(n0 + nr) * D_ + k0 + kc) = st.v;
  }
}

__global__ __launch_bounds__(256) void f1b_qf(const float* __restrict__ query, const float* __restrict__ Wq,
                                              const float* __restrict__ bq, float* __restrict__ qf) {
  __shared__ float q[8][128];
  const int c0 = blockIdx.x * 256, r0 = blockIdx.y * 8, k0 = blockIdx.z * 128;
  const int tid = threadIdx.x;
  for (int i = tid; i < 8 * 128; i += 256) {
    const int rl = i >> 7, kk = i & 127;
    q[rl][kk] = query[(size_t)(r0 + rl) * H_ + k0 + kk];
  }
  __syncthreads();
  const int col = c0 + tid;
  float acc[8] = {};
  for (int kk = 0; kk < 128; ++kk) {
    const float w = Wq[(size_t)(k0 + kk) * D_ + col];
#pragma unroll
    for (int r = 0; r < 8; ++r) acc[r] = fmaf(q[r][kk], w, acc[r]);
  }
  const float bb = (blockIdx.z == 0) ? bq[col] : 0.f;
#pragma unroll
  for (int r = 0; r < 8; ++r)
    atomicAdd(&qf[(size_t)(r0 + r) * D_ + col], TWO_LOG2E * (acc[r] + bb));
}

__global__ __launch_bounds__(256) void f2c_sfgemm(const u16* __restrict__ A, const u16* __restrict__ BT,
                                                  u16* __restrict__ Cb) {
  __shared__ __align__(16) u16 sA[128 * 40];
  __shared__ __align__(16) u16 sB[64 * 40];
  const int bm0 = blockIdx.y * 128, bn0 = blockIdx.x * 64;
  const int t = threadIdx.x;
  const int wv = t >> 6, lane = t & 63;
  const int wm = (wv >> 1) * 64, wn = (wv & 1) * 32;
  const int fm = lane & 15, fq = lane >> 4;
  const int arow = t >> 1, akc = (t & 1) * 16;
  const int brow = t >> 2, bkc = (t & 3) * 8;
  floatx4 acc[4][2];
  const floatx4 fz = {0.f, 0.f, 0.f, 0.f};
#pragma unroll
  for (int i = 0; i < 4; ++i) { acc[i][0] = fz; acc[i][1] = fz; }
  const uint4* gA = (const uint4*)(A + (size_t)(bm0 + arow) * D_ + akc);
  const uint4* gB = (const uint4*)(BT + (size_t)(bn0 + brow) * D_ + bkc);
  for (int k0 = 0; k0 < D_; k0 += 32) {
    uint4 va0 = gA[k0 >> 3];
    uint4 va1 = gA[(k0 >> 3) + 1];
    uint4 vb = gB[k0 >> 3];
    __syncthreads();
    *(uint4*)&sA[arow * 40 + akc] = va0;
    *(uint4*)&sA[arow * 40 + akc + 8] = va1;
    *(uint4*)&sB[brow * 40 + bkc] = vb;
    __syncthreads();
    bf16x8 af[4], bfr[2];
#pragma unroll
    for (int i = 0; i < 4; ++i) af[i] = *(const bf16x8*)&sA[(wm + i * 16 + fm) * 40 + fq * 8];
#pragma unroll
    for (int j = 0; j < 2; ++j) bfr[j] = *(const bf16x8*)&sB[(wn + j * 16 + fm) * 40 + fq * 8];
#pragma unroll
    for (int i = 0; i < 4; ++i)
#pragma unroll
      for (int j = 0; j < 2; ++j)
        acc[i][j] = __builtin_amdgcn_mfma_f32_16x16x32_bf16(af[i], bfr[j], acc[i][j], 0, 0, 0);
  }
#pragma unroll
  for (int i = 0; i < 4; ++i)
#pragma unroll
    for (int j = 0; j < 2; ++j)
#pragma unroll
      for (int r = 0; r < 4; ++r) {
        const int row = bm0 + wm + i * 16 + fq * 4 + r;
        const int col = bn0 + wn + j * 16 + fm;
        Cb[(size_t)row * D_ + col] = f2bf(TWO_LOG2E * acc[i][j][r]);
      }
}

__global__ __launch_bounds__(256) void f2d_sfgemm(const float* __restrict__ A, const u16* __restrict__ BT,
                                                  u16* __restrict__ Cb) {
  __shared__ __align__(16) u16 sA[128 * 40];
  __shared__ __align__(16) u16 sB[64 * 40];
  const int bm0 = blockIdx.y * 128, bn0 = blockIdx.x * 64;
  const int t = threadIdx.x;
  const int wv = t >> 6, lane = t & 63;
  const int wm = (wv >> 1) * 64, wn = (wv & 1) * 32;
  const int fm = lane & 15, fq = lane >> 4;
  const int arow = t >> 1, akc = (t & 1) * 16;
  const int brow = t >> 2, bkc = (t & 3) * 8;
  floatx4 acc[4][2];
  const floatx4 fz = {0.f, 0.f, 0.f, 0.f};
#pragma unroll
  for (int i = 0; i < 4; ++i) { acc[i][0] = fz; acc[i][1] = fz; }
  const float* gA = A + (size_t)(bm0 + arow) * D_ + akc;
  const uint4* gB = (const uint4*)(BT + (size_t)(bn0 + brow) * D_ + bkc);
  for (int k0 = 0; k0 < D_; k0 += 32) {
    float4 a0 = *(const float4*)(gA + k0);
    float4 a1 = *(const float4*)(gA + k0 + 4);
    float4 a2 = *(const float4*)(gA + k0 + 8);
    float4 a3 = *(const float4*)(gA + k0 + 12);
    uint4 vb = gB[k0 >> 3];
    union { uint4 v[2]; u16 s[16]; } pa;
    pa.s[0] = f2bf(a0.x); pa.s[1] = f2bf(a0.y); pa.s[2] = f2bf(a0.z); pa.s[3] = f2bf(a0.w);
    pa.s[4] = f2bf(a1.x); pa.s[5] = f2bf(a1.y); pa.s[6] = f2bf(a1.z); pa.s[7] = f2bf(a1.w);
    pa.s[8] = f2bf(a2.x); pa.s[9] = f2bf(a2.y); pa.s[10] = f2bf(a2.z); pa.s[11] = f2bf(a2.w);
    pa.s[12] = f2bf(a3.x); pa.s[13] = f2bf(a3.y); pa.s[14] = f2bf(a3.z); pa.s[15] = f2bf(a3.w);
    __syncthreads();
    *(uint4*)&sA[arow * 40 + akc] = pa.v[0];
    *(uint4*)&sA[arow * 40 + akc + 8] = pa.v[1];
    *(uint4*)&sB[brow * 40 + bkc] = vb;
    __syncthreads();
    bf16x8 af[4], bfr[2];
#pragma unroll
    for (int i = 0; i < 4; ++i) af[i] = *(const bf16x8*)&sA[(wm + i * 16 + fm) * 40 + fq * 8];
#pragma unroll
    for (int j = 0; j < 2; ++j) bfr[j] = *(const bf16x8*)&sB[(wn + j * 16 + fm) * 40 + fq * 8];
#pragma unroll
    for (int i = 0; i < 4; ++i)
#pragma unroll
      for (int j = 0; j < 2; ++j)
        acc[i][j] = __builtin_amdgcn_mfma_f32_16x16x32_bf16(af[i], bfr[j], acc[i][j], 0, 0, 0);
  }
#pragma unroll
  for (int i = 0; i < 4; ++i)
#pragma unroll
    for (int j = 0; j < 2; ++j)
#pragma unroll
      for (int r = 0; r < 4; ++r) {
        const int row = bm0 + wm + i * 16 + fq * 4 + r;
        const int col = bn0 + wn + j * 16 + fm;
        Cb[(size_t)row * D_ + col] = f2bf(TWO_LOG2E * acc[i][j][r]);
      }
}

__global__ __launch_bounds__(256) void f4_softmax(const float* __restrict__ alg, const int* __restrict__ mask,
                                                  float* __restrict__ attn) {
  const int r = blockIdx.x;
  const int b = r >> 5;
  const int tid = threadIdx.x;
  __shared__ float red[256];
  float a[4];
#pragma unroll
  for (int jj = 0; jj < 4; ++jj) {
    const int s = tid + 256 * jj;
    const float x = alg[(size_t)r * S_ + s];
    a[jj] = (mask[(size_t)b * S_ + s] != 0) ? x : -3.0e38f;
  }
  float m = fmaxf(fmaxf(a[0], a[1]), fmaxf(a[2], a[3]));
  red[tid] = m; __syncthreads();
  for (int st = 128; st > 0; st >>= 1) { if (tid < st) red[tid] = fmaxf(red[tid], red[tid + st]); __syncthreads(); }
  m = red[0]; __syncthreads();
  float e[4], lsum = 0.f;
#pragma unroll
  for (int jj = 0; jj < 4; ++jj) {
    e[jj] = (a[jj] > -1.0e38f) ? expf(a[jj] - m) : 0.f;
    lsum += e[jj];
  }
  red[tid] = lsum; __syncthreads();
  for (int st = 128; st > 0; st >>= 1) { if (tid < st) red[tid] += red[tid + st]; __syncthreads(); }
  const float rs = 1.f / red[0];
#pragma unroll
  for (int jj = 0; jj < 4; ++jj)
    attn[(size_t)r * S_ + tid + 256 * jj] = e[jj] * rs;
}

__global__ __launch_bounds__(256) void f5b_context(const float* __restrict__ attn, const u16* __restrict__ sbf,
                                                   float* __restrict__ ctx, float* __restrict__ out_at) {
  __shared__ float at[16][64];
  const int s0 = blockIdx.x * 64, t0 = blockIdx.y * 16, b = blockIdx.z;
  const int tid = threadIdx.x;
  for (int i = tid; i < 16 * 64; i += 256) {
    const int tl = i >> 6, sl = i & 63;
    at[tl][sl] = attn[(size_t)(b * T_ + t0 + tl) * S_ + s0 + sl];
  }
  __syncthreads();
  for (int i = tid; i < 64 * 16; i += 256) {
    const int sl = i >> 4, tl = i & 15;
    out_at[((size_t)b * S_ + s0 + sl) * T_ + t0 + tl] = at[tl][sl];
  }
  float acc[16][4] = {};
  for (int sl = 0; sl < 64; ++sl) {
    const u16* srow = sbf + ((size_t)b * S_ + s0 + sl) * D_ + tid;
    float sv[4];
#pragma unroll
    for (int jj = 0; jj < 4; ++jj) sv[jj] = bf2f(srow[256 * jj]);
#pragma unroll
    for (int tl = 0; tl < 16; ++tl) {
      const float w = at[tl][sl];
#pragma unroll
      for (int jj = 0; jj < 4; ++jj) acc[tl][jj] = fmaf(w, sv[jj], acc[tl][jj]);
    }
  }
#pragma unroll
  for (int tl = 0; tl < 16; ++tl)
#pragma unroll
    for (int jj = 0; jj < 4; ++jj)
      atomicAdd(&ctx[(size_t)(b * T_ + t0 + tl) * D_ + tid + 256 * jj], acc[tl][jj]);
}

__global__ __launch_bounds__(256) void f5_context(const float* __restrict__ attn, const float* __restrict__ states,
                                                  float* __restrict__ ctx, float* __restrict__ out_at) {
  __shared__ float at[16][64];
  const int s0 = blockIdx.x * 64, t0 = blockIdx.y * 16, b = blockIdx.z;
  const int tid = threadIdx.x;
  for (int i = tid; i < 16 * 64; i += 256) {
    const int tl = i >> 6, sl = i & 63;
    at[tl][sl] = attn[(size_t)(b * T_ + t0 + tl) * S_ + s0 + sl];
  }
  __syncthreads();
  for (int i = tid; i < 64 * 16; i += 256) {
    const int sl = i >> 4, tl = i & 15;
    out_at[((size_t)b * S_ + s0 + sl) * T_ + t0 + tl] = at[tl][sl];
  }
  float acc[16][4] = {};
  for (int sl = 0; sl < 64; ++sl) {
    const float* srow = states + ((size_t)b * S_ + s0 + sl) * D_ + tid;
    float sv[4];
#pragma unroll
    for (int jj = 0; jj < 4; ++jj) sv[jj] = srow[256 * jj];
#pragma unroll
    for (int tl = 0; tl < 16; ++tl) {
      const float w = at[tl][sl];
#pragma unroll
      for (int jj = 0; jj < 4; ++jj) acc[tl][jj] = fmaf(w, sv[jj], acc[tl][jj]);
    }
  }
#pragma unroll
  for (int tl = 0; tl < 16; ++tl)
#pragma unroll
    for (int jj = 0; jj < 4; ++jj)
      atomicAdd(&ctx[(size_t)(b * T_ + t0 + tl) * D_ + tid + 256 * jj], acc[tl][jj]);
}

// ================= FALLBACK (round-7, passing) =================

__global__ __launch_bounds__(256) void k1_qf(const float* __restrict__ query, const float* __restrict__ Wq,
                                             const float* __restrict__ bq, float* __restrict__ qf) {
  const int r = blockIdx.x;
  const int tid = threadIdx.x;
  __shared__ float q[H_];
  for (int i = tid; i < H_; i += 256) q[i] = query[(size_t)r * H_ + i];
  __syncthreads();
#pragma unroll
  for (int jj = 0; jj < 4; ++jj) {
    const int j = tid + 256 * jj;
    float acc = bq[j];
    for (int k = 0; k < H_; ++k) acc = fmaf(q[k], Wq[(size_t)k * D_ + j], acc);
    qf[(size_t)r * D_ + j] = acc;
  }
}

__global__ __launch_bounds__(256) void k23_align(const float* __restrict__ states, const float* __restrict__ Ws,
                                                 const float* __restrict__ v, const float* __restrict__ qf,
                                                 float* __restrict__ alg) {
  const int b = blockIdx.x >> 6;
  const int s0 = (blockIdx.x & 63) * 16;
  const int tid = threadIdx.x, lane = tid & 63, wv = tid >> 6;
  __shared__ u16 stL[16 * D_];
  __shared__ float vvL[D_];
  __shared__ float red[16 * 4];
  for (int i = tid; i < 16 * D_; i += 256) {
    const int row = i >> 10, col = i & (D_ - 1);
    stL[i] = f2bf(states[((size_t)b * S_ + s0 + row) * D_ + col]);
  }
  for (int i = tid; i < D_; i += 256) vvL[i] = v[i];
  __syncthreads();
  float acc[64];
#pragma unroll
  for (int i = 0; i < 64; ++i) acc[i] = 0.f;
#pragma unroll 4
  for (int k = 0; k < D_; ++k) {
    float wsv[4];
#pragma unroll
    for (int jj = 0; jj < 4; ++jj) wsv[jj] = Ws[(size_t)k * D_ + tid + 256 * jj];
#pragma unroll
    for (int i = 0; i < 16; ++i) {
      const float sv = bf2f(stL[i * D_ + k]);
#pragma unroll
      for (int jj = 0; jj < 4; ++jj) acc[i * 4 + jj] = fmaf(sv, wsv[jj], acc[i * 4 + jj]);
    }
  }
  for (int t = 0; t < T_; ++t) {
    float qv[4];
#pragma unroll
    for (int jj = 0; jj < 4; ++jj) qv[jj] = qf[((size_t)b * T_ + t) * D_ + tid + 256 * jj];
    float part[16];
#pragma unroll
    for (int i = 0; i < 16; ++i) {
      float p = 0.f;
#pragma unroll
      for (int jj = 0; jj < 4; ++jj)
        p = fmaf(vvL[tid + 256 * jj], tanhf(qv[jj] + acc[i * 4 + jj]), p);
      part[i] = p;
    }
#pragma unroll
    for (int i = 0; i < 16; ++i) {
      float x = part[i];
#pragma unroll
      for (int off = 32; off > 0; off >>= 1) x += __shfl_xor(x, off);
      if (lane == 0) red[i * 4 + wv] = x;
    }
    __syncthreads();
    if (tid < 16)
      alg[((size_t)b * T_ + t) * S_ + s0 + tid] =
          red[tid * 4 + 0] + red[tid * 4 + 1] + red[tid * 4 + 2] + red[tid * 4 + 3];
    __syncthreads();
  }
}

__global__ __launch_bounds__(256) void k4_softmax(const float* __restrict__ alg, const int* __restrict__ mask,
                                                  float* __restrict__ attn) {
  const int r = blockIdx.x;
  const int b = r >> 5;
  const int tid = threadIdx.x;
  __shared__ float red[256];
  float a[4];
#pragma unroll
  for (int jj = 0; jj < 4; ++jj) {
    const int s = tid + 256 * jj;
    const float x = alg[(size_t)r * S_ + s];
    a[jj] = (mask[(size_t)b * S_ + s] != 0) ? x : -3.0e38f;
  }
  float m = fmaxf(fmaxf(a[0], a[1]), fmaxf(a[2], a[3]));
  red[tid] = m; __syncthreads();
  for (int st = 128; st > 0; st >>= 1) { if (tid < st) red[tid] = fmaxf(red[tid], red[tid + st]); __syncthreads(); }
  m = red[0]; __syncthreads();
  float e[4], lsum = 0.f;
#pragma unroll
  for (int jj = 0; jj < 4; ++jj) {
    e[jj] = (a[jj] > -1.0e38f) ? expf(a[jj] - m) : 0.f;
    lsum += e[jj];
  }
  red[tid] = lsum; __syncthreads();
  for (int st = 128; st > 0; st >>= 1) { if (tid < st) red[tid] += red[tid + st]; __syncthreads(); }
  const float rs = 1.f / red[0];
#pragma unroll
  for (int jj = 0; jj < 4; ++jj)
    attn[(size_t)r * S_ + tid + 256 * jj] = e[jj] * rs;
}

__global__ __launch_bounds__(256) void k56_ctx_proj(const float* __restrict__ attn, const float* __restrict__ states,
                                                    const float* __restrict__ query, const float* __restrict__ Wc,
                                                    const float* __restrict__ bc,
                                                    float* __restrict__ out_ctx, float* __restrict__ out_hid,
                                                    float* __restrict__ out_at) {
  const int r = blockIdx.x;
  const int b = r >> 5, t = r & (T_ - 1);
  const int tid = threadIdx.x;
  __shared__ float pr[S_];
  __shared__ float cq[D_ + H_];
  for (int s = tid; s < S_; s += 256) pr[s] = attn[(size_t)r * S_ + s];
  __syncthreads();
  for (int s = tid; s < S_; s += 256) out_at[((size_t)b * S_ + s) * T_ + t] = pr[s];
  float acc[4] = {0.f, 0.f, 0.f, 0.f};
  for (int s = 0; s < S_; ++s) {
    const float w = pr[s];
    const float* srow = states + ((size_t)b * S_ + s) * D_ + tid;
#pragma unroll
    for (int jj = 0; jj < 4; ++jj) acc[jj] = fmaf(w, srow[256 * jj], acc[jj]);
  }
#pragma unroll
  for (int jj = 0; jj < 4; ++jj) {
    cq[tid + 256 * jj] = acc[jj];
    out_ctx[(size_t)r * D_ + tid + 256 * jj] = acc[jj];
  }
  for (int i = tid; i < H_; i += 256) cq[D_ + i] = query[(size_t)r * H_ + i];
  __syncthreads();
#pragma unroll
  for (int jj = 0; jj < 2; ++jj) {
    const int n = tid + 256 * jj;
    float h = bc[n];
    for (int k = 0; k < D_ + H_; ++k) h = fmaf(cq[k], Wc[(size_t)k * H_ + n], h);
    out_hid[(size_t)r * H_ + n] = h;
  }
}

extern "C" void kernel_launch(void* const* d_in, const int* in_sizes, int n_in,
                              void* d_out, int out_size, void* d_ws, size_t ws_size,
                              hipStream_t stream) {
  const float* query  = (const float*)d_in[0];
  const float* states = (const float*)d_in[1];
  const int*   mask   = (const int*)d_in[2];
  const float* Wq     = (const float*)d_in[3];
  const float* bq     = (const float*)d_in[4];
  const float* Ws     = (const float*)d_in[5];
  const float* v      = (const float*)d_in[6];
  const float* Wc     = (const float*)d_in[7];
  const float* bc     = (const float*)d_in[8];

  float* A  = (float*)d_out;               // ctx(final)
  float* Bh = A + (size_t)BT_ * D_;        // hidden
  float* C  = Bh + (size_t)BT_ * H_;       // attn_t

  char* ws = (char*)d_ws;
  u16*   sfb  = (u16*)(ws + 0);
  u16*   WsT  = (u16*)(ws + 8388608);
  float* alg  = (float*)(ws + 10485760);
  u16*   sbf  = (u16*)(ws + 11010048);
  u16*   sbfT = (u16*)(ws + 19398656);
  u16*   pbf  = (u16*)(ws + 27787264);

  const size_t WS_T1 = 11010048;
  const size_t WS_T2 = 19398656;
  const size_t WS_T3 = 28049408;
  const size_t WS_T4 = 36962816;   // + Es16 (8.4MB) + Eq (512KB) + rsum (512B); qfp/hidp in [0,3MB)

  if (ws_size >= WS_T4) {
    // ---------- tier 4 ----------
    float* qfp  = (float*)(ws + 0);        // 2 MB: 4 x 512KB qf split-K partials
    float* hidp = (float*)(ws + 2097152);  // 1 MB: 4 x 256KB hidQ split-K partials
    u16*   Es16 = (u16*)(ws + 28049408);   // 8.4 MB bf16 exp2(scale*sf)
    float* Eq4  = (float*)(ws + 36438016); // 512 KB fp32 exp2(scale*qf)
    float* rsum = (float*)(ws + 36962304); // 512 B fp32 softmax row sums
    prep_fused9<<<1920, 256, 0, stream>>>(states, Ws, query, Wq, bq, Wc, bc,
                                          sbf, sbfT, WsT, qfp, rsum, hidp);
    f2k_sfgemm<<<dim3(16, 32), 256, 0, stream>>>(sbf, WsT, qfp, hidp, Eq4, Bh, Es16);
    f3l_align<<<dim3(256, 2), 256, 0, stream>>>(Eq4, Es16, v, mask, pbf, rsum);
    f5e_context<<<256, 256, 0, stream>>>(pbf, sbfT, rsum, A, C);
    f6c_outproj<<<dim3(4, 8, 8), 256, 0, stream>>>(A, Wc, Bh);
  } else if (ws_size >= WS_T3) {
    // ---------- tier 3 ----------
    (void)hipMemsetAsync(A, 0, (size_t)(BT_ * D_ + BT_ * H_) * 4, stream);  // qf + hidden zero
    prep_fused<<<2816, 256, 0, stream>>>(states, Ws, query, Wq, bq, sbf, sbfT, WsT, A);
    f2e_sfgemm<<<dim3(16, 32), 256, 0, stream>>>(sbf, WsT, sfb);
    f3f_align<<<dim3(1024, 2), 256, 0, stream>>>(A, sfb, v, alg);
    f4b_softmax<<<BT_, 256, 0, stream>>>(alg, mask, C, pbf);
    f5c_context<<<64, 256, 0, stream>>>(pbf, sbfT, A);
    f6b_outproj<<<dim3(4, 8, 12), 256, 0, stream>>>(A, query, Wc, bc, Bh);
  } else if (ws_size >= WS_T1) {
    // ---------- tier 1/2 ----------
    float* attn = alg;
    (void)hipMemsetAsync(A, 0, (size_t)(BT_ * D_ + BT_ * H_) * 4, stream);
    f1b_qf<<<dim3(4, 16, 4), 256, 0, stream>>>(query, Wq, bq, A);
    f0_transpose<<<dim3(16, 32), 256, 0, stream>>>(Ws, WsT);
    const int tier2 = (ws_size >= WS_T2);
    if (tier2) {
      kc_cvt<<<2048, 256, 0, stream>>>(states, sbf);
      f2c_sfgemm<<<dim3(16, 32), 256, 0, stream>>>(sbf, WsT, sfb);
    } else {
      f2d_sfgemm<<<dim3(16, 32), 256, 0, stream>>>(states, WsT, sfb);
    }
    f3f_align<<<dim3(1024, 2), 256, 0, stream>>>(A, sfb, v, C);
    (void)hipMemsetAsync(A, 0, (size_t)BT_ * D_ * 4, stream);
    f4_softmax<<<BT_, 256, 0, stream>>>(C, mask, attn);
    if (tier2)
      f5b_context<<<dim3(16, 2, 4), 256, 0, stream>>>(attn, sbf, A, C);
    else
      f5_context<<<dim3(16, 2, 4), 256, 0, stream>>>(attn, states, A, C);
    f6b_outproj<<<dim3(4, 8, 12), 256, 0, stream>>>(A, query, Wc, bc, Bh);
  } else {
    // ---------- fallback ----------
    k1_qf<<<BT_, 256, 0, stream>>>(query, Wq, bq, A);
    k23_align<<<B_ * (S_ / 16), 256, 0, stream>>>(states, Ws, v, A, C);
    k4_softmax<<<BT_, 256, 0, stream>>>(C, mask, A);
    k56_ctx_proj<<<BT_, 256, 0, stream>>>(A, states, query, Wc, bc, A, Bh, C);
  }
}